// Round 3
// baseline (2845.406 us; speedup 1.0000x reference)
//
#include <hip/hip_runtime.h>
#include <hip/hip_bf16.h>

#define N_NODES  20000
#define N_EDGES  320000
#define E_TOT    (N_EDGES + N_NODES)   /* 340000 incl. self loops */
#define N_GRAPHS 512
#define H1 10
#define C1 78
#define F1 780                          /* H1*C1 */
#define C2 100
#define NEG_SLOPE 0.2f

__device__ __forceinline__ float bf_lo(unsigned int u) { return __uint_as_float(u << 16); }
__device__ __forceinline__ float bf_hi(unsigned int u) { return __uint_as_float(u & 0xFFFF0000u); }

/* ---------------- CSR build (by destination) ---------------- */

__global__ void k_count(const int* __restrict__ ei, int* __restrict__ cnt) {
  int e = blockIdx.x * blockDim.x + threadIdx.x;
  if (e >= E_TOT) return;
  int dst = (e < N_EDGES) ? ei[N_EDGES + e] : (e - N_EDGES);
  atomicAdd(&cnt[dst], 1);
}

__global__ __launch_bounds__(1024) void k_scan(const int* __restrict__ cnt,
                                               int* __restrict__ offs, int n) {
  const int PER = 20;
  int t = threadIdx.x;
  int lane = t & 63, wv = t >> 6;
  int base = t * PER;
  int loc[PER];
  int run = 0;
#pragma unroll
  for (int k = 0; k < PER; k++) {
    int idx = base + k;
    int v = (idx < n) ? cnt[idx] : 0;
    run += v;
    loc[k] = run;
  }
  int total = run;
  int sc = total;
#pragma unroll
  for (int o = 1; o < 64; o <<= 1) {
    int u = __shfl_up(sc, o);
    if (lane >= o) sc += u;
  }
  __shared__ int ws[16];
  if (lane == 63) ws[wv] = sc;
  __syncthreads();
  if (t == 0) {
    int r = 0;
#pragma unroll
    for (int i = 0; i < 16; i++) { int v = ws[i]; ws[i] = r; r += v; }
  }
  __syncthreads();
  int excl = ws[wv] + sc - total;
#pragma unroll
  for (int k = 0; k < PER; k++) {
    int idx = base + k;
    if (idx < n) offs[idx + 1] = excl + loc[k];
  }
  if (t == 0) offs[0] = 0;
}

__global__ void k_scatter(const int* __restrict__ ei, const int* __restrict__ offs,
                          int* __restrict__ cursor, int* __restrict__ srcs) {
  int e = blockIdx.x * blockDim.x + threadIdx.x;
  if (e >= E_TOT) return;
  int src, dst;
  if (e < N_EDGES) { src = ei[e]; dst = ei[N_EDGES + e]; }
  else             { src = dst = e - N_EDGES; }
  int pos = offs[dst] + atomicAdd(&cursor[dst], 1);
  srcs[pos] = src;
}

/* ---------------- Vs[h][k] = sum_c W1[k, h*C1+c] * a_src[h,c]  (and Vd) ---------------- */

__global__ void k_vmake(const float* __restrict__ W1, const float* __restrict__ a_src,
                        const float* __restrict__ a_dst, float* __restrict__ Vs,
                        float* __restrict__ Vd) {
  int t = blockIdx.x * blockDim.x + threadIdx.x;
  if (t >= 2 * H1 * C1) return;
  int which = (t >= H1 * C1) ? 1 : 0;
  int r = t - which * H1 * C1;
  int h = r / C1, k = r - h * C1;
  const float* a = which ? a_dst : a_src;
  float s = 0.f;
  for (int c = 0; c < C1; c++) s += W1[(size_t)k * F1 + h * C1 + c] * a[h * C1 + c];
  (which ? Vd : Vs)[h * C1 + k] = s;
}

/* ---------------- layer-1 logits: asb[h][n] = x[n] . Vs[h] ---------------- */

__global__ __launch_bounds__(256) void k_alpha1x(const float* __restrict__ x,
                                                 const float* __restrict__ Vs,
                                                 const float* __restrict__ Vd,
                                                 float* __restrict__ asb,
                                                 float* __restrict__ adb) {
  __shared__ float sVs[H1 * C1], sVd[H1 * C1];
  for (int i = threadIdx.x; i < H1 * C1; i += 256) { sVs[i] = Vs[i]; sVd[i] = Vd[i]; }
  __syncthreads();
  int t = blockIdx.x * 256 + threadIdx.x;
  if (t >= N_NODES * H1) return;
  int n = t / H1, h = t - n * H1;
  const float* row = x + (size_t)n * C1;
  float s0 = 0.f, s1 = 0.f;
#pragma unroll 2
  for (int c = 0; c < C1; c++) {
    float v = row[c];
    s0 += v * sVs[h * C1 + c];
    s1 += v * sVd[h * C1 + c];
  }
  asb[(size_t)h * N_NODES + n] = s0;
  adb[(size_t)h * N_NODES + n] = s1;
}

/* ---------------- layer-1 softmax + x-aggregation: wave per dst, ALL heads -----------
   xagg[n][h*C1+c] = sum_e alpha[e,h] * x[src_e][c]                                     */

__global__ __launch_bounds__(256) void k_agg(const float* __restrict__ x,
                                             const float* __restrict__ asb,
                                             const float* __restrict__ adb,
                                             const int* __restrict__ offs,
                                             const int* __restrict__ srcs,
                                             float* __restrict__ xagg) {
  int wid = (blockIdx.x * 256 + threadIdx.x) >> 6;
  int lane = threadIdx.x & 63;
  if (wid >= N_NODES) return;
  int n = wid;
  int beg = offs[n], deg = offs[n + 1] - beg;

  float acc[H1][2] = {};   /* lane<39 owns channels 2l, 2l+1 of every head */

  if (deg <= 64) {
    bool act = lane < deg;
    int s = act ? srcs[beg + lane] : 0;
    float p[H1];
#pragma unroll
    for (int h = 0; h < H1; h++) {
      float ev = -INFINITY;
      if (act) {
        float t = asb[(size_t)h * N_NODES + s] + adb[(size_t)h * N_NODES + n];
        ev = (t > 0.f) ? t : NEG_SLOPE * t;
      }
      float m = ev;
#pragma unroll
      for (int o = 32; o; o >>= 1) m = fmaxf(m, __shfl_xor(m, o));
      float pv = act ? __expf(ev - m) : 0.f;
      float ss = pv;
#pragma unroll
      for (int o = 32; o; o >>= 1) ss += __shfl_xor(ss, o);
      p[h] = pv / (ss + 1e-16f);
    }
    /* gather x rows, unroll 2 edges for MLP */
    int j = 0;
    for (; j + 1 < deg; j += 2) {
      int s0 = __shfl(s, j), s1 = __shfl(s, j + 1);
      float2 xv0 = make_float2(0.f, 0.f), xv1 = make_float2(0.f, 0.f);
      if (lane < C1 / 2) {
        xv0 = *(const float2*)(x + (size_t)s0 * C1 + 2 * lane);
        xv1 = *(const float2*)(x + (size_t)s1 * C1 + 2 * lane);
      }
#pragma unroll
      for (int h = 0; h < H1; h++) {
        float w0 = __shfl(p[h], j), w1 = __shfl(p[h], j + 1);
        acc[h][0] += w0 * xv0.x + w1 * xv1.x;
        acc[h][1] += w0 * xv0.y + w1 * xv1.y;
      }
    }
    if (j < deg) {
      int s0 = __shfl(s, j);
      float2 xv0 = make_float2(0.f, 0.f);
      if (lane < C1 / 2) xv0 = *(const float2*)(x + (size_t)s0 * C1 + 2 * lane);
#pragma unroll
      for (int h = 0; h < H1; h++) {
        float w0 = __shfl(p[h], j);
        acc[h][0] += w0 * xv0.x;
        acc[h][1] += w0 * xv0.y;
      }
    }
  } else {
    /* general path: strided max/sum, then chunked gather */
    float m[H1], ssum[H1];
#pragma unroll
    for (int h = 0; h < H1; h++) { m[h] = -INFINITY; ssum[h] = 0.f; }
    for (int i = lane; i < deg; i += 64) {
      int s = srcs[beg + i];
#pragma unroll
      for (int h = 0; h < H1; h++) {
        float t = asb[(size_t)h * N_NODES + s] + adb[(size_t)h * N_NODES + n];
        t = (t > 0.f) ? t : NEG_SLOPE * t;
        m[h] = fmaxf(m[h], t);
      }
    }
#pragma unroll
    for (int h = 0; h < H1; h++)
#pragma unroll
      for (int o = 32; o; o >>= 1) m[h] = fmaxf(m[h], __shfl_xor(m[h], o));
    for (int i = lane; i < deg; i += 64) {
      int s = srcs[beg + i];
#pragma unroll
      for (int h = 0; h < H1; h++) {
        float t = asb[(size_t)h * N_NODES + s] + adb[(size_t)h * N_NODES + n];
        t = (t > 0.f) ? t : NEG_SLOPE * t;
        ssum[h] += __expf(t - m[h]);
      }
    }
#pragma unroll
    for (int h = 0; h < H1; h++) {
#pragma unroll
      for (int o = 32; o; o >>= 1) ssum[h] += __shfl_xor(ssum[h], o);
      ssum[h] = 1.f / (ssum[h] + 1e-16f);
    }
    for (int chunk = 0; chunk < deg; chunk += 64) {
      int i = chunk + lane;
      bool act = i < deg;
      int s = act ? srcs[beg + i] : 0;
      float p[H1];
#pragma unroll
      for (int h = 0; h < H1; h++) {
        float pv = 0.f;
        if (act) {
          float t = asb[(size_t)h * N_NODES + s] + adb[(size_t)h * N_NODES + n];
          t = (t > 0.f) ? t : NEG_SLOPE * t;
          pv = __expf(t - m[h]) * ssum[h];
        }
        p[h] = pv;
      }
      int cl = min(64, deg - chunk);
      for (int j = 0; j < cl; j++) {
        int sj = __shfl(s, j);
        float2 xv = make_float2(0.f, 0.f);
        if (lane < C1 / 2) xv = *(const float2*)(x + (size_t)sj * C1 + 2 * lane);
#pragma unroll
        for (int h = 0; h < H1; h++) {
          float wj = __shfl(p[h], j);
          acc[h][0] += wj * xv.x;
          acc[h][1] += wj * xv.y;
        }
      }
    }
  }

  if (lane < C1 / 2) {
#pragma unroll
    for (int h = 0; h < H1; h++)
      *(float2*)(xagg + (size_t)n * F1 + h * C1 + 2 * lane) =
          make_float2(acc[h][0], acc[h][1]);
  }
}

/* ---------------- block-diag GEMM: ha[n, h*C1+j] = ELU(xagg[n,h,:] @ W1[:,h*C1+j] + b1) */

__global__ __launch_bounds__(256) void k_bgemm(const float* __restrict__ A,
                                               const float* __restrict__ W1,
                                               const float* __restrict__ b1,
                                               float* __restrict__ ha) {
  int h = blockIdx.x;
  int m0 = blockIdx.y * 64;
  __shared__ float As[16][64];
  __shared__ float Bs[16][80];
  int tid = threadIdx.x;
  int tx = tid & 15, ty = tid >> 4;
  float acc[4][5] = {};
  for (int k0 = 0; k0 < C1; k0 += 16) {
    int kc = min(16, C1 - k0);
#pragma unroll
    for (int i = 0; i < 4; i++) {
      int li = tid * 4 + i;
      int r = li >> 4, c = li & 15;
      float v = 0.f;
      if (c < kc && m0 + r < N_NODES) v = A[(size_t)(m0 + r) * F1 + h * C1 + k0 + c];
      As[c][r] = v;
    }
#pragma unroll
    for (int i = 0; i < 5; i++) {
      int li = tid * 5 + i;
      int kk = li / 80, j = li - kk * 80;
      float v = 0.f;
      if (kk < kc && j < C1) v = W1[(size_t)(k0 + kk) * F1 + h * C1 + j];
      Bs[kk][j] = v;
    }
    __syncthreads();
#pragma unroll
    for (int kk = 0; kk < 16; kk++) {
      float a[4], b[5];
#pragma unroll
      for (int i = 0; i < 4; i++) a[i] = As[kk][ty * 4 + i];
#pragma unroll
      for (int j = 0; j < 5; j++) b[j] = Bs[kk][tx * 5 + j];
#pragma unroll
      for (int i = 0; i < 4; i++)
#pragma unroll
        for (int j = 0; j < 5; j++) acc[i][j] += a[i] * b[j];
    }
    __syncthreads();
  }
#pragma unroll
  for (int i = 0; i < 4; i++) {
    int m = m0 + ty * 4 + i;
    if (m >= N_NODES) continue;
#pragma unroll
    for (int j = 0; j < 5; j++) {
      int col = tx * 5 + j;
      if (col < C1) {
        float v = acc[i][j] + b1[h * C1 + col];
        v = (v > 0.f) ? v : (__expf(v) - 1.f);
        ha[(size_t)m * F1 + h * C1 + col] = v;
      }
    }
  }
}

/* ---------------- generic fp32 GEMM: C[M,N] = A[M,K] @ B[K,N] ---------------- */

__global__ __launch_bounds__(256) void k_gemm(const float* __restrict__ A,
                                              const float* __restrict__ B,
                                              float* __restrict__ C,
                                              int M, int N, int K) {
  __shared__ float As[16][64];
  __shared__ float Bs[16][64];
  int tid = threadIdx.x;
  int tx = tid & 15, ty = tid >> 4;
  int m0 = blockIdx.y * 64, n0 = blockIdx.x * 64;
  float acc[4][4] = {};
  for (int k0 = 0; k0 < K; k0 += 16) {
#pragma unroll
    for (int i = 0; i < 4; i++) {
      int li = tid * 4 + i;
      int r = li >> 4, c = li & 15;
      float v = 0.f;
      if (m0 + r < M && k0 + c < K) v = A[(size_t)(m0 + r) * K + k0 + c];
      As[c][r] = v;
    }
#pragma unroll
    for (int i = 0; i < 4; i++) {
      int li = tid * 4 + i;
      int kk = li >> 6, j = li & 63;
      float v = 0.f;
      if (k0 + kk < K && n0 + j < N) v = B[(size_t)(k0 + kk) * N + n0 + j];
      Bs[kk][j] = v;
    }
    __syncthreads();
#pragma unroll
    for (int kk = 0; kk < 16; kk++) {
      float a[4], b[4];
#pragma unroll
      for (int i = 0; i < 4; i++) a[i] = As[kk][ty * 4 + i];
#pragma unroll
      for (int i = 0; i < 4; i++) b[i] = Bs[kk][tx * 4 + i];
#pragma unroll
      for (int i = 0; i < 4; i++)
#pragma unroll
        for (int j = 0; j < 4; j++) acc[i][j] += a[i] * b[j];
    }
    __syncthreads();
  }
  for (int i = 0; i < 4; i++) {
    int m = m0 + ty * 4 + i;
    if (m >= M) continue;
    for (int j = 0; j < 4; j++) {
      int n = n0 + tx * 4 + j;
      if (n < N) C[(size_t)m * N + n] = acc[i][j];
    }
  }
}

/* ---------------- layer-2 logits + bf16 convert ---------------- */

__global__ void k_alpha2(const float* __restrict__ z2, const float* __restrict__ a_src,
                         const float* __restrict__ a_dst, float* __restrict__ as,
                         float* __restrict__ ad) {
  int n = blockIdx.x * blockDim.x + threadIdx.x;
  if (n >= N_NODES) return;
  const float* row = z2 + (size_t)n * C2;
  float s0 = 0.f, s1 = 0.f;
  for (int c = 0; c < C2; c++) { float v = row[c]; s0 += v * a_src[c]; s1 += v * a_dst[c]; }
  as[n] = s0; ad[n] = s1;
}

__global__ void k_tobf16(const float* __restrict__ z2, unsigned short* __restrict__ z2b) {
  int t = blockIdx.x * blockDim.x + threadIdx.x;
  if (t >= N_NODES * C2 / 2) return;
  float2 v = ((const float2*)z2)[t];
  ushort2 o;
  o.x = (unsigned short)(__float_as_uint(v.x) >> 16);  /* RTZ bf16: rel err <2^-8, fine */
  o.y = (unsigned short)(__float_as_uint(v.y) >> 16);
  ((ushort2*)z2b)[t] = o;
}

/* ---------------- layer-2 GAT fused with bias+ReLU+graph-max-pool ---------------- */

__global__ __launch_bounds__(256) void k_gat2b(const unsigned short* __restrict__ z2b,
                                               const float* __restrict__ as,
                                               const float* __restrict__ ad,
                                               const int* __restrict__ offs,
                                               const int* __restrict__ srcs,
                                               const float* __restrict__ b2,
                                               const int* __restrict__ batch,
                                               unsigned int* __restrict__ pool) {
  int wid = (blockIdx.x * 256 + threadIdx.x) >> 6;
  int lane = threadIdx.x & 63;
  if (wid >= N_NODES) return;
  int n = wid;
  int beg = offs[n], deg = offs[n + 1] - beg;
  float adv = ad[n];
  const unsigned int* zrow = (const unsigned int*)z2b;

  float acc0 = 0.f, acc1 = 0.f;   /* lane<50: ch 2l, 2l+1 */

  if (deg <= 64) {
    bool act = lane < deg;
    int s = act ? srcs[beg + lane] : 0;
    float e = -INFINITY;
    if (act) {
      float t = as[s] + adv;
      e = (t > 0.f) ? t : NEG_SLOPE * t;
    }
    float m = e;
#pragma unroll
    for (int o = 32; o; o >>= 1) m = fmaxf(m, __shfl_xor(m, o));
    float p = act ? __expf(e - m) : 0.f;
    float ssum = p;
#pragma unroll
    for (int o = 32; o; o >>= 1) ssum += __shfl_xor(ssum, o);
    p *= 1.f / (ssum + 1e-16f);
    int j = 0;
    for (; j + 1 < deg; j += 2) {
      int s0 = __shfl(s, j), s1 = __shfl(s, j + 1);
      float w0 = __shfl(p, j), w1 = __shfl(p, j + 1);
      if (lane < C2 / 2) {
        unsigned int u0 = zrow[(size_t)s0 * (C2 / 2) + lane];
        unsigned int u1 = zrow[(size_t)s1 * (C2 / 2) + lane];
        acc0 += w0 * bf_lo(u0) + w1 * bf_lo(u1);
        acc1 += w0 * bf_hi(u0) + w1 * bf_hi(u1);
      }
    }
    if (j < deg) {
      int s0 = __shfl(s, j);
      float w0 = __shfl(p, j);
      if (lane < C2 / 2) {
        unsigned int u0 = zrow[(size_t)s0 * (C2 / 2) + lane];
        acc0 += w0 * bf_lo(u0);
        acc1 += w0 * bf_hi(u0);
      }
    }
  } else {
    float m = -INFINITY;
    for (int i = lane; i < deg; i += 64) {
      float t = as[srcs[beg + i]] + adv;
      t = (t > 0.f) ? t : NEG_SLOPE * t;
      m = fmaxf(m, t);
    }
#pragma unroll
    for (int o = 32; o; o >>= 1) m = fmaxf(m, __shfl_xor(m, o));
    float ssum = 0.f;
    for (int i = lane; i < deg; i += 64) {
      float t = as[srcs[beg + i]] + adv;
      t = (t > 0.f) ? t : NEG_SLOPE * t;
      ssum += __expf(t - m);
    }
#pragma unroll
    for (int o = 32; o; o >>= 1) ssum += __shfl_xor(ssum, o);
    float inv = 1.f / (ssum + 1e-16f);
    for (int chunk = 0; chunk < deg; chunk += 64) {
      int i = chunk + lane;
      float w = 0.f; int s = 0;
      if (i < deg) {
        s = srcs[beg + i];
        float t = as[s] + adv;
        t = (t > 0.f) ? t : NEG_SLOPE * t;
        w = __expf(t - m) * inv;
      }
      int cl = min(64, deg - chunk);
      for (int j = 0; j < cl; j++) {
        float wj = __shfl(w, j);
        int sj = __shfl(s, j);
        if (lane < C2 / 2) {
          unsigned int u = zrow[(size_t)sj * (C2 / 2) + lane];
          acc0 += wj * bf_lo(u);
          acc1 += wj * bf_hi(u);
        }
      }
    }
  }

  if (lane < C2 / 2) {
    float v0 = fmaxf(acc0 + b2[2 * lane], 0.f);
    float v1 = fmaxf(acc1 + b2[2 * lane + 1], 0.f);
    int g = batch[n];
    atomicMax(&pool[g * C2 + 2 * lane], __float_as_uint(v0));
    atomicMax(&pool[g * C2 + 2 * lane + 1], __float_as_uint(v1));
  }
}

/* ---------------- head: out = relu(pool @ Wg + bg) ---------------- */

__global__ __launch_bounds__(128) void k_head(const float* __restrict__ pool,
                                              const float* __restrict__ Wg,
                                              const float* __restrict__ bg,
                                              float* __restrict__ out) {
  __shared__ float row[C2];
  int g = blockIdx.x;
  if (threadIdx.x < C2) row[threadIdx.x] = pool[g * C2 + threadIdx.x];
  __syncthreads();
  int c = threadIdx.x;
  if (c < C2) {
    float acc = bg[c];
    for (int k = 0; k < C2; k++) acc += row[k] * Wg[k * C2 + c];
    out[g * C2 + c] = fmaxf(acc, 0.f);
  }
}

/* ---------------- launch ---------------- */

extern "C" void kernel_launch(void* const* d_in, const int* in_sizes, int n_in,
                              void* d_out, int out_size, void* d_ws, size_t ws_size,
                              hipStream_t stream) {
  const float* x      = (const float*)d_in[0];
  const int*   ei     = (const int*)d_in[1];
  const int*   batch  = (const int*)d_in[2];
  const float* W1     = (const float*)d_in[4];
  const float* a_src1 = (const float*)d_in[5];
  const float* a_dst1 = (const float*)d_in[6];
  const float* b1     = (const float*)d_in[7];
  const float* W2     = (const float*)d_in[8];
  const float* a_src2 = (const float*)d_in[9];
  const float* a_dst2 = (const float*)d_in[10];
  const float* b2     = (const float*)d_in[11];
  const float* Wg     = (const float*)d_in[12];
  const float* bg     = (const float*)d_in[13];
  float* out = (float*)d_out;

  char* w = (char*)d_ws;
  size_t off = 0;
  auto alloc = [&](size_t bytes) -> void* {
    void* p = w + off;
    off += (bytes + 255) & ~(size_t)255;
    return p;
  };

  float* xagg = (float*)alloc((size_t)N_NODES * F1 * 4);   /* 62.4 MB */
  float* ha   = (float*)alloc((size_t)N_NODES * F1 * 4);   /* 62.4 MB */
  float* asb  = (float*)alloc((size_t)H1 * N_NODES * 4);   /* 800 KB, head-major */
  float* adb  = (float*)alloc((size_t)H1 * N_NODES * 4);
  float* Vs   = (float*)alloc((size_t)H1 * C1 * 4);
  float* Vd   = (float*)alloc((size_t)H1 * C1 * 4);
  int* cnt    = (int*)alloc((size_t)N_NODES * 4);
  int* cursor = (int*)alloc((size_t)N_NODES * 4);
  int* offs   = (int*)alloc((size_t)(N_NODES + 1) * 4);
  int* srcs   = (int*)alloc((size_t)E_TOT * 4);

  /* layer-2 buffers alias dead xagg region (xagg unused after k_bgemm) */
  float* z2           = xagg;                               /* 8 MB */
  float* as2          = z2 + (size_t)N_NODES * C2;
  float* ad2          = as2 + N_NODES;
  unsigned short* z2b = (unsigned short*)(ad2 + N_NODES);   /* 4 MB */
  unsigned int* pool  = (unsigned int*)(z2b + (size_t)N_NODES * C2);

  hipMemsetAsync(cnt, 0, (size_t)N_NODES * 4, stream);
  hipMemsetAsync(cursor, 0, (size_t)N_NODES * 4, stream);

  k_count<<<(E_TOT + 255) / 256, 256, 0, stream>>>(ei, cnt);
  k_scan<<<1, 1024, 0, stream>>>(cnt, offs, N_NODES);
  k_scatter<<<(E_TOT + 255) / 256, 256, 0, stream>>>(ei, offs, cursor, srcs);

  k_vmake<<<7, 256, 0, stream>>>(W1, a_src1, a_dst1, Vs, Vd);
  k_alpha1x<<<(N_NODES * H1 + 255) / 256, 256, 0, stream>>>(x, Vs, Vd, asb, adb);
  k_agg<<<(N_NODES + 3) / 4, 256, 0, stream>>>(x, asb, adb, offs, srcs, xagg);
  k_bgemm<<<dim3(H1, (N_NODES + 63) / 64), 256, 0, stream>>>(xagg, W1, b1, ha);

  /* GEMM2: z2 = ha @ W2  (z2 aliases dead xagg) */
  k_gemm<<<dim3((C2 + 63) / 64, (N_NODES + 63) / 64), 256, 0, stream>>>(ha, W2, z2,
                                                                        N_NODES, C2, F1);
  k_alpha2<<<(N_NODES + 255) / 256, 256, 0, stream>>>(z2, a_src2, a_dst2, as2, ad2);
  k_tobf16<<<(N_NODES * C2 / 2 + 255) / 256, 256, 0, stream>>>(z2, z2b);

  hipMemsetAsync(pool, 0, (size_t)N_GRAPHS * C2 * 4, stream);
  k_gat2b<<<(N_NODES + 3) / 4, 256, 0, stream>>>(z2b, as2, ad2, offs, srcs, b2, batch, pool);
  k_head<<<N_GRAPHS, 128, 0, stream>>>((const float*)pool, Wg, bg, out);
}

// Round 4
// 498.446 us; speedup vs baseline: 5.7086x; 5.7086x over previous
//
#include <hip/hip_runtime.h>
#include <hip/hip_bf16.h>

#define N_NODES  20000
#define N_EDGES  320000
#define E_TOT    (N_EDGES + N_NODES)   /* 340000 incl. self loops */
#define N_GRAPHS 512
#define H1 10
#define C1 78
#define F1 780                          /* H1*C1 */
#define C2 100
#define NEG_SLOPE 0.2f

__device__ __forceinline__ float bf_lo(unsigned int u) { return __uint_as_float(u << 16); }
__device__ __forceinline__ float bf_hi(unsigned int u) { return __uint_as_float(u & 0xFFFF0000u); }

/* ---------------- CSR build (by destination) ---------------- */

__global__ void k_count(const int* __restrict__ ei, int* __restrict__ cnt) {
  int e = blockIdx.x * blockDim.x + threadIdx.x;
  if (e >= E_TOT) return;
  int dst = (e < N_EDGES) ? ei[N_EDGES + e] : (e - N_EDGES);
  atomicAdd(&cnt[dst], 1);
}

__global__ __launch_bounds__(1024) void k_scan(const int* __restrict__ cnt,
                                               int* __restrict__ offs, int n) {
  const int PER = 20;
  int t = threadIdx.x;
  int lane = t & 63, wv = t >> 6;
  int base = t * PER;
  int loc[PER];
  int run = 0;
#pragma unroll
  for (int k = 0; k < PER; k++) {
    int idx = base + k;
    int v = (idx < n) ? cnt[idx] : 0;
    run += v;
    loc[k] = run;
  }
  int total = run;
  int sc = total;
#pragma unroll
  for (int o = 1; o < 64; o <<= 1) {
    int u = __shfl_up(sc, o);
    if (lane >= o) sc += u;
  }
  __shared__ int ws[16];
  if (lane == 63) ws[wv] = sc;
  __syncthreads();
  if (t == 0) {
    int r = 0;
#pragma unroll
    for (int i = 0; i < 16; i++) { int v = ws[i]; ws[i] = r; r += v; }
  }
  __syncthreads();
  int excl = ws[wv] + sc - total;
#pragma unroll
  for (int k = 0; k < PER; k++) {
    int idx = base + k;
    if (idx < n) offs[idx + 1] = excl + loc[k];
  }
  if (t == 0) offs[0] = 0;
}

__global__ void k_scatter(const int* __restrict__ ei, const int* __restrict__ offs,
                          int* __restrict__ cursor, int* __restrict__ srcs) {
  int e = blockIdx.x * blockDim.x + threadIdx.x;
  if (e >= E_TOT) return;
  int src, dst;
  if (e < N_EDGES) { src = ei[e]; dst = ei[N_EDGES + e]; }
  else             { src = dst = e - N_EDGES; }
  int pos = offs[dst] + atomicAdd(&cursor[dst], 1);
  srcs[pos] = src;
}

/* ---------------- Vs[h][k] = sum_c W1[k, h*C1+c] * a_src[h,c]  (and Vd) ---------------- */

__global__ void k_vmake(const float* __restrict__ W1, const float* __restrict__ a_src,
                        const float* __restrict__ a_dst, float* __restrict__ Vs,
                        float* __restrict__ Vd) {
  int t = blockIdx.x * blockDim.x + threadIdx.x;
  if (t >= 2 * H1 * C1) return;
  int which = (t >= H1 * C1) ? 1 : 0;
  int r = t - which * H1 * C1;
  int h = r / C1, k = r - h * C1;
  const float* a = which ? a_dst : a_src;
  float s = 0.f;
  for (int c = 0; c < C1; c++) s += W1[(size_t)k * F1 + h * C1 + c] * a[h * C1 + c];
  (which ? Vd : Vs)[h * C1 + k] = s;
}

/* ---------------- layer-1 logits: asb[h][n] = x[n] . Vs[h] ---------------- */

__global__ __launch_bounds__(256) void k_alpha1x(const float* __restrict__ x,
                                                 const float* __restrict__ Vs,
                                                 const float* __restrict__ Vd,
                                                 float* __restrict__ asb,
                                                 float* __restrict__ adb) {
  __shared__ float sVs[H1 * C1], sVd[H1 * C1];
  for (int i = threadIdx.x; i < H1 * C1; i += 256) { sVs[i] = Vs[i]; sVd[i] = Vd[i]; }
  __syncthreads();
  int t = blockIdx.x * 256 + threadIdx.x;
  if (t >= N_NODES * H1) return;
  int n = t / H1, h = t - n * H1;
  const float* row = x + (size_t)n * C1;
  float s0 = 0.f, s1 = 0.f;
#pragma unroll 2
  for (int c = 0; c < C1; c++) {
    float v = row[c];
    s0 += v * sVs[h * C1 + c];
    s1 += v * sVd[h * C1 + c];
  }
  asb[(size_t)h * N_NODES + n] = s0;
  adb[(size_t)h * N_NODES + n] = s1;
}

/* ---------------- layer-1 softmax + x-aggregation: wave per dst, ALL heads -----------
   xagg[n][h*C1+c] = sum_e alpha[e,h] * x[src_e][c]                                     */

__global__ __launch_bounds__(256) void k_agg(const float* __restrict__ x,
                                             const float* __restrict__ asb,
                                             const float* __restrict__ adb,
                                             const int* __restrict__ offs,
                                             const int* __restrict__ srcs,
                                             float* __restrict__ xagg) {
  int wid = (blockIdx.x * 256 + threadIdx.x) >> 6;
  int lane = threadIdx.x & 63;
  if (wid >= N_NODES) return;
  int n = wid;
  int beg = offs[n], deg = offs[n + 1] - beg;

  float acc[H1][2] = {};   /* lane<39 owns channels 2l, 2l+1 of every head */

  if (deg <= 64) {
    bool act = lane < deg;
    int s = act ? srcs[beg + lane] : 0;
    float p[H1];
#pragma unroll
    for (int h = 0; h < H1; h++) {
      float ev = -INFINITY;
      if (act) {
        float t = asb[(size_t)h * N_NODES + s] + adb[(size_t)h * N_NODES + n];
        ev = (t > 0.f) ? t : NEG_SLOPE * t;
      }
      float m = ev;
#pragma unroll
      for (int o = 32; o; o >>= 1) m = fmaxf(m, __shfl_xor(m, o));
      float pv = act ? __expf(ev - m) : 0.f;
      float ss = pv;
#pragma unroll
      for (int o = 32; o; o >>= 1) ss += __shfl_xor(ss, o);
      p[h] = pv / (ss + 1e-16f);
    }
    int j = 0;
    for (; j + 1 < deg; j += 2) {
      int s0 = __shfl(s, j), s1 = __shfl(s, j + 1);
      float2 xv0 = make_float2(0.f, 0.f), xv1 = make_float2(0.f, 0.f);
      if (lane < C1 / 2) {
        xv0 = *(const float2*)(x + (size_t)s0 * C1 + 2 * lane);
        xv1 = *(const float2*)(x + (size_t)s1 * C1 + 2 * lane);
      }
#pragma unroll
      for (int h = 0; h < H1; h++) {
        float w0 = __shfl(p[h], j), w1 = __shfl(p[h], j + 1);
        acc[h][0] += w0 * xv0.x + w1 * xv1.x;
        acc[h][1] += w0 * xv0.y + w1 * xv1.y;
      }
    }
    if (j < deg) {
      int s0 = __shfl(s, j);
      float2 xv0 = make_float2(0.f, 0.f);
      if (lane < C1 / 2) xv0 = *(const float2*)(x + (size_t)s0 * C1 + 2 * lane);
#pragma unroll
      for (int h = 0; h < H1; h++) {
        float w0 = __shfl(p[h], j);
        acc[h][0] += w0 * xv0.x;
        acc[h][1] += w0 * xv0.y;
      }
    }
  } else {
    float m[H1], ssum[H1];
#pragma unroll
    for (int h = 0; h < H1; h++) { m[h] = -INFINITY; ssum[h] = 0.f; }
    for (int i = lane; i < deg; i += 64) {
      int s = srcs[beg + i];
#pragma unroll
      for (int h = 0; h < H1; h++) {
        float t = asb[(size_t)h * N_NODES + s] + adb[(size_t)h * N_NODES + n];
        t = (t > 0.f) ? t : NEG_SLOPE * t;
        m[h] = fmaxf(m[h], t);
      }
    }
#pragma unroll
    for (int h = 0; h < H1; h++)
#pragma unroll
      for (int o = 32; o; o >>= 1) m[h] = fmaxf(m[h], __shfl_xor(m[h], o));
    for (int i = lane; i < deg; i += 64) {
      int s = srcs[beg + i];
#pragma unroll
      for (int h = 0; h < H1; h++) {
        float t = asb[(size_t)h * N_NODES + s] + adb[(size_t)h * N_NODES + n];
        t = (t > 0.f) ? t : NEG_SLOPE * t;
        ssum[h] += __expf(t - m[h]);
      }
    }
#pragma unroll
    for (int h = 0; h < H1; h++) {
#pragma unroll
      for (int o = 32; o; o >>= 1) ssum[h] += __shfl_xor(ssum[h], o);
      ssum[h] = 1.f / (ssum[h] + 1e-16f);
    }
    for (int chunk = 0; chunk < deg; chunk += 64) {
      int i = chunk + lane;
      bool act = i < deg;
      int s = act ? srcs[beg + i] : 0;
      float p[H1];
#pragma unroll
      for (int h = 0; h < H1; h++) {
        float pv = 0.f;
        if (act) {
          float t = asb[(size_t)h * N_NODES + s] + adb[(size_t)h * N_NODES + n];
          t = (t > 0.f) ? t : NEG_SLOPE * t;
          pv = __expf(t - m[h]) * ssum[h];
        }
        p[h] = pv;
      }
      int cl = min(64, deg - chunk);
      for (int j = 0; j < cl; j++) {
        int sj = __shfl(s, j);
        float2 xv = make_float2(0.f, 0.f);
        if (lane < C1 / 2) xv = *(const float2*)(x + (size_t)sj * C1 + 2 * lane);
#pragma unroll
        for (int h = 0; h < H1; h++) {
          float wj = __shfl(p[h], j);
          acc[h][0] += wj * xv.x;
          acc[h][1] += wj * xv.y;
        }
      }
    }
  }

  if (lane < C1 / 2) {
#pragma unroll
    for (int h = 0; h < H1; h++)
      *(float2*)(xagg + (size_t)n * F1 + h * C1 + 2 * lane) =
          make_float2(acc[h][0], acc[h][1]);
  }
}

/* ---------------- block-diag GEMM, k_gemm-clone shape: grid (2, mblocks, H1) --------
   ha[m, h*C1+col] = ELU(sum_k xagg[m, h*C1+k] * W1[k, h*C1+col] + b1[h*C1+col])        */

__global__ __launch_bounds__(256) void k_bgemm(const float* __restrict__ A,
                                               const float* __restrict__ W1,
                                               const float* __restrict__ b1,
                                               float* __restrict__ ha) {
  __shared__ float As[16][64];
  __shared__ float Bs[16][64];
  int h = blockIdx.z;
  int tid = threadIdx.x;
  int tx = tid & 15, ty = tid >> 4;
  int m0 = blockIdx.y * 64, n0 = blockIdx.x * 64;
  float acc[4][4] = {};
  for (int k0 = 0; k0 < C1; k0 += 16) {
#pragma unroll
    for (int i = 0; i < 4; i++) {
      int li = tid * 4 + i;
      int r = li >> 4, c = li & 15;
      float v = 0.f;
      if (m0 + r < N_NODES && k0 + c < C1) v = A[(size_t)(m0 + r) * F1 + h * C1 + k0 + c];
      As[c][r] = v;
    }
#pragma unroll
    for (int i = 0; i < 4; i++) {
      int li = tid * 4 + i;
      int kk = li >> 6, j = li & 63;
      float v = 0.f;
      if (k0 + kk < C1 && n0 + j < C1) v = W1[(size_t)(k0 + kk) * F1 + h * C1 + n0 + j];
      Bs[kk][j] = v;
    }
    __syncthreads();
#pragma unroll
    for (int kk = 0; kk < 16; kk++) {
      float a[4], b[4];
#pragma unroll
      for (int i = 0; i < 4; i++) a[i] = As[kk][ty * 4 + i];
#pragma unroll
      for (int i = 0; i < 4; i++) b[i] = Bs[kk][tx * 4 + i];
#pragma unroll
      for (int i = 0; i < 4; i++)
#pragma unroll
        for (int j = 0; j < 4; j++) acc[i][j] += a[i] * b[j];
    }
    __syncthreads();
  }
  for (int i = 0; i < 4; i++) {
    int m = m0 + ty * 4 + i;
    if (m >= N_NODES) continue;
    for (int j = 0; j < 4; j++) {
      int col = n0 + tx * 4 + j;
      if (col < C1) {
        float v = acc[i][j] + b1[h * C1 + col];
        v = (v > 0.f) ? v : (__expf(v) - 1.f);
        ha[(size_t)m * F1 + h * C1 + col] = v;
      }
    }
  }
}

/* ---------------- generic fp32 GEMM: C[M,N] = A[M,K] @ B[K,N] ---------------- */

__global__ __launch_bounds__(256) void k_gemm(const float* __restrict__ A,
                                              const float* __restrict__ B,
                                              float* __restrict__ C,
                                              int M, int N, int K) {
  __shared__ float As[16][64];
  __shared__ float Bs[16][64];
  int tid = threadIdx.x;
  int tx = tid & 15, ty = tid >> 4;
  int m0 = blockIdx.y * 64, n0 = blockIdx.x * 64;
  float acc[4][4] = {};
  for (int k0 = 0; k0 < K; k0 += 16) {
#pragma unroll
    for (int i = 0; i < 4; i++) {
      int li = tid * 4 + i;
      int r = li >> 4, c = li & 15;
      float v = 0.f;
      if (m0 + r < M && k0 + c < K) v = A[(size_t)(m0 + r) * K + k0 + c];
      As[c][r] = v;
    }
#pragma unroll
    for (int i = 0; i < 4; i++) {
      int li = tid * 4 + i;
      int kk = li >> 6, j = li & 63;
      float v = 0.f;
      if (k0 + kk < K && n0 + j < N) v = B[(size_t)(k0 + kk) * N + n0 + j];
      Bs[kk][j] = v;
    }
    __syncthreads();
#pragma unroll
    for (int kk = 0; kk < 16; kk++) {
      float a[4], b[4];
#pragma unroll
      for (int i = 0; i < 4; i++) a[i] = As[kk][ty * 4 + i];
#pragma unroll
      for (int i = 0; i < 4; i++) b[i] = Bs[kk][tx * 4 + i];
#pragma unroll
      for (int i = 0; i < 4; i++)
#pragma unroll
        for (int j = 0; j < 4; j++) acc[i][j] += a[i] * b[j];
    }
    __syncthreads();
  }
  for (int i = 0; i < 4; i++) {
    int m = m0 + ty * 4 + i;
    if (m >= M) continue;
    for (int j = 0; j < 4; j++) {
      int n = n0 + tx * 4 + j;
      if (n < N) C[(size_t)m * N + n] = acc[i][j];
    }
  }
}

/* ---------------- layer-2 logits + bf16 convert ---------------- */

__global__ void k_alpha2(const float* __restrict__ z2, const float* __restrict__ a_src,
                         const float* __restrict__ a_dst, float* __restrict__ as,
                         float* __restrict__ ad) {
  int n = blockIdx.x * blockDim.x + threadIdx.x;
  if (n >= N_NODES) return;
  const float* row = z2 + (size_t)n * C2;
  float s0 = 0.f, s1 = 0.f;
  for (int c = 0; c < C2; c++) { float v = row[c]; s0 += v * a_src[c]; s1 += v * a_dst[c]; }
  as[n] = s0; ad[n] = s1;
}

__global__ void k_tobf16(const float* __restrict__ z2, unsigned short* __restrict__ z2b) {
  int t = blockIdx.x * blockDim.x + threadIdx.x;
  if (t >= N_NODES * C2 / 2) return;
  float2 v = ((const float2*)z2)[t];
  ushort2 o;
  o.x = (unsigned short)(__float_as_uint(v.x) >> 16);
  o.y = (unsigned short)(__float_as_uint(v.y) >> 16);
  ((ushort2*)z2b)[t] = o;
}

/* ---------------- layer-2 GAT fused with bias+ReLU+graph-max-pool ---------------- */

__global__ __launch_bounds__(256) void k_gat2b(const unsigned short* __restrict__ z2b,
                                               const float* __restrict__ as,
                                               const float* __restrict__ ad,
                                               const int* __restrict__ offs,
                                               const int* __restrict__ srcs,
                                               const float* __restrict__ b2,
                                               const int* __restrict__ batch,
                                               unsigned int* __restrict__ pool) {
  int wid = (blockIdx.x * 256 + threadIdx.x) >> 6;
  int lane = threadIdx.x & 63;
  if (wid >= N_NODES) return;
  int n = wid;
  int beg = offs[n], deg = offs[n + 1] - beg;
  float adv = ad[n];
  const unsigned int* zrow = (const unsigned int*)z2b;

  float acc0 = 0.f, acc1 = 0.f;

  if (deg <= 64) {
    bool act = lane < deg;
    int s = act ? srcs[beg + lane] : 0;
    float e = -INFINITY;
    if (act) {
      float t = as[s] + adv;
      e = (t > 0.f) ? t : NEG_SLOPE * t;
    }
    float m = e;
#pragma unroll
    for (int o = 32; o; o >>= 1) m = fmaxf(m, __shfl_xor(m, o));
    float p = act ? __expf(e - m) : 0.f;
    float ssum = p;
#pragma unroll
    for (int o = 32; o; o >>= 1) ssum += __shfl_xor(ssum, o);
    p *= 1.f / (ssum + 1e-16f);
    int j = 0;
    for (; j + 1 < deg; j += 2) {
      int s0 = __shfl(s, j), s1 = __shfl(s, j + 1);
      float w0 = __shfl(p, j), w1 = __shfl(p, j + 1);
      if (lane < C2 / 2) {
        unsigned int u0 = zrow[(size_t)s0 * (C2 / 2) + lane];
        unsigned int u1 = zrow[(size_t)s1 * (C2 / 2) + lane];
        acc0 += w0 * bf_lo(u0) + w1 * bf_lo(u1);
        acc1 += w0 * bf_hi(u0) + w1 * bf_hi(u1);
      }
    }
    if (j < deg) {
      int s0 = __shfl(s, j);
      float w0 = __shfl(p, j);
      if (lane < C2 / 2) {
        unsigned int u0 = zrow[(size_t)s0 * (C2 / 2) + lane];
        acc0 += w0 * bf_lo(u0);
        acc1 += w0 * bf_hi(u0);
      }
    }
  } else {
    float m = -INFINITY;
    for (int i = lane; i < deg; i += 64) {
      float t = as[srcs[beg + i]] + adv;
      t = (t > 0.f) ? t : NEG_SLOPE * t;
      m = fmaxf(m, t);
    }
#pragma unroll
    for (int o = 32; o; o >>= 1) m = fmaxf(m, __shfl_xor(m, o));
    float ssum = 0.f;
    for (int i = lane; i < deg; i += 64) {
      float t = as[srcs[beg + i]] + adv;
      t = (t > 0.f) ? t : NEG_SLOPE * t;
      ssum += __expf(t - m);
    }
#pragma unroll
    for (int o = 32; o; o >>= 1) ssum += __shfl_xor(ssum, o);
    float inv = 1.f / (ssum + 1e-16f);
    for (int chunk = 0; chunk < deg; chunk += 64) {
      int i = chunk + lane;
      float w = 0.f; int s = 0;
      if (i < deg) {
        s = srcs[beg + i];
        float t = as[s] + adv;
        t = (t > 0.f) ? t : NEG_SLOPE * t;
        w = __expf(t - m) * inv;
      }
      int cl = min(64, deg - chunk);
      for (int j = 0; j < cl; j++) {
        float wj = __shfl(w, j);
        int sj = __shfl(s, j);
        if (lane < C2 / 2) {
          unsigned int u = zrow[(size_t)sj * (C2 / 2) + lane];
          acc0 += wj * bf_lo(u);
          acc1 += wj * bf_hi(u);
        }
      }
    }
  }

  if (lane < C2 / 2) {
    float v0 = fmaxf(acc0 + b2[2 * lane], 0.f);
    float v1 = fmaxf(acc1 + b2[2 * lane + 1], 0.f);
    int g = batch[n];
    atomicMax(&pool[g * C2 + 2 * lane], __float_as_uint(v0));
    atomicMax(&pool[g * C2 + 2 * lane + 1], __float_as_uint(v1));
  }
}

/* ---------------- head: out = relu(pool @ Wg + bg) ---------------- */

__global__ __launch_bounds__(128) void k_head(const float* __restrict__ pool,
                                              const float* __restrict__ Wg,
                                              const float* __restrict__ bg,
                                              float* __restrict__ out) {
  __shared__ float row[C2];
  int g = blockIdx.x;
  if (threadIdx.x < C2) row[threadIdx.x] = pool[g * C2 + threadIdx.x];
  __syncthreads();
  int c = threadIdx.x;
  if (c < C2) {
    float acc = bg[c];
    for (int k = 0; k < C2; k++) acc += row[k] * Wg[k * C2 + c];
    out[g * C2 + c] = fmaxf(acc, 0.f);
  }
}

/* ---------------- launch ---------------- */

extern "C" void kernel_launch(void* const* d_in, const int* in_sizes, int n_in,
                              void* d_out, int out_size, void* d_ws, size_t ws_size,
                              hipStream_t stream) {
  const float* x      = (const float*)d_in[0];
  const int*   ei     = (const int*)d_in[1];
  const int*   batch  = (const int*)d_in[2];
  const float* W1     = (const float*)d_in[4];
  const float* a_src1 = (const float*)d_in[5];
  const float* a_dst1 = (const float*)d_in[6];
  const float* b1     = (const float*)d_in[7];
  const float* W2     = (const float*)d_in[8];
  const float* a_src2 = (const float*)d_in[9];
  const float* a_dst2 = (const float*)d_in[10];
  const float* b2     = (const float*)d_in[11];
  const float* Wg     = (const float*)d_in[12];
  const float* bg     = (const float*)d_in[13];
  float* out = (float*)d_out;

  char* w = (char*)d_ws;
  size_t off = 0;
  auto alloc = [&](size_t bytes) -> void* {
    void* p = w + off;
    off += (bytes + 255) & ~(size_t)255;
    return p;
  };

  float* xagg = (float*)alloc((size_t)N_NODES * F1 * 4);   /* 62.4 MB */
  float* ha   = (float*)alloc((size_t)N_NODES * F1 * 4);   /* 62.4 MB */
  float* asb  = (float*)alloc((size_t)H1 * N_NODES * 4);
  float* adb  = (float*)alloc((size_t)H1 * N_NODES * 4);
  float* Vs   = (float*)alloc((size_t)H1 * C1 * 4);
  float* Vd   = (float*)alloc((size_t)H1 * C1 * 4);
  int* cnt    = (int*)alloc((size_t)N_NODES * 4);
  int* cursor = (int*)alloc((size_t)N_NODES * 4);
  int* offs   = (int*)alloc((size_t)(N_NODES + 1) * 4);
  int* srcs   = (int*)alloc((size_t)E_TOT * 4);

  /* layer-2 buffers alias dead xagg region (xagg unused after k_bgemm) */
  float* z2           = xagg;
  float* as2          = z2 + (size_t)N_NODES * C2;
  float* ad2          = as2 + N_NODES;
  unsigned short* z2b = (unsigned short*)(ad2 + N_NODES);
  unsigned int* pool  = (unsigned int*)(z2b + (size_t)N_NODES * C2);

  hipMemsetAsync(cnt, 0, (size_t)N_NODES * 4, stream);
  hipMemsetAsync(cursor, 0, (size_t)N_NODES * 4, stream);

  k_count<<<(E_TOT + 255) / 256, 256, 0, stream>>>(ei, cnt);
  k_scan<<<1, 1024, 0, stream>>>(cnt, offs, N_NODES);
  k_scatter<<<(E_TOT + 255) / 256, 256, 0, stream>>>(ei, offs, cursor, srcs);

  k_vmake<<<7, 256, 0, stream>>>(W1, a_src1, a_dst1, Vs, Vd);
  k_alpha1x<<<(N_NODES * H1 + 255) / 256, 256, 0, stream>>>(x, Vs, Vd, asb, adb);
  k_agg<<<(N_NODES + 3) / 4, 256, 0, stream>>>(x, asb, adb, offs, srcs, xagg);
  k_bgemm<<<dim3(2, (N_NODES + 63) / 64, H1), 256, 0, stream>>>(xagg, W1, b1, ha);

  /* GEMM2: z2 = ha @ W2  (z2 aliases dead xagg) */
  k_gemm<<<dim3((C2 + 63) / 64, (N_NODES + 63) / 64), 256, 0, stream>>>(ha, W2, z2,
                                                                        N_NODES, C2, F1);
  k_alpha2<<<(N_NODES + 255) / 256, 256, 0, stream>>>(z2, a_src2, a_dst2, as2, ad2);
  k_tobf16<<<(N_NODES * C2 / 2 + 255) / 256, 256, 0, stream>>>(z2, z2b);

  hipMemsetAsync(pool, 0, (size_t)N_GRAPHS * C2 * 4, stream);
  k_gat2b<<<(N_NODES + 3) / 4, 256, 0, stream>>>(z2b, as2, ad2, offs, srcs, b2, batch, pool);
  k_head<<<N_GRAPHS, 128, 0, stream>>>((const float*)pool, Wg, bg, out);
}

// Round 5
// 490.381 us; speedup vs baseline: 5.8024x; 1.0164x over previous
//
#include <hip/hip_runtime.h>
#include <hip/hip_bf16.h>

#define N_NODES  20000
#define N_EDGES  320000
#define E_TOT    (N_EDGES + N_NODES)   /* 340000 incl. self loops */
#define N_GRAPHS 512
#define H1 10
#define C1 78
#define F1 780                          /* H1*C1 */
#define C2 100
#define NEG_SLOPE 0.2f
#define KSPLIT 5
#define KCHUNK 156                      /* 780 / 5 */

__device__ __forceinline__ float bf_lo(unsigned int u) { return __uint_as_float(u << 16); }
__device__ __forceinline__ float bf_hi(unsigned int u) { return __uint_as_float(u & 0xFFFF0000u); }

/* ---------------- CSR build (by destination) ---------------- */

__global__ void k_count(const int* __restrict__ ei, int* __restrict__ cnt) {
  int e = blockIdx.x * blockDim.x + threadIdx.x;
  if (e >= E_TOT) return;
  int dst = (e < N_EDGES) ? ei[N_EDGES + e] : (e - N_EDGES);
  atomicAdd(&cnt[dst], 1);
}

__global__ __launch_bounds__(1024) void k_scan(const int* __restrict__ cnt,
                                               int* __restrict__ offs, int n) {
  const int PER = 20;
  int t = threadIdx.x;
  int lane = t & 63, wv = t >> 6;
  int base = t * PER;
  int loc[PER];
  int run = 0;
#pragma unroll
  for (int k = 0; k < PER; k++) {
    int idx = base + k;
    int v = (idx < n) ? cnt[idx] : 0;
    run += v;
    loc[k] = run;
  }
  int total = run;
  int sc = total;
#pragma unroll
  for (int o = 1; o < 64; o <<= 1) {
    int u = __shfl_up(sc, o);
    if (lane >= o) sc += u;
  }
  __shared__ int ws[16];
  if (lane == 63) ws[wv] = sc;
  __syncthreads();
  if (t == 0) {
    int r = 0;
#pragma unroll
    for (int i = 0; i < 16; i++) { int v = ws[i]; ws[i] = r; r += v; }
  }
  __syncthreads();
  int excl = ws[wv] + sc - total;
#pragma unroll
  for (int k = 0; k < PER; k++) {
    int idx = base + k;
    if (idx < n) offs[idx + 1] = excl + loc[k];
  }
  if (t == 0) offs[0] = 0;
}

__global__ void k_scatter(const int* __restrict__ ei, const int* __restrict__ offs,
                          int* __restrict__ cursor, int* __restrict__ srcs) {
  int e = blockIdx.x * blockDim.x + threadIdx.x;
  if (e >= E_TOT) return;
  int src, dst;
  if (e < N_EDGES) { src = ei[e]; dst = ei[N_EDGES + e]; }
  else             { src = dst = e - N_EDGES; }
  int pos = offs[dst] + atomicAdd(&cursor[dst], 1);
  srcs[pos] = src;
}

/* ---------------- Vs[h][k] = sum_c W1[k, h*C1+c] * a_src[h,c]  (and Vd) ---------------- */

__global__ void k_vmake(const float* __restrict__ W1, const float* __restrict__ a_src,
                        const float* __restrict__ a_dst, float* __restrict__ Vs,
                        float* __restrict__ Vd) {
  int t = blockIdx.x * blockDim.x + threadIdx.x;
  if (t >= 2 * H1 * C1) return;
  int which = (t >= H1 * C1) ? 1 : 0;
  int r = t - which * H1 * C1;
  int h = r / C1, k = r - h * C1;
  const float* a = which ? a_dst : a_src;
  float s = 0.f;
  for (int c = 0; c < C1; c++) s += W1[(size_t)k * F1 + h * C1 + c] * a[h * C1 + c];
  (which ? Vd : Vs)[h * C1 + k] = s;
}

/* ---------------- layer-1 logits: asb[h][n] = x[n] . Vs[h] ---------------- */

__global__ __launch_bounds__(256) void k_alpha1x(const float* __restrict__ x,
                                                 const float* __restrict__ Vs,
                                                 const float* __restrict__ Vd,
                                                 float* __restrict__ asb,
                                                 float* __restrict__ adb) {
  __shared__ float sVs[H1 * C1], sVd[H1 * C1];
  for (int i = threadIdx.x; i < H1 * C1; i += 256) { sVs[i] = Vs[i]; sVd[i] = Vd[i]; }
  __syncthreads();
  int t = blockIdx.x * 256 + threadIdx.x;
  if (t >= N_NODES * H1) return;
  int n = t / H1, h = t - n * H1;
  const float* row = x + (size_t)n * C1;
  float s0 = 0.f, s1 = 0.f;
#pragma unroll 2
  for (int c = 0; c < C1; c++) {
    float v = row[c];
    s0 += v * sVs[h * C1 + c];
    s1 += v * sVd[h * C1 + c];
  }
  asb[(size_t)h * N_NODES + n] = s0;
  adb[(size_t)h * N_NODES + n] = s1;
}

/* ---------------- layer-1 softmax + x-aggregation: wave per dst, ALL heads -----------
   xagg[n][h*C1+c] = sum_e alpha[e,h] * x[src_e][c]                                     */

__global__ __launch_bounds__(256) void k_agg(const float* __restrict__ x,
                                             const float* __restrict__ asb,
                                             const float* __restrict__ adb,
                                             const int* __restrict__ offs,
                                             const int* __restrict__ srcs,
                                             float* __restrict__ xagg) {
  int wid = (blockIdx.x * 256 + threadIdx.x) >> 6;
  int lane = threadIdx.x & 63;
  if (wid >= N_NODES) return;
  int n = wid;
  int beg = offs[n], deg = offs[n + 1] - beg;

  float acc[H1][2] = {};

  if (deg <= 64) {
    bool act = lane < deg;
    int s = act ? srcs[beg + lane] : 0;
    float p[H1];
#pragma unroll
    for (int h = 0; h < H1; h++) {
      float ev = -INFINITY;
      if (act) {
        float t = asb[(size_t)h * N_NODES + s] + adb[(size_t)h * N_NODES + n];
        ev = (t > 0.f) ? t : NEG_SLOPE * t;
      }
      float m = ev;
#pragma unroll
      for (int o = 32; o; o >>= 1) m = fmaxf(m, __shfl_xor(m, o));
      float pv = act ? __expf(ev - m) : 0.f;
      float ss = pv;
#pragma unroll
      for (int o = 32; o; o >>= 1) ss += __shfl_xor(ss, o);
      p[h] = pv / (ss + 1e-16f);
    }
    int j = 0;
    for (; j + 1 < deg; j += 2) {
      int s0 = __shfl(s, j), s1 = __shfl(s, j + 1);
      float2 xv0 = make_float2(0.f, 0.f), xv1 = make_float2(0.f, 0.f);
      if (lane < C1 / 2) {
        xv0 = *(const float2*)(x + (size_t)s0 * C1 + 2 * lane);
        xv1 = *(const float2*)(x + (size_t)s1 * C1 + 2 * lane);
      }
#pragma unroll
      for (int h = 0; h < H1; h++) {
        float w0 = __shfl(p[h], j), w1 = __shfl(p[h], j + 1);
        acc[h][0] += w0 * xv0.x + w1 * xv1.x;
        acc[h][1] += w0 * xv0.y + w1 * xv1.y;
      }
    }
    if (j < deg) {
      int s0 = __shfl(s, j);
      float2 xv0 = make_float2(0.f, 0.f);
      if (lane < C1 / 2) xv0 = *(const float2*)(x + (size_t)s0 * C1 + 2 * lane);
#pragma unroll
      for (int h = 0; h < H1; h++) {
        float w0 = __shfl(p[h], j);
        acc[h][0] += w0 * xv0.x;
        acc[h][1] += w0 * xv0.y;
      }
    }
  } else {
    float m[H1], ssum[H1];
#pragma unroll
    for (int h = 0; h < H1; h++) { m[h] = -INFINITY; ssum[h] = 0.f; }
    for (int i = lane; i < deg; i += 64) {
      int s = srcs[beg + i];
#pragma unroll
      for (int h = 0; h < H1; h++) {
        float t = asb[(size_t)h * N_NODES + s] + adb[(size_t)h * N_NODES + n];
        t = (t > 0.f) ? t : NEG_SLOPE * t;
        m[h] = fmaxf(m[h], t);
      }
    }
#pragma unroll
    for (int h = 0; h < H1; h++)
#pragma unroll
      for (int o = 32; o; o >>= 1) m[h] = fmaxf(m[h], __shfl_xor(m[h], o));
    for (int i = lane; i < deg; i += 64) {
      int s = srcs[beg + i];
#pragma unroll
      for (int h = 0; h < H1; h++) {
        float t = asb[(size_t)h * N_NODES + s] + adb[(size_t)h * N_NODES + n];
        t = (t > 0.f) ? t : NEG_SLOPE * t;
        ssum[h] += __expf(t - m[h]);
      }
    }
#pragma unroll
    for (int h = 0; h < H1; h++) {
#pragma unroll
      for (int o = 32; o; o >>= 1) ssum[h] += __shfl_xor(ssum[h], o);
      ssum[h] = 1.f / (ssum[h] + 1e-16f);
    }
    for (int chunk = 0; chunk < deg; chunk += 64) {
      int i = chunk + lane;
      bool act = i < deg;
      int s = act ? srcs[beg + i] : 0;
      float p[H1];
#pragma unroll
      for (int h = 0; h < H1; h++) {
        float pv = 0.f;
        if (act) {
          float t = asb[(size_t)h * N_NODES + s] + adb[(size_t)h * N_NODES + n];
          t = (t > 0.f) ? t : NEG_SLOPE * t;
          pv = __expf(t - m[h]) * ssum[h];
        }
        p[h] = pv;
      }
      int cl = min(64, deg - chunk);
      for (int j = 0; j < cl; j++) {
        int sj = __shfl(s, j);
        float2 xv = make_float2(0.f, 0.f);
        if (lane < C1 / 2) xv = *(const float2*)(x + (size_t)sj * C1 + 2 * lane);
#pragma unroll
        for (int h = 0; h < H1; h++) {
          float wj = __shfl(p[h], j);
          acc[h][0] += wj * xv.x;
          acc[h][1] += wj * xv.y;
        }
      }
    }
  }

  if (lane < C1 / 2) {
#pragma unroll
    for (int h = 0; h < H1; h++)
      *(float2*)(xagg + (size_t)n * F1 + h * C1 + 2 * lane) =
          make_float2(acc[h][0], acc[h][1]);
  }
}

/* ---------------- block-diag GEMM, grid (2, mblocks, H1), padded As --------
   ha[m, h*C1+col] = ELU(sum_k xagg[m, h*C1+k] * W1[k, h*C1+col] + b1[h*C1+col])        */

__global__ __launch_bounds__(256) void k_bgemm(const float* __restrict__ A,
                                               const float* __restrict__ W1,
                                               const float* __restrict__ b1,
                                               float* __restrict__ ha) {
  __shared__ float As[16][68];
  __shared__ float Bs[16][64];
  int h = blockIdx.z;
  int tid = threadIdx.x;
  int tx = tid & 15, ty = tid >> 4;
  int m0 = blockIdx.y * 64, n0 = blockIdx.x * 64;
  float acc[4][4] = {};
  for (int k0 = 0; k0 < C1; k0 += 16) {
#pragma unroll
    for (int i = 0; i < 4; i++) {
      int li = tid * 4 + i;
      int r = li >> 4, c = li & 15;
      float v = 0.f;
      if (m0 + r < N_NODES && k0 + c < C1) v = A[(size_t)(m0 + r) * F1 + h * C1 + k0 + c];
      As[c][r] = v;
    }
#pragma unroll
    for (int i = 0; i < 4; i++) {
      int li = tid * 4 + i;
      int kk = li >> 6, j = li & 63;
      float v = 0.f;
      if (k0 + kk < C1 && n0 + j < C1) v = W1[(size_t)(k0 + kk) * F1 + h * C1 + n0 + j];
      Bs[kk][j] = v;
    }
    __syncthreads();
#pragma unroll
    for (int kk = 0; kk < 16; kk++) {
      float a[4], b[4];
#pragma unroll
      for (int i = 0; i < 4; i++) a[i] = As[kk][ty * 4 + i];
#pragma unroll
      for (int i = 0; i < 4; i++) b[i] = Bs[kk][tx * 4 + i];
#pragma unroll
      for (int i = 0; i < 4; i++)
#pragma unroll
        for (int j = 0; j < 4; j++) acc[i][j] += a[i] * b[j];
    }
    __syncthreads();
  }
  for (int i = 0; i < 4; i++) {
    int m = m0 + ty * 4 + i;
    if (m >= N_NODES) continue;
    for (int j = 0; j < 4; j++) {
      int col = n0 + tx * 4 + j;
      if (col < C1) {
        float v = acc[i][j] + b1[h * C1 + col];
        v = (v > 0.f) ? v : (__expf(v) - 1.f);
        ha[(size_t)m * F1 + h * C1 + col] = v;
      }
    }
  }
}

/* ---------------- GEMM2 split-K: part[z][m][n] = ha[m, kc] @ W2[kc, n] ---------------- */

__global__ __launch_bounds__(256) void k_gemm2s(const float* __restrict__ A,
                                                const float* __restrict__ B,
                                                float* __restrict__ part) {
  __shared__ float As[16][68];
  __shared__ float Bs[16][64];
  int tid = threadIdx.x;
  int tx = tid & 15, ty = tid >> 4;
  int m0 = blockIdx.y * 64, n0 = blockIdx.x * 64;
  int kc0 = blockIdx.z * KCHUNK, kend = kc0 + KCHUNK;
  float acc[4][4] = {};
  for (int k0 = kc0; k0 < kend; k0 += 16) {
#pragma unroll
    for (int i = 0; i < 4; i++) {
      int li = tid * 4 + i;
      int r = li >> 4, c = li & 15;
      float v = 0.f;
      if (m0 + r < N_NODES && k0 + c < kend) v = A[(size_t)(m0 + r) * F1 + k0 + c];
      As[c][r] = v;
    }
#pragma unroll
    for (int i = 0; i < 4; i++) {
      int li = tid * 4 + i;
      int kk = li >> 6, j = li & 63;
      float v = 0.f;
      if (k0 + kk < kend && n0 + j < C2) v = B[(size_t)(k0 + kk) * C2 + n0 + j];
      Bs[kk][j] = v;
    }
    __syncthreads();
#pragma unroll
    for (int kk = 0; kk < 16; kk++) {
      float a[4], b[4];
#pragma unroll
      for (int i = 0; i < 4; i++) a[i] = As[kk][ty * 4 + i];
#pragma unroll
      for (int i = 0; i < 4; i++) b[i] = Bs[kk][tx * 4 + i];
#pragma unroll
      for (int i = 0; i < 4; i++)
#pragma unroll
        for (int j = 0; j < 4; j++) acc[i][j] += a[i] * b[j];
    }
    __syncthreads();
  }
  float* P = part + (size_t)blockIdx.z * N_NODES * C2;
  for (int i = 0; i < 4; i++) {
    int m = m0 + ty * 4 + i;
    if (m >= N_NODES) continue;
    for (int j = 0; j < 4; j++) {
      int n = n0 + tx * 4 + j;
      if (n < C2) P[(size_t)m * C2 + n] = acc[i][j];
    }
  }
}

/* ---------------- reduce partials -> z2 (fp32) + z2b (bf16) ---------------- */

__global__ void k_reduce(const float* __restrict__ part, float* __restrict__ z2,
                         unsigned short* __restrict__ z2b) {
  int t = blockIdx.x * blockDim.x + threadIdx.x;
  if (t >= N_NODES * C2 / 2) return;
  float2 s = make_float2(0.f, 0.f);
#pragma unroll
  for (int c = 0; c < KSPLIT; c++) {
    float2 v = ((const float2*)(part + (size_t)c * N_NODES * C2))[t];
    s.x += v.x; s.y += v.y;
  }
  ((float2*)z2)[t] = s;
  ushort2 o;
  o.x = (unsigned short)(__float_as_uint(s.x) >> 16);
  o.y = (unsigned short)(__float_as_uint(s.y) >> 16);
  ((ushort2*)z2b)[t] = o;
}

/* ---------------- layer-2 logits ---------------- */

__global__ void k_alpha2(const float* __restrict__ z2, const float* __restrict__ a_src,
                         const float* __restrict__ a_dst, float* __restrict__ as,
                         float* __restrict__ ad) {
  int n = blockIdx.x * blockDim.x + threadIdx.x;
  if (n >= N_NODES) return;
  const float* row = z2 + (size_t)n * C2;
  float s0 = 0.f, s1 = 0.f;
  for (int c = 0; c < C2; c++) { float v = row[c]; s0 += v * a_src[c]; s1 += v * a_dst[c]; }
  as[n] = s0; ad[n] = s1;
}

/* ---------------- layer-2 GAT fused with bias+ReLU+graph-max-pool ---------------- */

__global__ __launch_bounds__(256) void k_gat2b(const unsigned short* __restrict__ z2b,
                                               const float* __restrict__ as,
                                               const float* __restrict__ ad,
                                               const int* __restrict__ offs,
                                               const int* __restrict__ srcs,
                                               const float* __restrict__ b2,
                                               const int* __restrict__ batch,
                                               unsigned int* __restrict__ pool) {
  int wid = (blockIdx.x * 256 + threadIdx.x) >> 6;
  int lane = threadIdx.x & 63;
  if (wid >= N_NODES) return;
  int n = wid;
  int beg = offs[n], deg = offs[n + 1] - beg;
  float adv = ad[n];
  const unsigned int* zrow = (const unsigned int*)z2b;

  float acc0 = 0.f, acc1 = 0.f;

  if (deg <= 64) {
    bool act = lane < deg;
    int s = act ? srcs[beg + lane] : 0;
    float e = -INFINITY;
    if (act) {
      float t = as[s] + adv;
      e = (t > 0.f) ? t : NEG_SLOPE * t;
    }
    float m = e;
#pragma unroll
    for (int o = 32; o; o >>= 1) m = fmaxf(m, __shfl_xor(m, o));
    float p = act ? __expf(e - m) : 0.f;
    float ssum = p;
#pragma unroll
    for (int o = 32; o; o >>= 1) ssum += __shfl_xor(ssum, o);
    p *= 1.f / (ssum + 1e-16f);
    int j = 0;
    for (; j + 1 < deg; j += 2) {
      int s0 = __shfl(s, j), s1 = __shfl(s, j + 1);
      float w0 = __shfl(p, j), w1 = __shfl(p, j + 1);
      if (lane < C2 / 2) {
        unsigned int u0 = zrow[(size_t)s0 * (C2 / 2) + lane];
        unsigned int u1 = zrow[(size_t)s1 * (C2 / 2) + lane];
        acc0 += w0 * bf_lo(u0) + w1 * bf_lo(u1);
        acc1 += w0 * bf_hi(u0) + w1 * bf_hi(u1);
      }
    }
    if (j < deg) {
      int s0 = __shfl(s, j);
      float w0 = __shfl(p, j);
      if (lane < C2 / 2) {
        unsigned int u0 = zrow[(size_t)s0 * (C2 / 2) + lane];
        acc0 += w0 * bf_lo(u0);
        acc1 += w0 * bf_hi(u0);
      }
    }
  } else {
    float m = -INFINITY;
    for (int i = lane; i < deg; i += 64) {
      float t = as[srcs[beg + i]] + adv;
      t = (t > 0.f) ? t : NEG_SLOPE * t;
      m = fmaxf(m, t);
    }
#pragma unroll
    for (int o = 32; o; o >>= 1) m = fmaxf(m, __shfl_xor(m, o));
    float ssum = 0.f;
    for (int i = lane; i < deg; i += 64) {
      float t = as[srcs[beg + i]] + adv;
      t = (t > 0.f) ? t : NEG_SLOPE * t;
      ssum += __expf(t - m);
    }
#pragma unroll
    for (int o = 32; o; o >>= 1) ssum += __shfl_xor(ssum, o);
    float inv = 1.f / (ssum + 1e-16f);
    for (int chunk = 0; chunk < deg; chunk += 64) {
      int i = chunk + lane;
      float w = 0.f; int s = 0;
      if (i < deg) {
        s = srcs[beg + i];
        float t = as[s] + adv;
        t = (t > 0.f) ? t : NEG_SLOPE * t;
        w = __expf(t - m) * inv;
      }
      int cl = min(64, deg - chunk);
      for (int j = 0; j < cl; j++) {
        float wj = __shfl(w, j);
        int sj = __shfl(s, j);
        if (lane < C2 / 2) {
          unsigned int u = zrow[(size_t)sj * (C2 / 2) + lane];
          acc0 += wj * bf_lo(u);
          acc1 += wj * bf_hi(u);
        }
      }
    }
  }

  if (lane < C2 / 2) {
    float v0 = fmaxf(acc0 + b2[2 * lane], 0.f);
    float v1 = fmaxf(acc1 + b2[2 * lane + 1], 0.f);
    int g = batch[n];
    atomicMax(&pool[g * C2 + 2 * lane], __float_as_uint(v0));
    atomicMax(&pool[g * C2 + 2 * lane + 1], __float_as_uint(v1));
  }
}

/* ---------------- head: out = relu(pool @ Wg + bg) ---------------- */

__global__ __launch_bounds__(128) void k_head(const float* __restrict__ pool,
                                              const float* __restrict__ Wg,
                                              const float* __restrict__ bg,
                                              float* __restrict__ out) {
  __shared__ float row[C2];
  int g = blockIdx.x;
  if (threadIdx.x < C2) row[threadIdx.x] = pool[g * C2 + threadIdx.x];
  __syncthreads();
  int c = threadIdx.x;
  if (c < C2) {
    float acc = bg[c];
    for (int k = 0; k < C2; k++) acc += row[k] * Wg[k * C2 + c];
    out[g * C2 + c] = fmaxf(acc, 0.f);
  }
}

/* ---------------- launch ---------------- */

extern "C" void kernel_launch(void* const* d_in, const int* in_sizes, int n_in,
                              void* d_out, int out_size, void* d_ws, size_t ws_size,
                              hipStream_t stream) {
  const float* x      = (const float*)d_in[0];
  const int*   ei     = (const int*)d_in[1];
  const int*   batch  = (const int*)d_in[2];
  const float* W1     = (const float*)d_in[4];
  const float* a_src1 = (const float*)d_in[5];
  const float* a_dst1 = (const float*)d_in[6];
  const float* b1     = (const float*)d_in[7];
  const float* W2     = (const float*)d_in[8];
  const float* a_src2 = (const float*)d_in[9];
  const float* a_dst2 = (const float*)d_in[10];
  const float* b2     = (const float*)d_in[11];
  const float* Wg     = (const float*)d_in[12];
  const float* bg     = (const float*)d_in[13];
  float* out = (float*)d_out;

  char* w = (char*)d_ws;
  size_t off = 0;
  auto alloc = [&](size_t bytes) -> void* {
    void* p = w + off;
    off += (bytes + 255) & ~(size_t)255;
    return p;
  };

  float* xagg = (float*)alloc((size_t)N_NODES * F1 * 4);   /* 62.4 MB */
  float* ha   = (float*)alloc((size_t)N_NODES * F1 * 4);   /* 62.4 MB */
  float* asb  = (float*)alloc((size_t)H1 * N_NODES * 4);
  float* adb  = (float*)alloc((size_t)H1 * N_NODES * 4);
  float* Vs   = (float*)alloc((size_t)H1 * C1 * 4);
  float* Vd   = (float*)alloc((size_t)H1 * C1 * 4);
  int* cnt    = (int*)alloc((size_t)N_NODES * 4);
  int* cursor = (int*)alloc((size_t)N_NODES * 4);
  int* offs   = (int*)alloc((size_t)(N_NODES + 1) * 4);
  int* srcs   = (int*)alloc((size_t)E_TOT * 4);

  /* layer-2 buffers alias dead xagg region (xagg unused after k_bgemm):
     z2(8MB) as2 ad2 z2b(4MB) pool part[5](40MB) = ~52.5MB < 62.4MB */
  float* z2           = xagg;
  float* as2          = z2 + (size_t)N_NODES * C2;
  float* ad2          = as2 + N_NODES;
  unsigned short* z2b = (unsigned short*)(ad2 + N_NODES);
  unsigned int* pool  = (unsigned int*)(z2b + (size_t)N_NODES * C2);
  float* part         = (float*)(pool + (size_t)N_GRAPHS * C2);

  hipMemsetAsync(cnt, 0, (size_t)N_NODES * 4, stream);
  hipMemsetAsync(cursor, 0, (size_t)N_NODES * 4, stream);

  k_count<<<(E_TOT + 255) / 256, 256, 0, stream>>>(ei, cnt);
  k_scan<<<1, 1024, 0, stream>>>(cnt, offs, N_NODES);
  k_scatter<<<(E_TOT + 255) / 256, 256, 0, stream>>>(ei, offs, cursor, srcs);

  k_vmake<<<7, 256, 0, stream>>>(W1, a_src1, a_dst1, Vs, Vd);
  k_alpha1x<<<(N_NODES * H1 + 255) / 256, 256, 0, stream>>>(x, Vs, Vd, asb, adb);
  k_agg<<<(N_NODES + 3) / 4, 256, 0, stream>>>(x, asb, adb, offs, srcs, xagg);
  k_bgemm<<<dim3(2, (N_NODES + 63) / 64, H1), 256, 0, stream>>>(xagg, W1, b1, ha);

  /* GEMM2 split-K: part[z] = ha @ W2 chunks; reduce -> z2 (fp32) + z2b (bf16) */
  k_gemm2s<<<dim3(2, (N_NODES + 63) / 64, KSPLIT), 256, 0, stream>>>(ha, W2, part);
  k_reduce<<<(N_NODES * C2 / 2 + 255) / 256, 256, 0, stream>>>(part, z2, z2b);
  k_alpha2<<<(N_NODES + 255) / 256, 256, 0, stream>>>(z2, a_src2, a_dst2, as2, ad2);

  hipMemsetAsync(pool, 0, (size_t)N_GRAPHS * C2 * 4, stream);
  k_gat2b<<<(N_NODES + 3) / 4, 256, 0, stream>>>(z2b, as2, ad2, offs, srcs, b2, batch, pool);
  k_head<<<N_GRAPHS, 128, 0, stream>>>((const float*)pool, Wg, bg, out);
}

// Round 6
// 330.317 us; speedup vs baseline: 8.6142x; 1.4846x over previous
//
#include <hip/hip_runtime.h>
#include <hip/hip_bf16.h>

#define N_NODES  20000
#define N_EDGES  320000
#define E_TOT    (N_EDGES + N_NODES)   /* 340000 incl. self loops */
#define N_GRAPHS 512
#define H1 10
#define C1 78
#define F1 780                          /* H1*C1 */
#define C2 100
#define NEG_SLOPE 0.2f
#define KSPLIT 5
#define K1PAD 96                        /* layer-1 K (78) padded to 3x32 */
#define K2PAD 800                       /* layer-2 K (780) padded to 25x32 */
#define K2CHUNK 160                     /* 800 / KSPLIT, = 5 x 32 */
#define AP1 104                         /* LDS row stride (bf16) for bgemm: 2-way banks */
#define AP2 40                          /* LDS row stride for gemm2 */

typedef short bf16x8 __attribute__((ext_vector_type(8)));
typedef float f32x4 __attribute__((ext_vector_type(4)));
typedef unsigned short ushort_t;

__device__ __forceinline__ float bf_lo(unsigned int u) { return __uint_as_float(u << 16); }
__device__ __forceinline__ float bf_hi(unsigned int u) { return __uint_as_float(u & 0xFFFF0000u); }
__device__ __forceinline__ ushort_t f2b(float v) {
  __hip_bfloat16 b = __float2bfloat16(v);   /* RNE */
  return *reinterpret_cast<ushort_t*>(&b);
}

/* ---------------- CSR build (by destination) ---------------- */

__global__ void k_count(const int* __restrict__ ei, int* __restrict__ cnt) {
  int e = blockIdx.x * blockDim.x + threadIdx.x;
  if (e >= E_TOT) return;
  int dst = (e < N_EDGES) ? ei[N_EDGES + e] : (e - N_EDGES);
  atomicAdd(&cnt[dst], 1);
}

__global__ __launch_bounds__(1024) void k_scan(const int* __restrict__ cnt,
                                               int* __restrict__ offs, int n) {
  const int PER = 20;
  int t = threadIdx.x;
  int lane = t & 63, wv = t >> 6;
  int base = t * PER;
  int loc[PER];
  int run = 0;
#pragma unroll
  for (int k = 0; k < PER; k++) {
    int idx = base + k;
    int v = (idx < n) ? cnt[idx] : 0;
    run += v;
    loc[k] = run;
  }
  int total = run;
  int sc = total;
#pragma unroll
  for (int o = 1; o < 64; o <<= 1) {
    int u = __shfl_up(sc, o);
    if (lane >= o) sc += u;
  }
  __shared__ int ws[16];
  if (lane == 63) ws[wv] = sc;
  __syncthreads();
  if (t == 0) {
    int r = 0;
#pragma unroll
    for (int i = 0; i < 16; i++) { int v = ws[i]; ws[i] = r; r += v; }
  }
  __syncthreads();
  int excl = ws[wv] + sc - total;
#pragma unroll
  for (int k = 0; k < PER; k++) {
    int idx = base + k;
    if (idx < n) offs[idx + 1] = excl + loc[k];
  }
  if (t == 0) offs[0] = 0;
}

__global__ void k_scatter(const int* __restrict__ ei, const int* __restrict__ offs,
                          int* __restrict__ cursor, int* __restrict__ srcs) {
  int e = blockIdx.x * blockDim.x + threadIdx.x;
  if (e >= E_TOT) return;
  int src, dst;
  if (e < N_EDGES) { src = ei[e]; dst = ei[N_EDGES + e]; }
  else             { src = dst = e - N_EDGES; }
  int pos = offs[dst] + atomicAdd(&cursor[dst], 1);
  srcs[pos] = src;
}

/* ---------------- weight prep: transposed, padded, bf16 ---------------- */

__global__ void k_vmake(const float* __restrict__ W1, const float* __restrict__ a_src,
                        const float* __restrict__ a_dst, float* __restrict__ Vs,
                        float* __restrict__ Vd) {
  int t = blockIdx.x * blockDim.x + threadIdx.x;
  if (t >= 2 * H1 * C1) return;
  int which = (t >= H1 * C1) ? 1 : 0;
  int r = t - which * H1 * C1;
  int h = r / C1, k = r - h * C1;
  const float* a = which ? a_dst : a_src;
  float s = 0.f;
  for (int c = 0; c < C1; c++) s += W1[(size_t)k * F1 + h * C1 + c] * a[h * C1 + c];
  (which ? Vd : Vs)[h * C1 + k] = s;
}

/* W1t[h][c(80)][k(96)] = bf16(W1[k, h*C1+c]), zero-padded */
__global__ void k_prepW1t(const float* __restrict__ W1, ushort_t* __restrict__ W1t) {
  int t = blockIdx.x * blockDim.x + threadIdx.x;
  if (t >= H1 * 80 * K1PAD) return;
  int h = t / (80 * K1PAD);
  int rem = t - h * 80 * K1PAD;
  int c = rem / K1PAD, k = rem - c * K1PAD;
  float v = (c < C1 && k < C1) ? W1[(size_t)k * F1 + h * C1 + c] : 0.f;
  W1t[t] = f2b(v);
}

/* W2t[c(112)][k(800)] = bf16(W2[k, c]), zero-padded */
__global__ void k_prepW2t(const float* __restrict__ W2, ushort_t* __restrict__ W2t) {
  int t = blockIdx.x * blockDim.x + threadIdx.x;
  if (t >= 112 * K2PAD) return;
  int c = t / K2PAD, k = t - c * K2PAD;
  float v = (c < C2 && k < F1) ? W2[(size_t)k * C2 + c] : 0.f;
  W2t[t] = f2b(v);
}

/* zero the K-pad columns of ha_b[n][780..800) */
__global__ void k_padha(ushort_t* __restrict__ hab) {
  int t = blockIdx.x * blockDim.x + threadIdx.x;
  if (t >= N_NODES * (K2PAD - F1)) return;
  int n = t / (K2PAD - F1), j = t - n * (K2PAD - F1);
  hab[(size_t)n * K2PAD + F1 + j] = 0;
}

/* ---------------- layer-1 logits: asb[h][n] = x[n] . Vs[h] ---------------- */

__global__ __launch_bounds__(256) void k_alpha1x(const float* __restrict__ x,
                                                 const float* __restrict__ Vs,
                                                 const float* __restrict__ Vd,
                                                 float* __restrict__ asb,
                                                 float* __restrict__ adb) {
  __shared__ float sVs[H1 * C1], sVd[H1 * C1];
  for (int i = threadIdx.x; i < H1 * C1; i += 256) { sVs[i] = Vs[i]; sVd[i] = Vd[i]; }
  __syncthreads();
  int t = blockIdx.x * 256 + threadIdx.x;
  if (t >= N_NODES * H1) return;
  int n = t / H1, h = t - n * H1;
  const float* row = x + (size_t)n * C1;
  float s0 = 0.f, s1 = 0.f;
#pragma unroll 2
  for (int c = 0; c < C1; c++) {
    float v = row[c];
    s0 += v * sVs[h * C1 + c];
    s1 += v * sVd[h * C1 + c];
  }
  asb[(size_t)h * N_NODES + n] = s0;
  adb[(size_t)h * N_NODES + n] = s1;
}

/* ---------------- layer-1 softmax + x-aggregation -> bf16 head-planes -----------
   xb[h][n][96] = bf16( sum_e alpha[e,h] * x[src_e][c] ), cols 78..95 zeroed        */

__global__ __launch_bounds__(256) void k_agg(const float* __restrict__ x,
                                             const float* __restrict__ asb,
                                             const float* __restrict__ adb,
                                             const int* __restrict__ offs,
                                             const int* __restrict__ srcs,
                                             ushort_t* __restrict__ xb) {
  int wid = (blockIdx.x * 256 + threadIdx.x) >> 6;
  int lane = threadIdx.x & 63;
  if (wid >= N_NODES) return;
  int n = wid;
  int beg = offs[n], deg = offs[n + 1] - beg;

  float acc[H1][2] = {};

  if (deg <= 64) {
    bool act = lane < deg;
    int s = act ? srcs[beg + lane] : 0;
    float p[H1];
#pragma unroll
    for (int h = 0; h < H1; h++) {
      float ev = -INFINITY;
      if (act) {
        float t = asb[(size_t)h * N_NODES + s] + adb[(size_t)h * N_NODES + n];
        ev = (t > 0.f) ? t : NEG_SLOPE * t;
      }
      float m = ev;
#pragma unroll
      for (int o = 32; o; o >>= 1) m = fmaxf(m, __shfl_xor(m, o));
      float pv = act ? __expf(ev - m) : 0.f;
      float ss = pv;
#pragma unroll
      for (int o = 32; o; o >>= 1) ss += __shfl_xor(ss, o);
      p[h] = pv / (ss + 1e-16f);
    }
    int j = 0;
    for (; j + 1 < deg; j += 2) {
      int s0 = __shfl(s, j), s1 = __shfl(s, j + 1);
      float2 xv0 = make_float2(0.f, 0.f), xv1 = make_float2(0.f, 0.f);
      if (lane < C1 / 2) {
        xv0 = *(const float2*)(x + (size_t)s0 * C1 + 2 * lane);
        xv1 = *(const float2*)(x + (size_t)s1 * C1 + 2 * lane);
      }
#pragma unroll
      for (int h = 0; h < H1; h++) {
        float w0 = __shfl(p[h], j), w1 = __shfl(p[h], j + 1);
        acc[h][0] += w0 * xv0.x + w1 * xv1.x;
        acc[h][1] += w0 * xv0.y + w1 * xv1.y;
      }
    }
    if (j < deg) {
      int s0 = __shfl(s, j);
      float2 xv0 = make_float2(0.f, 0.f);
      if (lane < C1 / 2) xv0 = *(const float2*)(x + (size_t)s0 * C1 + 2 * lane);
#pragma unroll
      for (int h = 0; h < H1; h++) {
        float w0 = __shfl(p[h], j);
        acc[h][0] += w0 * xv0.x;
        acc[h][1] += w0 * xv0.y;
      }
    }
  } else {
    float m[H1], ssum[H1];
#pragma unroll
    for (int h = 0; h < H1; h++) { m[h] = -INFINITY; ssum[h] = 0.f; }
    for (int i = lane; i < deg; i += 64) {
      int s = srcs[beg + i];
#pragma unroll
      for (int h = 0; h < H1; h++) {
        float t = asb[(size_t)h * N_NODES + s] + adb[(size_t)h * N_NODES + n];
        t = (t > 0.f) ? t : NEG_SLOPE * t;
        m[h] = fmaxf(m[h], t);
      }
    }
#pragma unroll
    for (int h = 0; h < H1; h++)
#pragma unroll
      for (int o = 32; o; o >>= 1) m[h] = fmaxf(m[h], __shfl_xor(m[h], o));
    for (int i = lane; i < deg; i += 64) {
      int s = srcs[beg + i];
#pragma unroll
      for (int h = 0; h < H1; h++) {
        float t = asb[(size_t)h * N_NODES + s] + adb[(size_t)h * N_NODES + n];
        t = (t > 0.f) ? t : NEG_SLOPE * t;
        ssum[h] += __expf(t - m[h]);
      }
    }
#pragma unroll
    for (int h = 0; h < H1; h++) {
#pragma unroll
      for (int o = 32; o; o >>= 1) ssum[h] += __shfl_xor(ssum[h], o);
      ssum[h] = 1.f / (ssum[h] + 1e-16f);
    }
    for (int chunk = 0; chunk < deg; chunk += 64) {
      int i = chunk + lane;
      bool act = i < deg;
      int s = act ? srcs[beg + i] : 0;
      float p[H1];
#pragma unroll
      for (int h = 0; h < H1; h++) {
        float pv = 0.f;
        if (act) {
          float t = asb[(size_t)h * N_NODES + s] + adb[(size_t)h * N_NODES + n];
          t = (t > 0.f) ? t : NEG_SLOPE * t;
          pv = __expf(t - m[h]) * ssum[h];
        }
        p[h] = pv;
      }
      int cl = min(64, deg - chunk);
      for (int j = 0; j < cl; j++) {
        int sj = __shfl(s, j);
        float2 xv = make_float2(0.f, 0.f);
        if (lane < C1 / 2) xv = *(const float2*)(x + (size_t)sj * C1 + 2 * lane);
#pragma unroll
        for (int h = 0; h < H1; h++) {
          float wj = __shfl(p[h], j);
          acc[h][0] += wj * xv.x;
          acc[h][1] += wj * xv.y;
        }
      }
    }
  }

  if (lane < 48) {
    int colu = (lane < 39) ? 2 * lane : C1 + 2 * (lane - 39);   /* pad cols 78..95 */
#pragma unroll
    for (int h = 0; h < H1; h++) {
      ushort2 o;
      if (lane < 39) { o.x = f2b(acc[h][0]); o.y = f2b(acc[h][1]); }
      else           { o.x = 0; o.y = 0; }
      *(ushort2*)(xb + ((size_t)h * N_NODES + n) * K1PAD + colu) = o;
    }
  }
}

/* ---------------- layer-1 block-diag GEMM via MFMA --------------------------------
   ha_b[m][h*78+col] = bf16(ELU(xb[h][m][:] @ W1h + b1)); grid (313, H1), 4 waves    */

__global__ __launch_bounds__(256) void k_bgemm_m(const ushort_t* __restrict__ xb,
                                                 const ushort_t* __restrict__ W1t,
                                                 const float* __restrict__ b1,
                                                 ushort_t* __restrict__ hab) {
  __shared__ ushort_t sA[64 * AP1];
  __shared__ ushort_t sB[80 * AP1];
  int h = blockIdx.y;
  int m0 = blockIdx.x * 64;
  int tid = threadIdx.x;

  /* stage A: 64 rows x 12 x 16B chunks */
  for (int i = tid; i < 64 * 12; i += 256) {
    int r = i / 12, cx = i - r * 12;
    uint4 v = make_uint4(0, 0, 0, 0);
    int m = m0 + r;
    if (m < N_NODES) v = *(const uint4*)(xb + ((size_t)h * N_NODES + m) * K1PAD + cx * 8);
    *(uint4*)(sA + r * AP1 + cx * 8) = v;
  }
  /* stage B (whole per-head weight): 80 x 12 chunks */
  for (int i = tid; i < 80 * 12; i += 256) {
    int c = i / 12, cx = i - c * 12;
    uint4 v = *(const uint4*)(W1t + ((size_t)h * 80 + c) * K1PAD + cx * 8);
    *(uint4*)(sB + c * AP1 + cx * 8) = v;
  }
  __syncthreads();

  int w = tid >> 6, l = tid & 63;
  int rb = l & 15, g = l >> 4;
  f32x4 acc[5] = {};
  const ushort_t* pa = sA + (w * 16 + rb) * AP1 + g * 8;
#pragma unroll
  for (int k0 = 0; k0 < K1PAD; k0 += 32) {
    bf16x8 a = *(const bf16x8*)(pa + k0);
#pragma unroll
    for (int ct = 0; ct < 5; ct++) {
      bf16x8 b = *(const bf16x8*)(sB + (ct * 16 + rb) * AP1 + k0 + g * 8);
      acc[ct] = __builtin_amdgcn_mfma_f32_16x16x32_bf16(a, b, acc[ct], 0, 0, 0);
    }
  }

  int mrow = m0 + w * 16 + g * 4;
#pragma unroll
  for (int ct = 0; ct < 5; ct++) {
    int col = ct * 16 + rb;
    if (col >= C1) continue;
    float bias = b1[h * C1 + col];
#pragma unroll
    for (int r = 0; r < 4; r++) {
      int m = mrow + r;
      if (m >= N_NODES) continue;
      float v = acc[ct][r] + bias;
      v = (v > 0.f) ? v : (__expf(v) - 1.f);
      hab[(size_t)m * K2PAD + h * C1 + col] = f2b(v);
    }
  }
}

/* ---------------- layer-2 GEMM via MFMA, split-K: grid (313, KSPLIT) -------------
   part[z][m][col] = ha_b[m, kz..kz+160) @ W2[kz.., col]                            */

__global__ __launch_bounds__(256) void k_gemm2m(const ushort_t* __restrict__ hab,
                                                const ushort_t* __restrict__ W2t,
                                                float* __restrict__ part) {
  __shared__ ushort_t sA[64 * AP2];
  __shared__ ushort_t sB[112 * AP2];
  int m0 = blockIdx.x * 64;
  int kz = blockIdx.y * K2CHUNK;
  int tid = threadIdx.x;
  int w = tid >> 6, l = tid & 63;
  int rb = l & 15, g = l >> 4;
  f32x4 acc[7] = {};

  for (int ks = 0; ks < K2CHUNK; ks += 32) {
    int kbase = kz + ks;
    {
      int r = tid >> 2, cx = tid & 3;           /* 64 rows x 4 chunks = 256 */
      uint4 v = make_uint4(0, 0, 0, 0);
      int m = m0 + r;
      if (m < N_NODES) v = *(const uint4*)(hab + (size_t)m * K2PAD + kbase + cx * 8);
      *(uint4*)(sA + r * AP2 + cx * 8) = v;
    }
    for (int i = tid; i < 112 * 4; i += 256) {
      int c = i >> 2, cx = i & 3;
      uint4 v = *(const uint4*)(W2t + (size_t)c * K2PAD + kbase + cx * 8);
      *(uint4*)(sB + c * AP2 + cx * 8) = v;
    }
    __syncthreads();
    bf16x8 a = *(const bf16x8*)(sA + (w * 16 + rb) * AP2 + g * 8);
#pragma unroll
    for (int ct = 0; ct < 7; ct++) {
      bf16x8 b = *(const bf16x8*)(sB + (ct * 16 + rb) * AP2 + g * 8);
      acc[ct] = __builtin_amdgcn_mfma_f32_16x16x32_bf16(a, b, acc[ct], 0, 0, 0);
    }
    __syncthreads();
  }

  float* P = part + (size_t)blockIdx.y * N_NODES * C2;
  int mrow = m0 + w * 16 + g * 4;
#pragma unroll
  for (int ct = 0; ct < 7; ct++) {
    int col = ct * 16 + rb;
    if (col >= C2) continue;
#pragma unroll
    for (int r = 0; r < 4; r++) {
      int m = mrow + r;
      if (m < N_NODES) P[(size_t)m * C2 + col] = acc[ct][r];
    }
  }
}

/* ---------------- reduce partials -> z2 (fp32) + z2b (bf16) ---------------- */

__global__ void k_reduce(const float* __restrict__ part, float* __restrict__ z2,
                         ushort_t* __restrict__ z2b) {
  int t = blockIdx.x * blockDim.x + threadIdx.x;
  if (t >= N_NODES * C2 / 2) return;
  float2 s = make_float2(0.f, 0.f);
#pragma unroll
  for (int c = 0; c < KSPLIT; c++) {
    float2 v = ((const float2*)(part + (size_t)c * N_NODES * C2))[t];
    s.x += v.x; s.y += v.y;
  }
  ((float2*)z2)[t] = s;
  ushort2 o;
  o.x = f2b(s.x);
  o.y = f2b(s.y);
  ((ushort2*)z2b)[t] = o;
}

/* ---------------- layer-2 logits ---------------- */

__global__ void k_alpha2(const float* __restrict__ z2, const float* __restrict__ a_src,
                         const float* __restrict__ a_dst, float* __restrict__ as,
                         float* __restrict__ ad) {
  int n = blockIdx.x * blockDim.x + threadIdx.x;
  if (n >= N_NODES) return;
  const float* row = z2 + (size_t)n * C2;
  float s0 = 0.f, s1 = 0.f;
  for (int c = 0; c < C2; c++) { float v = row[c]; s0 += v * a_src[c]; s1 += v * a_dst[c]; }
  as[n] = s0; ad[n] = s1;
}

/* ---------------- layer-2 GAT fused with bias+ReLU+graph-max-pool ---------------- */

__global__ __launch_bounds__(256) void k_gat2b(const ushort_t* __restrict__ z2b,
                                               const float* __restrict__ as,
                                               const float* __restrict__ ad,
                                               const int* __restrict__ offs,
                                               const int* __restrict__ srcs,
                                               const float* __restrict__ b2,
                                               const int* __restrict__ batch,
                                               unsigned int* __restrict__ pool) {
  int wid = (blockIdx.x * 256 + threadIdx.x) >> 6;
  int lane = threadIdx.x & 63;
  if (wid >= N_NODES) return;
  int n = wid;
  int beg = offs[n], deg = offs[n + 1] - beg;
  float adv = ad[n];
  const unsigned int* zrow = (const unsigned int*)z2b;

  float acc0 = 0.f, acc1 = 0.f;

  if (deg <= 64) {
    bool act = lane < deg;
    int s = act ? srcs[beg + lane] : 0;
    float e = -INFINITY;
    if (act) {
      float t = as[s] + adv;
      e = (t > 0.f) ? t : NEG_SLOPE * t;
    }
    float m = e;
#pragma unroll
    for (int o = 32; o; o >>= 1) m = fmaxf(m, __shfl_xor(m, o));
    float p = act ? __expf(e - m) : 0.f;
    float ssum = p;
#pragma unroll
    for (int o = 32; o; o >>= 1) ssum += __shfl_xor(ssum, o);
    p *= 1.f / (ssum + 1e-16f);
    int j = 0;
    for (; j + 1 < deg; j += 2) {
      int s0 = __shfl(s, j), s1 = __shfl(s, j + 1);
      float w0 = __shfl(p, j), w1 = __shfl(p, j + 1);
      if (lane < C2 / 2) {
        unsigned int u0 = zrow[(size_t)s0 * (C2 / 2) + lane];
        unsigned int u1 = zrow[(size_t)s1 * (C2 / 2) + lane];
        acc0 += w0 * bf_lo(u0) + w1 * bf_lo(u1);
        acc1 += w0 * bf_hi(u0) + w1 * bf_hi(u1);
      }
    }
    if (j < deg) {
      int s0 = __shfl(s, j);
      float w0 = __shfl(p, j);
      if (lane < C2 / 2) {
        unsigned int u0 = zrow[(size_t)s0 * (C2 / 2) + lane];
        acc0 += w0 * bf_lo(u0);
        acc1 += w0 * bf_hi(u0);
      }
    }
  } else {
    float m = -INFINITY;
    for (int i = lane; i < deg; i += 64) {
      float t = as[srcs[beg + i]] + adv;
      t = (t > 0.f) ? t : NEG_SLOPE * t;
      m = fmaxf(m, t);
    }
#pragma unroll
    for (int o = 32; o; o >>= 1) m = fmaxf(m, __shfl_xor(m, o));
    float ssum = 0.f;
    for (int i = lane; i < deg; i += 64) {
      float t = as[srcs[beg + i]] + adv;
      t = (t > 0.f) ? t : NEG_SLOPE * t;
      ssum += __expf(t - m);
    }
#pragma unroll
    for (int o = 32; o; o >>= 1) ssum += __shfl_xor(ssum, o);
    float inv = 1.f / (ssum + 1e-16f);
    for (int chunk = 0; chunk < deg; chunk += 64) {
      int i = chunk + lane;
      float w = 0.f; int s = 0;
      if (i < deg) {
        s = srcs[beg + i];
        float t = as[s] + adv;
        t = (t > 0.f) ? t : NEG_SLOPE * t;
        w = __expf(t - m) * inv;
      }
      int cl = min(64, deg - chunk);
      for (int j = 0; j < cl; j++) {
        float wj = __shfl(w, j);
        int sj = __shfl(s, j);
        if (lane < C2 / 2) {
          unsigned int u = zrow[(size_t)sj * (C2 / 2) + lane];
          acc0 += wj * bf_lo(u);
          acc1 += wj * bf_hi(u);
        }
      }
    }
  }

  if (lane < C2 / 2) {
    float v0 = fmaxf(acc0 + b2[2 * lane], 0.f);
    float v1 = fmaxf(acc1 + b2[2 * lane + 1], 0.f);
    int g = batch[n];
    atomicMax(&pool[g * C2 + 2 * lane], __float_as_uint(v0));
    atomicMax(&pool[g * C2 + 2 * lane + 1], __float_as_uint(v1));
  }
}

/* ---------------- head: out = relu(pool @ Wg + bg) ---------------- */

__global__ __launch_bounds__(128) void k_head(const float* __restrict__ pool,
                                              const float* __restrict__ Wg,
                                              const float* __restrict__ bg,
                                              float* __restrict__ out) {
  __shared__ float row[C2];
  int g = blockIdx.x;
  if (threadIdx.x < C2) row[threadIdx.x] = pool[g * C2 + threadIdx.x];
  __syncthreads();
  int c = threadIdx.x;
  if (c < C2) {
    float acc = bg[c];
    for (int k = 0; k < C2; k++) acc += row[k] * Wg[k * C2 + c];
    out[g * C2 + c] = fmaxf(acc, 0.f);
  }
}

/* ---------------- launch ---------------- */

extern "C" void kernel_launch(void* const* d_in, const int* in_sizes, int n_in,
                              void* d_out, int out_size, void* d_ws, size_t ws_size,
                              hipStream_t stream) {
  const float* x      = (const float*)d_in[0];
  const int*   ei     = (const int*)d_in[1];
  const int*   batch  = (const int*)d_in[2];
  const float* W1     = (const float*)d_in[4];
  const float* a_src1 = (const float*)d_in[5];
  const float* a_dst1 = (const float*)d_in[6];
  const float* b1     = (const float*)d_in[7];
  const float* W2     = (const float*)d_in[8];
  const float* a_src2 = (const float*)d_in[9];
  const float* a_dst2 = (const float*)d_in[10];
  const float* b2     = (const float*)d_in[11];
  const float* Wg     = (const float*)d_in[12];
  const float* bg     = (const float*)d_in[13];
  float* out = (float*)d_out;

  char* w = (char*)d_ws;
  size_t off = 0;
  auto alloc = [&](size_t bytes) -> void* {
    void* p = w + off;
    off += (bytes + 255) & ~(size_t)255;
    return p;
  };

  ushort_t* xb  = (ushort_t*)alloc((size_t)H1 * N_NODES * K1PAD * 2);  /* 38.4 MB */
  ushort_t* hab = (ushort_t*)alloc((size_t)N_NODES * K2PAD * 2);       /* 32 MB  */
  float* part   = (float*)alloc((size_t)KSPLIT * N_NODES * C2 * 4);    /* 40 MB  */
  float* asb    = (float*)alloc((size_t)H1 * N_NODES * 4);
  float* adb    = (float*)alloc((size_t)H1 * N_NODES * 4);
  float* Vs     = (float*)alloc((size_t)H1 * C1 * 4);
  float* Vd     = (float*)alloc((size_t)H1 * C1 * 4);
  ushort_t* W1t = (ushort_t*)alloc((size_t)H1 * 80 * K1PAD * 2);
  ushort_t* W2t = (ushort_t*)alloc((size_t)112 * K2PAD * 2);
  int* cnt    = (int*)alloc((size_t)N_NODES * 4);
  int* cursor = (int*)alloc((size_t)N_NODES * 4);
  int* offs   = (int*)alloc((size_t)(N_NODES + 1) * 4);
  int* srcs   = (int*)alloc((size_t)E_TOT * 4);

  /* layer-2 small buffers alias xb (dead after k_bgemm_m): 12.2 MB < 38.4 MB */
  float* z2           = (float*)xb;
  float* as2          = z2 + (size_t)N_NODES * C2;
  float* ad2          = as2 + N_NODES;
  ushort_t* z2b       = (ushort_t*)(ad2 + N_NODES);
  unsigned int* pool  = (unsigned int*)(z2b + (size_t)N_NODES * C2);

  hipMemsetAsync(cnt, 0, (size_t)N_NODES * 4, stream);
  hipMemsetAsync(cursor, 0, (size_t)N_NODES * 4, stream);

  k_count<<<(E_TOT + 255) / 256, 256, 0, stream>>>(ei, cnt);
  k_scan<<<1, 1024, 0, stream>>>(cnt, offs, N_NODES);
  k_scatter<<<(E_TOT + 255) / 256, 256, 0, stream>>>(ei, offs, cursor, srcs);

  k_vmake<<<7, 256, 0, stream>>>(W1, a_src1, a_dst1, Vs, Vd);
  k_prepW1t<<<(H1 * 80 * K1PAD + 255) / 256, 256, 0, stream>>>(W1, W1t);
  k_prepW2t<<<(112 * K2PAD + 255) / 256, 256, 0, stream>>>(W2, W2t);
  k_padha<<<(N_NODES * (K2PAD - F1) + 255) / 256, 256, 0, stream>>>(hab);

  k_alpha1x<<<(N_NODES * H1 + 255) / 256, 256, 0, stream>>>(x, Vs, Vd, asb, adb);
  k_agg<<<(N_NODES + 3) / 4, 256, 0, stream>>>(x, asb, adb, offs, srcs, xb);
  k_bgemm_m<<<dim3((N_NODES + 63) / 64, H1), 256, 0, stream>>>(xb, W1t, b1, hab);

  k_gemm2m<<<dim3((N_NODES + 63) / 64, KSPLIT), 256, 0, stream>>>(hab, W2t, part);
  k_reduce<<<(N_NODES * C2 / 2 + 255) / 256, 256, 0, stream>>>(part, z2, z2b);
  k_alpha2<<<(N_NODES + 255) / 256, 256, 0, stream>>>(z2, a_src2, a_dst2, as2, ad2);

  hipMemsetAsync(pool, 0, (size_t)N_GRAPHS * C2 * 4, stream);
  k_gat2b<<<(N_NODES + 3) / 4, 256, 0, stream>>>(z2b, as2, ad2, offs, srcs, b2, batch, pool);
  k_head<<<N_GRAPHS, 128, 0, stream>>>((const float*)pool, Wg, bg, out);
}

// Round 7
// 319.525 us; speedup vs baseline: 8.9051x; 1.0338x over previous
//
#include <hip/hip_runtime.h>
#include <hip/hip_bf16.h>

#define N_NODES  20000
#define N_EDGES  320000
#define E_TOT    (N_EDGES + N_NODES)   /* 340000 incl. self loops */
#define N_GRAPHS 512
#define H1 10
#define C1 78
#define F1 780                          /* H1*C1 */
#define C2 100
#define NEG_SLOPE 0.2f
#define KSPLIT 5
#define K1PAD 96                        /* layer-1 K (78) padded to 3x32 */
#define K2PAD 800                       /* layer-2 K (780) padded to 25x32 */
#define K2CHUNK 160                     /* 800 / KSPLIT */
#define AP1 104                         /* LDS row stride (bf16) for bgemm */
#define AP2 40                          /* LDS row stride for gemm2 */

typedef short bf16x8 __attribute__((ext_vector_type(8)));
typedef float f32x4 __attribute__((ext_vector_type(4)));
typedef unsigned short ushort_t;

__device__ __forceinline__ float bf_lo(unsigned int u) { return __uint_as_float(u << 16); }
__device__ __forceinline__ float bf_hi(unsigned int u) { return __uint_as_float(u & 0xFFFF0000u); }
__device__ __forceinline__ float bfu(ushort_t u) { return __uint_as_float(((unsigned int)u) << 16); }
__device__ __forceinline__ ushort_t f2b(float v) {
  __hip_bfloat16 b = __float2bfloat16(v);   /* RNE */
  return *reinterpret_cast<ushort_t*>(&b);
}

/* ---------------- CSR build (by destination) ---------------- */

__global__ void k_count(const int* __restrict__ ei, int* __restrict__ cnt) {
  int e = blockIdx.x * blockDim.x + threadIdx.x;
  if (e >= E_TOT) return;
  int dst = (e < N_EDGES) ? ei[N_EDGES + e] : (e - N_EDGES);
  atomicAdd(&cnt[dst], 1);
}

__global__ __launch_bounds__(1024) void k_scan(const int* __restrict__ cnt,
                                               int* __restrict__ offs, int n) {
  const int PER = 20;
  int t = threadIdx.x;
  int lane = t & 63, wv = t >> 6;
  int base = t * PER;
  int loc[PER];
  int run = 0;
#pragma unroll
  for (int k = 0; k < PER; k++) {
    int idx = base + k;
    int v = (idx < n) ? cnt[idx] : 0;
    run += v;
    loc[k] = run;
  }
  int total = run;
  int sc = total;
#pragma unroll
  for (int o = 1; o < 64; o <<= 1) {
    int u = __shfl_up(sc, o);
    if (lane >= o) sc += u;
  }
  __shared__ int ws[16];
  if (lane == 63) ws[wv] = sc;
  __syncthreads();
  if (t == 0) {
    int r = 0;
#pragma unroll
    for (int i = 0; i < 16; i++) { int v = ws[i]; ws[i] = r; r += v; }
  }
  __syncthreads();
  int excl = ws[wv] + sc - total;
#pragma unroll
  for (int k = 0; k < PER; k++) {
    int idx = base + k;
    if (idx < n) offs[idx + 1] = excl + loc[k];
  }
  if (t == 0) offs[0] = 0;
}

__global__ void k_scatter(const int* __restrict__ ei, const int* __restrict__ offs,
                          int* __restrict__ cursor, int* __restrict__ srcs,
                          int* __restrict__ dsts) {
  int e = blockIdx.x * blockDim.x + threadIdx.x;
  if (e >= E_TOT) return;
  int src, dst;
  if (e < N_EDGES) { src = ei[e]; dst = ei[N_EDGES + e]; }
  else             { src = dst = e - N_EDGES; }
  int pos = offs[dst] + atomicAdd(&cursor[dst], 1);
  srcs[pos] = src;
  dsts[pos] = dst;
}

/* ---------------- fused prep: Vs/Vd + W1t + W2t + hab K-pad zero ---------------- */

#define PR0 (2 * H1 * C1)
#define PR1 (H1 * 80 * K1PAD)
#define PR2 (112 * K2PAD)
#define PR3 (N_NODES * (K2PAD - F1))

__global__ void k_prep(const float* __restrict__ W1, const float* __restrict__ a_src,
                       const float* __restrict__ a_dst, const float* __restrict__ W2,
                       float* __restrict__ Vs, float* __restrict__ Vd,
                       ushort_t* __restrict__ W1t, ushort_t* __restrict__ W2t,
                       ushort_t* __restrict__ hab) {
  int t = blockIdx.x * blockDim.x + threadIdx.x;
  if (t < PR0) {
    int which = (t >= H1 * C1) ? 1 : 0;
    int r = t - which * H1 * C1;
    int h = r / C1, k = r - h * C1;
    const float* a = which ? a_dst : a_src;
    float s = 0.f;
    for (int c = 0; c < C1; c++) s += W1[(size_t)k * F1 + h * C1 + c] * a[h * C1 + c];
    (which ? Vd : Vs)[h * C1 + k] = s;
    return;
  }
  t -= PR0;
  if (t < PR1) {
    int h = t / (80 * K1PAD);
    int rem = t - h * 80 * K1PAD;
    int c = rem / K1PAD, k = rem - c * K1PAD;
    float v = (c < C1 && k < C1) ? W1[(size_t)k * F1 + h * C1 + c] : 0.f;
    W1t[t] = f2b(v);
    return;
  }
  t -= PR1;
  if (t < PR2) {
    int c = t / K2PAD, k = t - c * K2PAD;
    float v = (c < C2 && k < F1) ? W2[(size_t)k * C2 + c] : 0.f;
    W2t[t] = f2b(v);
    return;
  }
  t -= PR2;
  if (t < PR3) {
    int n = t / (K2PAD - F1), j = t - n * (K2PAD - F1);
    hab[(size_t)n * K2PAD + F1 + j] = 0;
  }
}

/* ---------------- layer-1 logits: asb[h][n] = x[n] . Vs[h] (float2 vectorized) ----- */

__global__ __launch_bounds__(256) void k_alpha1x(const float* __restrict__ x,
                                                 const float* __restrict__ Vs,
                                                 const float* __restrict__ Vd,
                                                 float* __restrict__ asb,
                                                 float* __restrict__ adb) {
  __shared__ float sVs[H1 * C1], sVd[H1 * C1];
  for (int i = threadIdx.x; i < H1 * C1; i += 256) { sVs[i] = Vs[i]; sVd[i] = Vd[i]; }
  __syncthreads();
  int t = blockIdx.x * 256 + threadIdx.x;
  if (t >= N_NODES * H1) return;
  int n = t / H1, h = t - n * H1;
  const float2* row = (const float2*)(x + (size_t)n * C1);
  const float2* vs2 = (const float2*)(sVs + h * C1);
  const float2* vd2 = (const float2*)(sVd + h * C1);
  float s0 = 0.f, s1 = 0.f;
#pragma unroll 13
  for (int i = 0; i < C1 / 2; i++) {
    float2 v = row[i];
    float2 a = vs2[i];
    float2 b = vd2[i];
    s0 += v.x * a.x + v.y * a.y;
    s1 += v.x * b.x + v.y * b.y;
  }
  asb[(size_t)h * N_NODES + n] = s0;
  adb[(size_t)h * N_NODES + n] = s1;
}

/* ---------------- edge-parallel unnormalized weights: ex1[e][h] = bf16(exp(leaky)) -- */

__global__ void k_ex1(const float* __restrict__ asb, const float* __restrict__ adb,
                      const int* __restrict__ srcs, const int* __restrict__ dsts,
                      ushort_t* __restrict__ ex1) {
  int t = blockIdx.x * blockDim.x + threadIdx.x;
  if (t >= E_TOT * H1) return;
  int e = t / H1, h = t - e * H1;
  int s = srcs[e], d = dsts[e];
  float v = asb[(size_t)h * N_NODES + s] + adb[(size_t)h * N_NODES + d];
  v = (v > 0.f) ? v : NEG_SLOPE * v;
  ex1[t] = f2b(__expf(v));
}

/* ---------------- per-(n,h) denominators: inv1[n][h] = 1/sum ---------------- */

__global__ void k_den1(const ushort_t* __restrict__ ex1, const int* __restrict__ offs,
                       float* __restrict__ inv1) {
  int t = blockIdx.x * blockDim.x + threadIdx.x;
  if (t >= N_NODES * H1) return;
  int n = t / H1, h = t - n * H1;
  int beg = offs[n], end = offs[n + 1];
  float s = 0.f;
  for (int e = beg; e < end; e++) s += bfu(ex1[(size_t)e * H1 + h]);
  inv1[t] = 1.f / (s + 1e-16f);
}

/* ---------------- layer-1 aggregation: wave per dst, NO cross-lane ops -------------
   xb[h][n][96] = bf16( inv1[n][h] * sum_e ex1[e][h] * x[src_e][c] )                  */

__global__ __launch_bounds__(256) void k_aggv2(const float* __restrict__ x,
                                               const ushort_t* __restrict__ ex1,
                                               const float* __restrict__ inv1,
                                               const int* __restrict__ offs,
                                               const int* __restrict__ srcs,
                                               ushort_t* __restrict__ xb) {
  int wid = (blockIdx.x * 256 + threadIdx.x) >> 6;
  int lane = threadIdx.x & 63;
  if (wid >= N_NODES) return;
  int n = wid;
  int beg = offs[n], deg = offs[n + 1] - beg;
  const unsigned int* exw = (const unsigned int*)ex1;   /* [e][10] bf16 = 5 uints */

  float acc[H1][2] = {};
  int j = 0;
  for (; j + 1 < deg; j += 2) {
    int e0 = beg + j, e1 = e0 + 1;
    int s0 = srcs[e0], s1 = srcs[e1];
    unsigned int w0[5], w1[5];
#pragma unroll
    for (int q = 0; q < 5; q++) { w0[q] = exw[(size_t)e0 * 5 + q]; w1[q] = exw[(size_t)e1 * 5 + q]; }
    float2 xv0 = make_float2(0.f, 0.f), xv1 = make_float2(0.f, 0.f);
    if (lane < C1 / 2) {
      xv0 = *(const float2*)(x + (size_t)s0 * C1 + 2 * lane);
      xv1 = *(const float2*)(x + (size_t)s1 * C1 + 2 * lane);
    }
#pragma unroll
    for (int h = 0; h < H1; h++) {
      float p0 = (h & 1) ? bf_hi(w0[h >> 1]) : bf_lo(w0[h >> 1]);
      float p1 = (h & 1) ? bf_hi(w1[h >> 1]) : bf_lo(w1[h >> 1]);
      acc[h][0] += p0 * xv0.x + p1 * xv1.x;
      acc[h][1] += p0 * xv0.y + p1 * xv1.y;
    }
  }
  if (j < deg) {
    int e0 = beg + j;
    int s0 = srcs[e0];
    unsigned int w0[5];
#pragma unroll
    for (int q = 0; q < 5; q++) w0[q] = exw[(size_t)e0 * 5 + q];
    float2 xv0 = make_float2(0.f, 0.f);
    if (lane < C1 / 2) xv0 = *(const float2*)(x + (size_t)s0 * C1 + 2 * lane);
#pragma unroll
    for (int h = 0; h < H1; h++) {
      float p0 = (h & 1) ? bf_hi(w0[h >> 1]) : bf_lo(w0[h >> 1]);
      acc[h][0] += p0 * xv0.x;
      acc[h][1] += p0 * xv0.y;
    }
  }

  if (lane < 48) {
    float iv[H1];
#pragma unroll
    for (int h = 0; h < H1; h++) iv[h] = inv1[n * H1 + h];
    int colu = (lane < 39) ? 2 * lane : C1 + 2 * (lane - 39);   /* pad cols 78..95 */
#pragma unroll
    for (int h = 0; h < H1; h++) {
      ushort2 o;
      if (lane < 39) { o.x = f2b(acc[h][0] * iv[h]); o.y = f2b(acc[h][1] * iv[h]); }
      else           { o.x = 0; o.y = 0; }
      *(ushort2*)(xb + ((size_t)h * N_NODES + n) * K1PAD + colu) = o;
    }
  }
}

/* ---------------- layer-1 block-diag GEMM via MFMA (unchanged) ---------------- */

__global__ __launch_bounds__(256) void k_bgemm_m(const ushort_t* __restrict__ xb,
                                                 const ushort_t* __restrict__ W1t,
                                                 const float* __restrict__ b1,
                                                 ushort_t* __restrict__ hab) {
  __shared__ ushort_t sA[64 * AP1];
  __shared__ ushort_t sB[80 * AP1];
  int h = blockIdx.y;
  int m0 = blockIdx.x * 64;
  int tid = threadIdx.x;

  for (int i = tid; i < 64 * 12; i += 256) {
    int r = i / 12, cx = i - r * 12;
    uint4 v = make_uint4(0, 0, 0, 0);
    int m = m0 + r;
    if (m < N_NODES) v = *(const uint4*)(xb + ((size_t)h * N_NODES + m) * K1PAD + cx * 8);
    *(uint4*)(sA + r * AP1 + cx * 8) = v;
  }
  for (int i = tid; i < 80 * 12; i += 256) {
    int c = i / 12, cx = i - c * 12;
    uint4 v = *(const uint4*)(W1t + ((size_t)h * 80 + c) * K1PAD + cx * 8);
    *(uint4*)(sB + c * AP1 + cx * 8) = v;
  }
  __syncthreads();

  int w = tid >> 6, l = tid & 63;
  int rb = l & 15, g = l >> 4;
  f32x4 acc[5] = {};
  const ushort_t* pa = sA + (w * 16 + rb) * AP1 + g * 8;
#pragma unroll
  for (int k0 = 0; k0 < K1PAD; k0 += 32) {
    bf16x8 a = *(const bf16x8*)(pa + k0);
#pragma unroll
    for (int ct = 0; ct < 5; ct++) {
      bf16x8 b = *(const bf16x8*)(sB + (ct * 16 + rb) * AP1 + k0 + g * 8);
      acc[ct] = __builtin_amdgcn_mfma_f32_16x16x32_bf16(a, b, acc[ct], 0, 0, 0);
    }
  }

  int mrow = m0 + w * 16 + g * 4;
#pragma unroll
  for (int ct = 0; ct < 5; ct++) {
    int col = ct * 16 + rb;
    if (col >= C1) continue;
    float bias = b1[h * C1 + col];
#pragma unroll
    for (int r = 0; r < 4; r++) {
      int m = mrow + r;
      if (m >= N_NODES) continue;
      float v = acc[ct][r] + bias;
      v = (v > 0.f) ? v : (__expf(v) - 1.f);
      hab[(size_t)m * K2PAD + h * C1 + col] = f2b(v);
    }
  }
}

/* ---------------- layer-2 GEMM via MFMA, split-K (unchanged) ---------------- */

__global__ __launch_bounds__(256) void k_gemm2m(const ushort_t* __restrict__ hab,
                                                const ushort_t* __restrict__ W2t,
                                                float* __restrict__ part) {
  __shared__ ushort_t sA[64 * AP2];
  __shared__ ushort_t sB[112 * AP2];
  int m0 = blockIdx.x * 64;
  int kz = blockIdx.y * K2CHUNK;
  int tid = threadIdx.x;
  int w = tid >> 6, l = tid & 63;
  int rb = l & 15, g = l >> 4;
  f32x4 acc[7] = {};

  for (int ks = 0; ks < K2CHUNK; ks += 32) {
    int kbase = kz + ks;
    {
      int r = tid >> 2, cx = tid & 3;
      uint4 v = make_uint4(0, 0, 0, 0);
      int m = m0 + r;
      if (m < N_NODES) v = *(const uint4*)(hab + (size_t)m * K2PAD + kbase + cx * 8);
      *(uint4*)(sA + r * AP2 + cx * 8) = v;
    }
    for (int i = tid; i < 112 * 4; i += 256) {
      int c = i >> 2, cx = i & 3;
      uint4 v = *(const uint4*)(W2t + (size_t)c * K2PAD + kbase + cx * 8);
      *(uint4*)(sB + c * AP2 + cx * 8) = v;
    }
    __syncthreads();
    bf16x8 a = *(const bf16x8*)(sA + (w * 16 + rb) * AP2 + g * 8);
#pragma unroll
    for (int ct = 0; ct < 7; ct++) {
      bf16x8 b = *(const bf16x8*)(sB + (ct * 16 + rb) * AP2 + g * 8);
      acc[ct] = __builtin_amdgcn_mfma_f32_16x16x32_bf16(a, b, acc[ct], 0, 0, 0);
    }
    __syncthreads();
  }

  float* P = part + (size_t)blockIdx.y * N_NODES * C2;
  int mrow = m0 + w * 16 + g * 4;
#pragma unroll
  for (int ct = 0; ct < 7; ct++) {
    int col = ct * 16 + rb;
    if (col >= C2) continue;
#pragma unroll
    for (int r = 0; r < 4; r++) {
      int m = mrow + r;
      if (m < N_NODES) P[(size_t)m * C2 + col] = acc[ct][r];
    }
  }
}

/* ---------------- fused reduce + layer-2 logits: wave per node -----------------
   z2b[n] = bf16(sum_c part[c][n]); as2/ad2[n] = z . a_{src,dst}2                  */

__global__ __launch_bounds__(256) void k_redalpha(const float* __restrict__ part,
                                                  const float* __restrict__ a_src,
                                                  const float* __restrict__ a_dst,
                                                  ushort_t* __restrict__ z2b,
                                                  float* __restrict__ as2,
                                                  float* __restrict__ ad2) {
  int wid = (blockIdx.x * 256 + threadIdx.x) >> 6;
  int lane = threadIdx.x & 63;
  if (wid >= N_NODES) return;
  float ps = 0.f, pd = 0.f;
  if (lane < C2 / 2) {
    float2 s = make_float2(0.f, 0.f);
#pragma unroll
    for (int c = 0; c < KSPLIT; c++) {
      float2 v = *(const float2*)(part + (size_t)c * N_NODES * C2 + (size_t)wid * C2 + 2 * lane);
      s.x += v.x; s.y += v.y;
    }
    ushort2 o; o.x = f2b(s.x); o.y = f2b(s.y);
    *(ushort2*)(z2b + (size_t)wid * C2 + 2 * lane) = o;
    ps = s.x * a_src[2 * lane] + s.y * a_src[2 * lane + 1];
    pd = s.x * a_dst[2 * lane] + s.y * a_dst[2 * lane + 1];
  }
#pragma unroll
  for (int o = 32; o; o >>= 1) { ps += __shfl_xor(ps, o); pd += __shfl_xor(pd, o); }
  if (lane == 0) { as2[wid] = ps; ad2[wid] = pd; }
}

/* ---------------- layer-2 edge weights + denominators ---------------- */

__global__ void k_ex2(const float* __restrict__ as2, const float* __restrict__ ad2,
                      const int* __restrict__ srcs, const int* __restrict__ dsts,
                      float* __restrict__ ex2) {
  int e = blockIdx.x * blockDim.x + threadIdx.x;
  if (e >= E_TOT) return;
  float v = as2[srcs[e]] + ad2[dsts[e]];
  v = (v > 0.f) ? v : NEG_SLOPE * v;
  ex2[e] = __expf(v);
}

__global__ void k_den2(const float* __restrict__ ex2, const int* __restrict__ offs,
                       float* __restrict__ inv2) {
  int n = blockIdx.x * blockDim.x + threadIdx.x;
  if (n >= N_NODES) return;
  int beg = offs[n], end = offs[n + 1];
  float s = 0.f;
  for (int e = beg; e < end; e++) s += ex2[e];
  inv2[n] = 1.f / (s + 1e-16f);
}

/* ---------------- layer-2 aggregation + bias + ReLU + graph-max-pool -------------- */

__global__ __launch_bounds__(256) void k_gat2v2(const ushort_t* __restrict__ z2b,
                                                const float* __restrict__ ex2,
                                                const float* __restrict__ inv2,
                                                const int* __restrict__ offs,
                                                const int* __restrict__ srcs,
                                                const float* __restrict__ b2,
                                                const int* __restrict__ batch,
                                                unsigned int* __restrict__ pool) {
  int wid = (blockIdx.x * 256 + threadIdx.x) >> 6;
  int lane = threadIdx.x & 63;
  if (wid >= N_NODES) return;
  int n = wid;
  int beg = offs[n], deg = offs[n + 1] - beg;
  const unsigned int* zrow = (const unsigned int*)z2b;

  float acc0 = 0.f, acc1 = 0.f;
  int j = 0;
  for (; j + 1 < deg; j += 2) {
    int e0 = beg + j, e1 = e0 + 1;
    float p0 = ex2[e0], p1 = ex2[e1];
    int s0 = srcs[e0], s1 = srcs[e1];
    if (lane < C2 / 2) {
      unsigned int u0 = zrow[(size_t)s0 * (C2 / 2) + lane];
      unsigned int u1 = zrow[(size_t)s1 * (C2 / 2) + lane];
      acc0 += p0 * bf_lo(u0) + p1 * bf_lo(u1);
      acc1 += p0 * bf_hi(u0) + p1 * bf_hi(u1);
    }
  }
  if (j < deg) {
    int e0 = beg + j;
    float p0 = ex2[e0];
    int s0 = srcs[e0];
    if (lane < C2 / 2) {
      unsigned int u0 = zrow[(size_t)s0 * (C2 / 2) + lane];
      acc0 += p0 * bf_lo(u0);
      acc1 += p0 * bf_hi(u0);
    }
  }

  if (lane < C2 / 2) {
    float iv = inv2[n];
    float v0 = fmaxf(acc0 * iv + b2[2 * lane], 0.f);
    float v1 = fmaxf(acc1 * iv + b2[2 * lane + 1], 0.f);
    int g = batch[n];
    atomicMax(&pool[g * C2 + 2 * lane], __float_as_uint(v0));
    atomicMax(&pool[g * C2 + 2 * lane + 1], __float_as_uint(v1));
  }
}

/* ---------------- head: out = relu(pool @ Wg + bg) ---------------- */

__global__ __launch_bounds__(128) void k_head(const float* __restrict__ pool,
                                              const float* __restrict__ Wg,
                                              const float* __restrict__ bg,
                                              float* __restrict__ out) {
  __shared__ float row[C2];
  int g = blockIdx.x;
  if (threadIdx.x < C2) row[threadIdx.x] = pool[g * C2 + threadIdx.x];
  __syncthreads();
  int c = threadIdx.x;
  if (c < C2) {
    float acc = bg[c];
    for (int k = 0; k < C2; k++) acc += row[k] * Wg[k * C2 + c];
    out[g * C2 + c] = fmaxf(acc, 0.f);
  }
}

/* ---------------- launch ---------------- */

extern "C" void kernel_launch(void* const* d_in, const int* in_sizes, int n_in,
                              void* d_out, int out_size, void* d_ws, size_t ws_size,
                              hipStream_t stream) {
  const float* x      = (const float*)d_in[0];
  const int*   ei     = (const int*)d_in[1];
  const int*   batch  = (const int*)d_in[2];
  const float* W1     = (const float*)d_in[4];
  const float* a_src1 = (const float*)d_in[5];
  const float* a_dst1 = (const float*)d_in[6];
  const float* b1     = (const float*)d_in[7];
  const float* W2     = (const float*)d_in[8];
  const float* a_src2 = (const float*)d_in[9];
  const float* a_dst2 = (const float*)d_in[10];
  const float* b2     = (const float*)d_in[11];
  const float* Wg     = (const float*)d_in[12];
  const float* bg     = (const float*)d_in[13];
  float* out = (float*)d_out;

  char* w = (char*)d_ws;
  size_t off = 0;
  auto alloc = [&](size_t bytes) -> void* {
    void* p = w + off;
    off += (bytes + 255) & ~(size_t)255;
    return p;
  };

  ushort_t* xb  = (ushort_t*)alloc((size_t)H1 * N_NODES * K1PAD * 2);  /* 38.4 MB */
  ushort_t* hab = (ushort_t*)alloc((size_t)N_NODES * K2PAD * 2);       /* 32 MB  */
  float* part   = (float*)alloc((size_t)KSPLIT * N_NODES * C2 * 4);    /* 40 MB  */
  float* asb    = (float*)alloc((size_t)H1 * N_NODES * 4);
  float* adb    = (float*)alloc((size_t)H1 * N_NODES * 4);
  float* Vs     = (float*)alloc((size_t)H1 * C1 * 4);
  float* Vd     = (float*)alloc((size_t)H1 * C1 * 4);
  ushort_t* W1t = (ushort_t*)alloc((size_t)H1 * 80 * K1PAD * 2);
  ushort_t* W2t = (ushort_t*)alloc((size_t)112 * K2PAD * 2);
  ushort_t* ex1 = (ushort_t*)alloc((size_t)E_TOT * H1 * 2);            /* 6.8 MB */
  float* inv1   = (float*)alloc((size_t)N_NODES * H1 * 4);
  /* cnt / cursor / pool: one contiguous zero region */
  int* cnt           = (int*)alloc((size_t)N_NODES * 4);
  int* cursor        = (int*)alloc((size_t)N_NODES * 4);
  unsigned int* pool = (unsigned int*)alloc((size_t)N_GRAPHS * C2 * 4);
  size_t zspan = (size_t)((char*)(pool + (size_t)N_GRAPHS * C2) - (char*)cnt);
  int* offs   = (int*)alloc((size_t)(N_NODES + 1) * 4);
  int* srcs   = (int*)alloc((size_t)E_TOT * 4);
  int* dsts   = (int*)alloc((size_t)E_TOT * 4);

  /* layer-2 buffers alias xb (dead after k_bgemm_m): ~5.8 MB < 38.4 MB */
  float* as2    = (float*)xb;
  float* ad2    = as2 + N_NODES;
  ushort_t* z2b = (ushort_t*)(ad2 + N_NODES);
  float* ex2    = (float*)(z2b + (size_t)N_NODES * C2);
  float* inv2   = ex2 + E_TOT;

  hipMemsetAsync(cnt, 0, zspan, stream);

  k_count<<<(E_TOT + 255) / 256, 256, 0, stream>>>(ei, cnt);
  k_scan<<<1, 1024, 0, stream>>>(cnt, offs, N_NODES);
  k_scatter<<<(E_TOT + 255) / 256, 256, 0, stream>>>(ei, offs, cursor, srcs, dsts);

  k_prep<<<(PR0 + PR1 + PR2 + PR3 + 255) / 256, 256, 0, stream>>>(W1, a_src1, a_dst1, W2,
                                                                  Vs, Vd, W1t, W2t, hab);
  k_alpha1x<<<(N_NODES * H1 + 255) / 256, 256, 0, stream>>>(x, Vs, Vd, asb, adb);
  k_ex1<<<((size_t)E_TOT * H1 + 255) / 256, 256, 0, stream>>>(asb, adb, srcs, dsts, ex1);
  k_den1<<<(N_NODES * H1 + 255) / 256, 256, 0, stream>>>(ex1, offs, inv1);
  k_aggv2<<<(N_NODES + 3) / 4, 256, 0, stream>>>(x, ex1, inv1, offs, srcs, xb);
  k_bgemm_m<<<dim3((N_NODES + 63) / 64, H1), 256, 0, stream>>>(xb, W1t, b1, hab);

  k_gemm2m<<<dim3((N_NODES + 63) / 64, KSPLIT), 256, 0, stream>>>(hab, W2t, part);
  k_redalpha<<<(N_NODES + 3) / 4, 256, 0, stream>>>(part, a_src2, a_dst2, z2b, as2, ad2);
  k_ex2<<<(E_TOT + 255) / 256, 256, 0, stream>>>(as2, ad2, srcs, dsts, ex2);
  k_den2<<<(N_NODES + 255) / 256, 256, 0, stream>>>(ex2, offs, inv2);
  k_gat2v2<<<(N_NODES + 3) / 4, 256, 0, stream>>>(z2b, ex2, inv2, offs, srcs, b2, batch, pool);
  k_head<<<N_GRAPHS, 128, 0, stream>>>((const float*)pool, Wg, bg, out);
}

// Round 8
// 295.678 us; speedup vs baseline: 9.6233x; 1.0807x over previous
//
#include <hip/hip_runtime.h>
#include <hip/hip_bf16.h>

#define N_NODES  20000
#define N_EDGES  320000
#define E_TOT    (N_EDGES + N_NODES)   /* 340000 incl. self loops */
#define N_GRAPHS 512
#define H1 10
#define C1 78
#define F1 780                          /* H1*C1 */
#define C2 100
#define NEG_SLOPE 0.2f
#define KSPLIT 5
#define K1PAD 96                        /* layer-1 K (78) padded to 3x32 */
#define K2PAD 800                       /* layer-2 K (780) padded to 25x32 */
#define K2CHUNK 160                     /* 800 / KSPLIT */
#define AP1 104                         /* LDS row stride (bf16) for bgemm */
#define AP2 40                          /* LDS row stride for gemm2 */
#define HP 12                           /* padded head stride for asb/adb/ex1 */

typedef short bf16x8 __attribute__((ext_vector_type(8)));
typedef float f32x4 __attribute__((ext_vector_type(4)));
typedef unsigned short ushort_t;

__device__ __forceinline__ float bf_lo(unsigned int u) { return __uint_as_float(u << 16); }
__device__ __forceinline__ float bf_hi(unsigned int u) { return __uint_as_float(u & 0xFFFF0000u); }
__device__ __forceinline__ ushort_t f2b(float v) {
  __hip_bfloat16 b = __float2bfloat16(v);   /* RNE */
  return *reinterpret_cast<ushort_t*>(&b);
}
__device__ __forceinline__ float lrelu(float v) { return (v > 0.f) ? v : NEG_SLOPE * v; }

/* ---------------- CSR build (by destination) ---------------- */

__global__ void k_count(const int* __restrict__ ei, int* __restrict__ cnt) {
  int e = blockIdx.x * blockDim.x + threadIdx.x;
  if (e >= E_TOT) return;
  int dst = (e < N_EDGES) ? ei[N_EDGES + e] : (e - N_EDGES);
  atomicAdd(&cnt[dst], 1);
}

__global__ __launch_bounds__(1024) void k_scan(const int* __restrict__ cnt,
                                               int* __restrict__ offs, int n) {
  const int PER = 20;
  int t = threadIdx.x;
  int lane = t & 63, wv = t >> 6;
  int base = t * PER;
  int loc[PER];
  int run = 0;
#pragma unroll
  for (int k = 0; k < PER; k++) {
    int idx = base + k;
    int v = (idx < n) ? cnt[idx] : 0;
    run += v;
    loc[k] = run;
  }
  int total = run;
  int sc = total;
#pragma unroll
  for (int o = 1; o < 64; o <<= 1) {
    int u = __shfl_up(sc, o);
    if (lane >= o) sc += u;
  }
  __shared__ int ws[16];
  if (lane == 63) ws[wv] = sc;
  __syncthreads();
  if (t == 0) {
    int r = 0;
#pragma unroll
    for (int i = 0; i < 16; i++) { int v = ws[i]; ws[i] = r; r += v; }
  }
  __syncthreads();
  int excl = ws[wv] + sc - total;
#pragma unroll
  for (int k = 0; k < PER; k++) {
    int idx = base + k;
    if (idx < n) offs[idx + 1] = excl + loc[k];
  }
  if (t == 0) offs[0] = 0;
}

__global__ void k_scatter(const int* __restrict__ ei, const int* __restrict__ offs,
                          int* __restrict__ cursor, int* __restrict__ srcs,
                          int* __restrict__ dsts) {
  int e = blockIdx.x * blockDim.x + threadIdx.x;
  if (e >= E_TOT) return;
  int src, dst;
  if (e < N_EDGES) { src = ei[e]; dst = ei[N_EDGES + e]; }
  else             { src = dst = e - N_EDGES; }
  int pos = offs[dst] + atomicAdd(&cursor[dst], 1);
  srcs[pos] = src;
  dsts[pos] = dst;
}

/* ---------------- fused prep: Vs/Vd + W1t + W2t + hab K-pad zero + x->bf16 -------- */

#define PR0 (2 * H1 * C1)
#define PR1 (H1 * 80 * K1PAD)
#define PR2 (112 * K2PAD)
#define PR3 (N_NODES * (K2PAD - F1))
#define PR4 (N_NODES * 40)

__global__ void k_prep(const float* __restrict__ W1, const float* __restrict__ a_src,
                       const float* __restrict__ a_dst, const float* __restrict__ W2,
                       const float* __restrict__ x,
                       float* __restrict__ Vs, float* __restrict__ Vd,
                       ushort_t* __restrict__ W1t, ushort_t* __restrict__ W2t,
                       ushort_t* __restrict__ hab, ushort_t* __restrict__ xbf) {
  int t = blockIdx.x * blockDim.x + threadIdx.x;
  if (t < PR0) {
    int which = (t >= H1 * C1) ? 1 : 0;
    int r = t - which * H1 * C1;
    int h = r / C1, k = r - h * C1;
    const float* a = which ? a_dst : a_src;
    float s = 0.f;
    for (int c = 0; c < C1; c++) s += W1[(size_t)k * F1 + h * C1 + c] * a[h * C1 + c];
    (which ? Vd : Vs)[h * C1 + k] = s;
    return;
  }
  t -= PR0;
  if (t < PR1) {
    int h = t / (80 * K1PAD);
    int rem = t - h * 80 * K1PAD;
    int c = rem / K1PAD, k = rem - c * K1PAD;
    float v = (c < C1 && k < C1) ? W1[(size_t)k * F1 + h * C1 + c] : 0.f;
    W1t[t] = f2b(v);
    return;
  }
  t -= PR1;
  if (t < PR2) {
    int c = t / K2PAD, k = t - c * K2PAD;
    float v = (c < C2 && k < F1) ? W2[(size_t)k * C2 + c] : 0.f;
    W2t[t] = f2b(v);
    return;
  }
  t -= PR2;
  if (t < PR3) {
    int n = t / (K2PAD - F1), j = t - n * (K2PAD - F1);
    hab[(size_t)n * K2PAD + F1 + j] = 0;
    return;
  }
  t -= PR3;
  if (t < PR4) {
    int n = t / 40, c2 = t - n * 40;
    ushort2 o;
    if (c2 < 39) { o.x = f2b(x[(size_t)n * C1 + 2 * c2]); o.y = f2b(x[(size_t)n * C1 + 2 * c2 + 1]); }
    else         { o.x = 0; o.y = 0; }
    *(ushort2*)(xbf + (size_t)n * 80 + 2 * c2) = o;
  }
}

/* ---------------- layer-1 logits: asb[n][12] node-major ---------------- */

__global__ __launch_bounds__(256) void k_alpha1x(const float* __restrict__ x,
                                                 const float* __restrict__ Vs,
                                                 const float* __restrict__ Vd,
                                                 float* __restrict__ asb,
                                                 float* __restrict__ adb) {
  __shared__ float sVs[H1 * C1], sVd[H1 * C1];
  for (int i = threadIdx.x; i < H1 * C1; i += 256) { sVs[i] = Vs[i]; sVd[i] = Vd[i]; }
  __syncthreads();
  int t = blockIdx.x * 256 + threadIdx.x;
  if (t >= N_NODES * H1) return;
  int n = t / H1, h = t - n * H1;
  const float2* row = (const float2*)(x + (size_t)n * C1);
  const float2* vs2 = (const float2*)(sVs + h * C1);
  const float2* vd2 = (const float2*)(sVd + h * C1);
  float s0 = 0.f, s1 = 0.f;
#pragma unroll 13
  for (int i = 0; i < C1 / 2; i++) {
    float2 v = row[i];
    float2 a = vs2[i];
    float2 b = vd2[i];
    s0 += v.x * a.x + v.y * a.y;
    s1 += v.x * b.x + v.y * b.y;
  }
  asb[(size_t)n * HP + h] = s0;
  adb[(size_t)n * HP + h] = s1;
}

/* ---------------- edge-parallel weights: ex1[e][12] = exp(leaky(as+ad)) fp32 ------ */

__global__ void k_ex1(const float* __restrict__ asb, const float* __restrict__ adb,
                      const int* __restrict__ srcs, const int* __restrict__ dsts,
                      float* __restrict__ ex1) {
  int e = blockIdx.x * blockDim.x + threadIdx.x;
  if (e > E_TOT) return;
  float* o = ex1 + (size_t)e * HP;
  if (e == E_TOT) {   /* zero sentinel row for group-padding */
    *(float4*)o = make_float4(0.f, 0.f, 0.f, 0.f);
    *(float4*)(o + 4) = make_float4(0.f, 0.f, 0.f, 0.f);
    *(float2*)(o + 8) = make_float2(0.f, 0.f);
    return;
  }
  int s = srcs[e], d = dsts[e];
  const float* pa = asb + (size_t)s * HP;
  const float* pd = adb + (size_t)d * HP;
  float4 a0 = *(const float4*)pa, a1 = *(const float4*)(pa + 4);
  float2 a2 = *(const float2*)(pa + 8);
  float4 d0 = *(const float4*)pd, d1 = *(const float4*)(pd + 4);
  float2 d2 = *(const float2*)(pd + 8);
  float4 r0, r1; float2 r2;
  r0.x = __expf(lrelu(a0.x + d0.x)); r0.y = __expf(lrelu(a0.y + d0.y));
  r0.z = __expf(lrelu(a0.z + d0.z)); r0.w = __expf(lrelu(a0.w + d0.w));
  r1.x = __expf(lrelu(a1.x + d1.x)); r1.y = __expf(lrelu(a1.y + d1.y));
  r1.z = __expf(lrelu(a1.z + d1.z)); r1.w = __expf(lrelu(a1.w + d1.w));
  r2.x = __expf(lrelu(a2.x + d2.x)); r2.y = __expf(lrelu(a2.y + d2.y));
  *(float4*)o = r0; *(float4*)(o + 4) = r1; *(float2*)(o + 8) = r2;
}

/* ---------------- layer-1 aggregation: wave per dst, group-4, fused denom ---------
   xb[h][n][96] = bf16( (1/sum ex) * sum_e ex1[e][h] * xbf[src_e][c] )               */

__global__ __launch_bounds__(256) void k_aggv3(const ushort_t* __restrict__ xbf,
                                               const float* __restrict__ ex1,
                                               const int* __restrict__ offs,
                                               const int* __restrict__ srcs,
                                               ushort_t* __restrict__ xb) {
  int wid = (blockIdx.x * 256 + threadIdx.x) >> 6;
  int lane = threadIdx.x & 63;
  if (wid >= N_NODES) return;
  int n = wid;
  int beg = offs[n], deg = offs[n + 1] - beg;

  float acc[H1][2] = {};
  float sum[H1] = {};

  for (int j = 0; j < deg; j += 4) {
    int ej[4], sj[4];
#pragma unroll
    for (int q = 0; q < 4; q++) {
      int jj = j + q;
      bool v = jj < deg;
      ej[q] = v ? beg + jj : E_TOT;        /* sentinel row: all-zero weights */
      sj[q] = srcs[v ? beg + jj : beg];
    }
    float4 p0[4], p1[4]; float2 p2[4];
#pragma unroll
    for (int q = 0; q < 4; q++) {
      const float* er = ex1 + (size_t)ej[q] * HP;
      p0[q] = *(const float4*)er;
      p1[q] = *(const float4*)(er + 4);
      p2[q] = *(const float2*)(er + 8);
    }
    unsigned int xv[4] = {0, 0, 0, 0};
    if (lane < 39) {
#pragma unroll
      for (int q = 0; q < 4; q++)
        xv[q] = *(const unsigned int*)(xbf + (size_t)sj[q] * 80 + 2 * lane);
    }
#pragma unroll
    for (int q = 0; q < 4; q++) {
      float xl = bf_lo(xv[q]), xh = bf_hi(xv[q]);
      float p[H1] = {p0[q].x, p0[q].y, p0[q].z, p0[q].w,
                     p1[q].x, p1[q].y, p1[q].z, p1[q].w,
                     p2[q].x, p2[q].y};
#pragma unroll
      for (int h = 0; h < H1; h++) {
        acc[h][0] += p[h] * xl;
        acc[h][1] += p[h] * xh;
        sum[h] += p[h];
      }
    }
  }

  if (lane < 48) {
    int colu = (lane < 39) ? 2 * lane : C1 + 2 * (lane - 39);   /* pad cols 78..95 */
#pragma unroll
    for (int h = 0; h < H1; h++) {
      float iv = 1.f / (sum[h] + 1e-16f);
      ushort2 o;
      if (lane < 39) { o.x = f2b(acc[h][0] * iv); o.y = f2b(acc[h][1] * iv); }
      else           { o.x = 0; o.y = 0; }
      *(ushort2*)(xb + ((size_t)h * N_NODES + n) * K1PAD + colu) = o;
    }
  }
}

/* ---------------- layer-1 block-diag GEMM via MFMA (unchanged) ---------------- */

__global__ __launch_bounds__(256) void k_bgemm_m(const ushort_t* __restrict__ xb,
                                                 const ushort_t* __restrict__ W1t,
                                                 const float* __restrict__ b1,
                                                 ushort_t* __restrict__ hab) {
  __shared__ ushort_t sA[64 * AP1];
  __shared__ ushort_t sB[80 * AP1];
  int h = blockIdx.y;
  int m0 = blockIdx.x * 64;
  int tid = threadIdx.x;

  for (int i = tid; i < 64 * 12; i += 256) {
    int r = i / 12, cx = i - r * 12;
    uint4 v = make_uint4(0, 0, 0, 0);
    int m = m0 + r;
    if (m < N_NODES) v = *(const uint4*)(xb + ((size_t)h * N_NODES + m) * K1PAD + cx * 8);
    *(uint4*)(sA + r * AP1 + cx * 8) = v;
  }
  for (int i = tid; i < 80 * 12; i += 256) {
    int c = i / 12, cx = i - c * 12;
    uint4 v = *(const uint4*)(W1t + ((size_t)h * 80 + c) * K1PAD + cx * 8);
    *(uint4*)(sB + c * AP1 + cx * 8) = v;
  }
  __syncthreads();

  int w = tid >> 6, l = tid & 63;
  int rb = l & 15, g = l >> 4;
  f32x4 acc[5] = {};
  const ushort_t* pa = sA + (w * 16 + rb) * AP1 + g * 8;
#pragma unroll
  for (int k0 = 0; k0 < K1PAD; k0 += 32) {
    bf16x8 a = *(const bf16x8*)(pa + k0);
#pragma unroll
    for (int ct = 0; ct < 5; ct++) {
      bf16x8 b = *(const bf16x8*)(sB + (ct * 16 + rb) * AP1 + k0 + g * 8);
      acc[ct] = __builtin_amdgcn_mfma_f32_16x16x32_bf16(a, b, acc[ct], 0, 0, 0);
    }
  }

  int mrow = m0 + w * 16 + g * 4;
#pragma unroll
  for (int ct = 0; ct < 5; ct++) {
    int col = ct * 16 + rb;
    if (col >= C1) continue;
    float bias = b1[h * C1 + col];
#pragma unroll
    for (int r = 0; r < 4; r++) {
      int m = mrow + r;
      if (m >= N_NODES) continue;
      float v = acc[ct][r] + bias;
      v = (v > 0.f) ? v : (__expf(v) - 1.f);
      hab[(size_t)m * K2PAD + h * C1 + col] = f2b(v);
    }
  }
}

/* ---------------- layer-2 GEMM via MFMA, split-K (unchanged) ---------------- */

__global__ __launch_bounds__(256) void k_gemm2m(const ushort_t* __restrict__ hab,
                                                const ushort_t* __restrict__ W2t,
                                                float* __restrict__ part) {
  __shared__ ushort_t sA[64 * AP2];
  __shared__ ushort_t sB[112 * AP2];
  int m0 = blockIdx.x * 64;
  int kz = blockIdx.y * K2CHUNK;
  int tid = threadIdx.x;
  int w = tid >> 6, l = tid & 63;
  int rb = l & 15, g = l >> 4;
  f32x4 acc[7] = {};

  for (int ks = 0; ks < K2CHUNK; ks += 32) {
    int kbase = kz + ks;
    {
      int r = tid >> 2, cx = tid & 3;
      uint4 v = make_uint4(0, 0, 0, 0);
      int m = m0 + r;
      if (m < N_NODES) v = *(const uint4*)(hab + (size_t)m * K2PAD + kbase + cx * 8);
      *(uint4*)(sA + r * AP2 + cx * 8) = v;
    }
    for (int i = tid; i < 112 * 4; i += 256) {
      int c = i >> 2, cx = i & 3;
      uint4 v = *(const uint4*)(W2t + (size_t)c * K2PAD + kbase + cx * 8);
      *(uint4*)(sB + c * AP2 + cx * 8) = v;
    }
    __syncthreads();
    bf16x8 a = *(const bf16x8*)(sA + (w * 16 + rb) * AP2 + g * 8);
#pragma unroll
    for (int ct = 0; ct < 7; ct++) {
      bf16x8 b = *(const bf16x8*)(sB + (ct * 16 + rb) * AP2 + g * 8);
      acc[ct] = __builtin_amdgcn_mfma_f32_16x16x32_bf16(a, b, acc[ct], 0, 0, 0);
    }
    __syncthreads();
  }

  float* P = part + (size_t)blockIdx.y * N_NODES * C2;
  int mrow = m0 + w * 16 + g * 4;
#pragma unroll
  for (int ct = 0; ct < 7; ct++) {
    int col = ct * 16 + rb;
    if (col >= C2) continue;
#pragma unroll
    for (int r = 0; r < 4; r++) {
      int m = mrow + r;
      if (m < N_NODES) P[(size_t)m * C2 + col] = acc[ct][r];
    }
  }
}

/* ---------------- fused reduce + layer-2 logits: wave per node ---------------- */

__global__ __launch_bounds__(256) void k_redalpha(const float* __restrict__ part,
                                                  const float* __restrict__ a_src,
                                                  const float* __restrict__ a_dst,
                                                  ushort_t* __restrict__ z2b,
                                                  float* __restrict__ as2,
                                                  float* __restrict__ ad2) {
  int wid = (blockIdx.x * 256 + threadIdx.x) >> 6;
  int lane = threadIdx.x & 63;
  if (wid >= N_NODES) return;
  float ps = 0.f, pd = 0.f;
  if (lane < C2 / 2) {
    float2 s = make_float2(0.f, 0.f);
#pragma unroll
    for (int c = 0; c < KSPLIT; c++) {
      float2 v = *(const float2*)(part + (size_t)c * N_NODES * C2 + (size_t)wid * C2 + 2 * lane);
      s.x += v.x; s.y += v.y;
    }
    ushort2 o; o.x = f2b(s.x); o.y = f2b(s.y);
    *(ushort2*)(z2b + (size_t)wid * C2 + 2 * lane) = o;
    ps = s.x * a_src[2 * lane] + s.y * a_src[2 * lane + 1];
    pd = s.x * a_dst[2 * lane] + s.y * a_dst[2 * lane + 1];
  }
#pragma unroll
  for (int o = 32; o; o >>= 1) { ps += __shfl_xor(ps, o); pd += __shfl_xor(pd, o); }
  if (lane == 0) { as2[wid] = ps; ad2[wid] = pd; }
}

/* ---------------- layer-2 edge weights (with zero sentinel) ---------------- */

__global__ void k_ex2(const float* __restrict__ as2, const float* __restrict__ ad2,
                      const int* __restrict__ srcs, const int* __restrict__ dsts,
                      float* __restrict__ ex2) {
  int e = blockIdx.x * blockDim.x + threadIdx.x;
  if (e > E_TOT) return;
  if (e == E_TOT) { ex2[e] = 0.f; return; }
  float v = as2[srcs[e]] + ad2[dsts[e]];
  ex2[e] = __expf(lrelu(v));
}

/* ---------------- layer-2 aggregation + bias + ReLU + pool, group-8, fused denom -- */

__global__ __launch_bounds__(256) void k_gat2v3(const ushort_t* __restrict__ z2b,
                                                const float* __restrict__ ex2,
                                                const int* __restrict__ offs,
                                                const int* __restrict__ srcs,
                                                const float* __restrict__ b2,
                                                const int* __restrict__ batch,
                                                unsigned int* __restrict__ pool) {
  int wid = (blockIdx.x * 256 + threadIdx.x) >> 6;
  int lane = threadIdx.x & 63;
  if (wid >= N_NODES) return;
  int n = wid;
  int beg = offs[n], deg = offs[n + 1] - beg;
  const unsigned int* zrow = (const unsigned int*)z2b;

  float acc0 = 0.f, acc1 = 0.f, sum = 0.f;

  for (int j = 0; j < deg; j += 8) {
    int ej[8], sj[8];
#pragma unroll
    for (int q = 0; q < 8; q++) {
      int jj = j + q;
      bool v = jj < deg;
      ej[q] = v ? beg + jj : E_TOT;
      sj[q] = srcs[v ? beg + jj : beg];
    }
    float p[8];
#pragma unroll
    for (int q = 0; q < 8; q++) p[q] = ex2[ej[q]];
    unsigned int z[8] = {0, 0, 0, 0, 0, 0, 0, 0};
    if (lane < C2 / 2) {
#pragma unroll
      for (int q = 0; q < 8; q++) z[q] = zrow[(size_t)sj[q] * (C2 / 2) + lane];
    }
#pragma unroll
    for (int q = 0; q < 8; q++) {
      acc0 += p[q] * bf_lo(z[q]);
      acc1 += p[q] * bf_hi(z[q]);
      sum += p[q];
    }
  }

  if (lane < C2 / 2) {
    float iv = 1.f / (sum + 1e-16f);
    float v0 = fmaxf(acc0 * iv + b2[2 * lane], 0.f);
    float v1 = fmaxf(acc1 * iv + b2[2 * lane + 1], 0.f);
    int g = batch[n];
    atomicMax(&pool[g * C2 + 2 * lane], __float_as_uint(v0));
    atomicMax(&pool[g * C2 + 2 * lane + 1], __float_as_uint(v1));
  }
}

/* ---------------- head: out = relu(pool @ Wg + bg) ---------------- */

__global__ __launch_bounds__(128) void k_head(const float* __restrict__ pool,
                                              const float* __restrict__ Wg,
                                              const float* __restrict__ bg,
                                              float* __restrict__ out) {
  __shared__ float row[C2];
  int g = blockIdx.x;
  if (threadIdx.x < C2) row[threadIdx.x] = pool[g * C2 + threadIdx.x];
  __syncthreads();
  int c = threadIdx.x;
  if (c < C2) {
    float acc = bg[c];
    for (int k = 0; k < C2; k++) acc += row[k] * Wg[k * C2 + c];
    out[g * C2 + c] = fmaxf(acc, 0.f);
  }
}

/* ---------------- launch ---------------- */

extern "C" void kernel_launch(void* const* d_in, const int* in_sizes, int n_in,
                              void* d_out, int out_size, void* d_ws, size_t ws_size,
                              hipStream_t stream) {
  const float* x      = (const float*)d_in[0];
  const int*   ei     = (const int*)d_in[1];
  const int*   batch  = (const int*)d_in[2];
  const float* W1     = (const float*)d_in[4];
  const float* a_src1 = (const float*)d_in[5];
  const float* a_dst1 = (const float*)d_in[6];
  const float* b1     = (const float*)d_in[7];
  const float* W2     = (const float*)d_in[8];
  const float* a_src2 = (const float*)d_in[9];
  const float* a_dst2 = (const float*)d_in[10];
  const float* b2     = (const float*)d_in[11];
  const float* Wg     = (const float*)d_in[12];
  const float* bg     = (const float*)d_in[13];
  float* out = (float*)d_out;

  char* w = (char*)d_ws;
  size_t off = 0;
  auto alloc = [&](size_t bytes) -> void* {
    void* p = w + off;
    off += (bytes + 255) & ~(size_t)255;
    return p;
  };

  ushort_t* xb  = (ushort_t*)alloc((size_t)H1 * N_NODES * K1PAD * 2);  /* 38.4 MB */
  ushort_t* hab = (ushort_t*)alloc((size_t)N_NODES * K2PAD * 2);       /* 32 MB  */
  float* part   = (float*)alloc((size_t)KSPLIT * N_NODES * C2 * 4);    /* 40 MB  */
  float* asb    = (float*)alloc((size_t)N_NODES * HP * 4);             /* 0.96 MB */
  float* adb    = (float*)alloc((size_t)N_NODES * HP * 4);
  float* ex1    = (float*)alloc((size_t)(E_TOT + 1) * HP * 4);         /* 16.3 MB */
  ushort_t* xbf = (ushort_t*)alloc((size_t)N_NODES * 80 * 2);          /* 3.2 MB */
  float* Vs     = (float*)alloc((size_t)H1 * C1 * 4);
  float* Vd     = (float*)alloc((size_t)H1 * C1 * 4);
  ushort_t* W1t = (ushort_t*)alloc((size_t)H1 * 80 * K1PAD * 2);
  ushort_t* W2t = (ushort_t*)alloc((size_t)112 * K2PAD * 2);
  /* cnt / cursor / pool: one contiguous zero region */
  int* cnt           = (int*)alloc((size_t)N_NODES * 4);
  int* cursor        = (int*)alloc((size_t)N_NODES * 4);
  unsigned int* pool = (unsigned int*)alloc((size_t)N_GRAPHS * C2 * 4);
  size_t zspan = (size_t)((char*)(pool + (size_t)N_GRAPHS * C2) - (char*)cnt);
  int* offs   = (int*)alloc((size_t)(N_NODES + 1) * 4);
  int* srcs   = (int*)alloc((size_t)E_TOT * 4);
  int* dsts   = (int*)alloc((size_t)E_TOT * 4);

  /* layer-2 buffers alias xb (dead after k_bgemm_m): ~5.7 MB < 38.4 MB */
  float* as2    = (float*)xb;
  float* ad2    = as2 + N_NODES;
  ushort_t* z2b = (ushort_t*)(ad2 + N_NODES);
  float* ex2    = (float*)(z2b + (size_t)N_NODES * C2);

  hipMemsetAsync(cnt, 0, zspan, stream);

  k_count<<<(E_TOT + 255) / 256, 256, 0, stream>>>(ei, cnt);
  k_scan<<<1, 1024, 0, stream>>>(cnt, offs, N_NODES);
  k_scatter<<<(E_TOT + 255) / 256, 256, 0, stream>>>(ei, offs, cursor, srcs, dsts);

  k_prep<<<(PR0 + PR1 + PR2 + PR3 + PR4 + 255) / 256, 256, 0, stream>>>(
      W1, a_src1, a_dst1, W2, x, Vs, Vd, W1t, W2t, hab, xbf);
  k_alpha1x<<<(N_NODES * H1 + 255) / 256, 256, 0, stream>>>(x, Vs, Vd, asb, adb);
  k_ex1<<<(E_TOT + 1 + 255) / 256, 256, 0, stream>>>(asb, adb, srcs, dsts, ex1);
  k_aggv3<<<(N_NODES + 3) / 4, 256, 0, stream>>>(xbf, ex1, offs, srcs, xb);
  k_bgemm_m<<<dim3((N_NODES + 63) / 64, H1), 256, 0, stream>>>(xb, W1t, b1, hab);

  k_gemm2m<<<dim3((N_NODES + 63) / 64, KSPLIT), 256, 0, stream>>>(hab, W2t, part);
  k_redalpha<<<(N_NODES + 3) / 4, 256, 0, stream>>>(part, a_src2, a_dst2, z2b, as2, ad2);
  k_ex2<<<(E_TOT + 1 + 255) / 256, 256, 0, stream>>>(as2, ad2, srcs, dsts, ex2);
  k_gat2v3<<<(N_NODES + 3) / 4, 256, 0, stream>>>(z2b, ex2, offs, srcs, b2, batch, pool);
  k_head<<<N_GRAPHS, 128, 0, stream>>>((const float*)pool, Wg, bg, out);
}

// Round 9
// 280.845 us; speedup vs baseline: 10.1316x; 1.0528x over previous
//
#include <hip/hip_runtime.h>
#include <hip/hip_bf16.h>

#define N_NODES  20000
#define N_EDGES  320000
#define E_TOT    (N_EDGES + N_NODES)   /* 340000 incl. self loops */
#define N_GRAPHS 512
#define H1 10
#define C1 78
#define F1 780                          /* H1*C1 */
#define C2 100
#define NEG_SLOPE 0.2f
#define KSPLIT 5
#define K1PAD 96                        /* layer-1 K (78) padded to 3x32 */
#define K2PAD 800                       /* layer-2 K (780) padded to 25x32 */
#define K2CHUNK 160                     /* 800 / KSPLIT */
#define AP1 104                         /* LDS row stride (bf16) for bgemm */
#define AP2 40                          /* LDS row stride for gemm2 */
#define HP 12                           /* padded head stride for asb/adb */

typedef short bf16x8 __attribute__((ext_vector_type(8)));
typedef float f32x4 __attribute__((ext_vector_type(4)));
typedef unsigned short ushort_t;

__device__ __forceinline__ float bf_lo(unsigned int u) { return __uint_as_float(u << 16); }
__device__ __forceinline__ float bf_hi(unsigned int u) { return __uint_as_float(u & 0xFFFF0000u); }
__device__ __forceinline__ ushort_t f2b(float v) {
  __hip_bfloat16 b = __float2bfloat16(v);   /* RNE */
  return *reinterpret_cast<ushort_t*>(&b);
}
__device__ __forceinline__ float lrelu(float v) { return (v > 0.f) ? v : NEG_SLOPE * v; }

/* ---------------- CSR build (by destination) ---------------- */

__global__ void k_count(const int* __restrict__ ei, int* __restrict__ cnt) {
  int e = blockIdx.x * blockDim.x + threadIdx.x;
  if (e >= E_TOT) return;
  int dst = (e < N_EDGES) ? ei[N_EDGES + e] : (e - N_EDGES);
  atomicAdd(&cnt[dst], 1);
}

__global__ __launch_bounds__(1024) void k_scan(const int* __restrict__ cnt,
                                               int* __restrict__ offs, int n) {
  const int PER = 20;
  int t = threadIdx.x;
  int lane = t & 63, wv = t >> 6;
  int base = t * PER;
  int loc[PER];
  int run = 0;
#pragma unroll
  for (int k = 0; k < PER; k++) {
    int idx = base + k;
    int v = (idx < n) ? cnt[idx] : 0;
    run += v;
    loc[k] = run;
  }
  int total = run;
  int sc = total;
#pragma unroll
  for (int o = 1; o < 64; o <<= 1) {
    int u = __shfl_up(sc, o);
    if (lane >= o) sc += u;
  }
  __shared__ int ws[16];
  if (lane == 63) ws[wv] = sc;
  __syncthreads();
  if (t == 0) {
    int r = 0;
#pragma unroll
    for (int i = 0; i < 16; i++) { int v = ws[i]; ws[i] = r; r += v; }
  }
  __syncthreads();
  int excl = ws[wv] + sc - total;
#pragma unroll
  for (int k = 0; k < PER; k++) {
    int idx = base + k;
    if (idx < n) offs[idx + 1] = excl + loc[k];
  }
  if (t == 0) offs[0] = 0;
}

__global__ void k_scatter(const int* __restrict__ ei, const int* __restrict__ offs,
                          int* __restrict__ cursor, int* __restrict__ srcs,
                          int* __restrict__ dsts) {
  int e = blockIdx.x * blockDim.x + threadIdx.x;
  if (e >= E_TOT) return;
  int src, dst;
  if (e < N_EDGES) { src = ei[e]; dst = ei[N_EDGES + e]; }
  else             { src = dst = e - N_EDGES; }
  int pos = offs[dst] + atomicAdd(&cursor[dst], 1);
  srcs[pos] = src;
  dsts[pos] = dst;
}

/* ---------------- fused prep: Vs/Vd + W1t + W2t + hab K-pad zero + x->bf16 -------- */

#define PR0 (2 * H1 * C1)
#define PR1 (H1 * 80 * K1PAD)
#define PR2 (112 * K2PAD)
#define PR3 (N_NODES * (K2PAD - F1))
#define PR4 (N_NODES * 40)

__global__ void k_prep(const float* __restrict__ W1, const float* __restrict__ a_src,
                       const float* __restrict__ a_dst, const float* __restrict__ W2,
                       const float* __restrict__ x,
                       float* __restrict__ Vs, float* __restrict__ Vd,
                       ushort_t* __restrict__ W1t, ushort_t* __restrict__ W2t,
                       ushort_t* __restrict__ hab, ushort_t* __restrict__ xbf) {
  int t = blockIdx.x * blockDim.x + threadIdx.x;
  if (t < PR0) {
    int which = (t >= H1 * C1) ? 1 : 0;
    int r = t - which * H1 * C1;
    int h = r / C1, k = r - h * C1;
    const float* a = which ? a_dst : a_src;
    float s = 0.f;
    for (int c = 0; c < C1; c++) s += W1[(size_t)k * F1 + h * C1 + c] * a[h * C1 + c];
    (which ? Vd : Vs)[h * C1 + k] = s;
    return;
  }
  t -= PR0;
  if (t < PR1) {
    int h = t / (80 * K1PAD);
    int rem = t - h * 80 * K1PAD;
    int c = rem / K1PAD, k = rem - c * K1PAD;
    float v = (c < C1 && k < C1) ? W1[(size_t)k * F1 + h * C1 + c] : 0.f;
    W1t[t] = f2b(v);
    return;
  }
  t -= PR1;
  if (t < PR2) {
    int c = t / K2PAD, k = t - c * K2PAD;
    float v = (c < C2 && k < F1) ? W2[(size_t)k * C2 + c] : 0.f;
    W2t[t] = f2b(v);
    return;
  }
  t -= PR2;
  if (t < PR3) {
    int n = t / (K2PAD - F1), j = t - n * (K2PAD - F1);
    hab[(size_t)n * K2PAD + F1 + j] = 0;
    return;
  }
  t -= PR3;
  if (t < PR4) {
    int n = t / 40, c2 = t - n * 40;
    ushort2 o;
    if (c2 < 39) { o.x = f2b(x[(size_t)n * C1 + 2 * c2]); o.y = f2b(x[(size_t)n * C1 + 2 * c2 + 1]); }
    else         { o.x = 0; o.y = 0; }
    *(ushort2*)(xbf + (size_t)n * 80 + 2 * c2) = o;
  }
}

/* ---------------- layer-1 logits: asb[n][12] node-major ---------------- */

__global__ __launch_bounds__(256) void k_alpha1x(const float* __restrict__ x,
                                                 const float* __restrict__ Vs,
                                                 const float* __restrict__ Vd,
                                                 float* __restrict__ asb,
                                                 float* __restrict__ adb) {
  __shared__ float sVs[H1 * C1], sVd[H1 * C1];
  for (int i = threadIdx.x; i < H1 * C1; i += 256) { sVs[i] = Vs[i]; sVd[i] = Vd[i]; }
  __syncthreads();
  int t = blockIdx.x * 256 + threadIdx.x;
  if (t >= N_NODES * H1) return;
  int n = t / H1, h = t - n * H1;
  const float2* row = (const float2*)(x + (size_t)n * C1);
  const float2* vs2 = (const float2*)(sVs + h * C1);
  const float2* vd2 = (const float2*)(sVd + h * C1);
  float s0 = 0.f, s1 = 0.f;
#pragma unroll 13
  for (int i = 0; i < C1 / 2; i++) {
    float2 v = row[i];
    float2 a = vs2[i];
    float2 b = vd2[i];
    s0 += v.x * a.x + v.y * a.y;
    s1 += v.x * b.x + v.y * b.y;
  }
  asb[(size_t)n * HP + h] = s0;
  adb[(size_t)n * HP + h] = s1;
}

/* ---------------- edge-parallel weights: ex1[e][10] bf16-packed (5 dwords) -------- */

__global__ void k_ex1(const float* __restrict__ asb, const float* __restrict__ adb,
                      const int* __restrict__ srcs, const int* __restrict__ dsts,
                      unsigned int* __restrict__ ex1) {
  int e = blockIdx.x * blockDim.x + threadIdx.x;
  if (e > E_TOT) return;
  unsigned int* o = ex1 + (size_t)e * 5;
  if (e == E_TOT) {   /* zero sentinel row for pair-padding */
#pragma unroll
    for (int q = 0; q < 5; q++) o[q] = 0u;
    return;
  }
  int s = srcs[e], d = dsts[e];
  const float* pa = asb + (size_t)s * HP;
  const float* pd = adb + (size_t)d * HP;
  float4 a0 = *(const float4*)pa, a1 = *(const float4*)(pa + 4);
  float2 a2 = *(const float2*)(pa + 8);
  float4 d0 = *(const float4*)pd, d1 = *(const float4*)(pd + 4);
  float2 d2 = *(const float2*)(pd + 8);
  float r[10];
  r[0] = __expf(lrelu(a0.x + d0.x)); r[1] = __expf(lrelu(a0.y + d0.y));
  r[2] = __expf(lrelu(a0.z + d0.z)); r[3] = __expf(lrelu(a0.w + d0.w));
  r[4] = __expf(lrelu(a1.x + d1.x)); r[5] = __expf(lrelu(a1.y + d1.y));
  r[6] = __expf(lrelu(a1.z + d1.z)); r[7] = __expf(lrelu(a1.w + d1.w));
  r[8] = __expf(lrelu(a2.x + d2.x)); r[9] = __expf(lrelu(a2.y + d2.y));
#pragma unroll
  for (int q = 0; q < 5; q++)
    o[q] = (unsigned int)f2b(r[2 * q]) | ((unsigned int)f2b(r[2 * q + 1]) << 16);
}

/* ---------------- layer-1 aggregation: wave per dst, 2-edge pairs, fused denom ----
   xb[h][n][96] = bf16( (1/sum ex) * sum_e ex1[e][h] * xbf[src_e][c] )               */

__global__ __launch_bounds__(256) void k_aggv4(const ushort_t* __restrict__ xbf,
                                               const unsigned int* __restrict__ ex1,
                                               const int* __restrict__ offs,
                                               const int* __restrict__ srcs,
                                               ushort_t* __restrict__ xb) {
  int wid = (blockIdx.x * 256 + threadIdx.x) >> 6;
  int lane = threadIdx.x & 63;
  if (wid >= N_NODES) return;
  int n = wid;
  int beg = offs[n], deg = offs[n + 1] - beg;

  float acc[H1][2] = {};
  float sum[H1] = {};

  for (int j = 0; j < deg; j += 2) {
    int e0 = beg + j;
    int s0 = srcs[e0];
    bool v1 = (j + 1) < deg;
    int e1 = v1 ? e0 + 1 : E_TOT;        /* sentinel row: all-zero weights */
    int s1 = v1 ? srcs[e0 + 1] : s0;
    unsigned int w0[5], w1[5];
#pragma unroll
    for (int q = 0; q < 5; q++) { w0[q] = ex1[(size_t)e0 * 5 + q]; w1[q] = ex1[(size_t)e1 * 5 + q]; }
    unsigned int xv0 = 0, xv1 = 0;
    if (lane < 39) {
      xv0 = *(const unsigned int*)(xbf + (size_t)s0 * 80 + 2 * lane);
      xv1 = *(const unsigned int*)(xbf + (size_t)s1 * 80 + 2 * lane);
    }
    float xl0 = bf_lo(xv0), xh0 = bf_hi(xv0);
    float xl1 = bf_lo(xv1), xh1 = bf_hi(xv1);
#pragma unroll
    for (int h = 0; h < H1; h++) {
      float p0 = (h & 1) ? bf_hi(w0[h >> 1]) : bf_lo(w0[h >> 1]);
      float p1 = (h & 1) ? bf_hi(w1[h >> 1]) : bf_lo(w1[h >> 1]);
      acc[h][0] += p0 * xl0 + p1 * xl1;
      acc[h][1] += p0 * xh0 + p1 * xh1;
      sum[h] += p0 + p1;
    }
  }

  if (lane < 48) {
    int colu = (lane < 39) ? 2 * lane : C1 + 2 * (lane - 39);   /* pad cols 78..95 */
#pragma unroll
    for (int h = 0; h < H1; h++) {
      float iv = 1.f / (sum[h] + 1e-16f);
      ushort2 o;
      if (lane < 39) { o.x = f2b(acc[h][0] * iv); o.y = f2b(acc[h][1] * iv); }
      else           { o.x = 0; o.y = 0; }
      *(ushort2*)(xb + ((size_t)h * N_NODES + n) * K1PAD + colu) = o;
    }
  }
}

/* ---------------- layer-1 block-diag GEMM via MFMA (unchanged) ---------------- */

__global__ __launch_bounds__(256) void k_bgemm_m(const ushort_t* __restrict__ xb,
                                                 const ushort_t* __restrict__ W1t,
                                                 const float* __restrict__ b1,
                                                 ushort_t* __restrict__ hab) {
  __shared__ ushort_t sA[64 * AP1];
  __shared__ ushort_t sB[80 * AP1];
  int h = blockIdx.y;
  int m0 = blockIdx.x * 64;
  int tid = threadIdx.x;

  for (int i = tid; i < 64 * 12; i += 256) {
    int r = i / 12, cx = i - r * 12;
    uint4 v = make_uint4(0, 0, 0, 0);
    int m = m0 + r;
    if (m < N_NODES) v = *(const uint4*)(xb + ((size_t)h * N_NODES + m) * K1PAD + cx * 8);
    *(uint4*)(sA + r * AP1 + cx * 8) = v;
  }
  for (int i = tid; i < 80 * 12; i += 256) {
    int c = i / 12, cx = i - c * 12;
    uint4 v = *(const uint4*)(W1t + ((size_t)h * 80 + c) * K1PAD + cx * 8);
    *(uint4*)(sB + c * AP1 + cx * 8) = v;
  }
  __syncthreads();

  int w = tid >> 6, l = tid & 63;
  int rb = l & 15, g = l >> 4;
  f32x4 acc[5] = {};
  const ushort_t* pa = sA + (w * 16 + rb) * AP1 + g * 8;
#pragma unroll
  for (int k0 = 0; k0 < K1PAD; k0 += 32) {
    bf16x8 a = *(const bf16x8*)(pa + k0);
#pragma unroll
    for (int ct = 0; ct < 5; ct++) {
      bf16x8 b = *(const bf16x8*)(sB + (ct * 16 + rb) * AP1 + k0 + g * 8);
      acc[ct] = __builtin_amdgcn_mfma_f32_16x16x32_bf16(a, b, acc[ct], 0, 0, 0);
    }
  }

  int mrow = m0 + w * 16 + g * 4;
#pragma unroll
  for (int ct = 0; ct < 5; ct++) {
    int col = ct * 16 + rb;
    if (col >= C1) continue;
    float bias = b1[h * C1 + col];
#pragma unroll
    for (int r = 0; r < 4; r++) {
      int m = mrow + r;
      if (m >= N_NODES) continue;
      float v = acc[ct][r] + bias;
      v = (v > 0.f) ? v : (__expf(v) - 1.f);
      hab[(size_t)m * K2PAD + h * C1 + col] = f2b(v);
    }
  }
}

/* ---------------- layer-2 GEMM via MFMA, split-K (unchanged) ---------------- */

__global__ __launch_bounds__(256) void k_gemm2m(const ushort_t* __restrict__ hab,
                                                const ushort_t* __restrict__ W2t,
                                                float* __restrict__ part) {
  __shared__ ushort_t sA[64 * AP2];
  __shared__ ushort_t sB[112 * AP2];
  int m0 = blockIdx.x * 64;
  int kz = blockIdx.y * K2CHUNK;
  int tid = threadIdx.x;
  int w = tid >> 6, l = tid & 63;
  int rb = l & 15, g = l >> 4;
  f32x4 acc[7] = {};

  for (int ks = 0; ks < K2CHUNK; ks += 32) {
    int kbase = kz + ks;
    {
      int r = tid >> 2, cx = tid & 3;
      uint4 v = make_uint4(0, 0, 0, 0);
      int m = m0 + r;
      if (m < N_NODES) v = *(const uint4*)(hab + (size_t)m * K2PAD + kbase + cx * 8);
      *(uint4*)(sA + r * AP2 + cx * 8) = v;
    }
    for (int i = tid; i < 112 * 4; i += 256) {
      int c = i >> 2, cx = i & 3;
      uint4 v = *(const uint4*)(W2t + (size_t)c * K2PAD + kbase + cx * 8);
      *(uint4*)(sB + c * AP2 + cx * 8) = v;
    }
    __syncthreads();
    bf16x8 a = *(const bf16x8*)(sA + (w * 16 + rb) * AP2 + g * 8);
#pragma unroll
    for (int ct = 0; ct < 7; ct++) {
      bf16x8 b = *(const bf16x8*)(sB + (ct * 16 + rb) * AP2 + g * 8);
      acc[ct] = __builtin_amdgcn_mfma_f32_16x16x32_bf16(a, b, acc[ct], 0, 0, 0);
    }
    __syncthreads();
  }

  float* P = part + (size_t)blockIdx.y * N_NODES * C2;
  int mrow = m0 + w * 16 + g * 4;
#pragma unroll
  for (int ct = 0; ct < 7; ct++) {
    int col = ct * 16 + rb;
    if (col >= C2) continue;
#pragma unroll
    for (int r = 0; r < 4; r++) {
      int m = mrow + r;
      if (m < N_NODES) P[(size_t)m * C2 + col] = acc[ct][r];
    }
  }
}

/* ---------------- fused reduce + layer-2 logits: wave per node ---------------- */

__global__ __launch_bounds__(256) void k_redalpha(const float* __restrict__ part,
                                                  const float* __restrict__ a_src,
                                                  const float* __restrict__ a_dst,
                                                  ushort_t* __restrict__ z2b,
                                                  float* __restrict__ as2,
                                                  float* __restrict__ ad2) {
  int wid = (blockIdx.x * 256 + threadIdx.x) >> 6;
  int lane = threadIdx.x & 63;
  if (wid >= N_NODES) return;
  float ps = 0.f, pd = 0.f;
  if (lane < C2 / 2) {
    float2 s = make_float2(0.f, 0.f);
#pragma unroll
    for (int c = 0; c < KSPLIT; c++) {
      float2 v = *(const float2*)(part + (size_t)c * N_NODES * C2 + (size_t)wid * C2 + 2 * lane);
      s.x += v.x; s.y += v.y;
    }
    ushort2 o; o.x = f2b(s.x); o.y = f2b(s.y);
    *(ushort2*)(z2b + (size_t)wid * C2 + 2 * lane) = o;
    ps = s.x * a_src[2 * lane] + s.y * a_src[2 * lane + 1];
    pd = s.x * a_dst[2 * lane] + s.y * a_dst[2 * lane + 1];
  }
#pragma unroll
  for (int o = 32; o; o >>= 1) { ps += __shfl_xor(ps, o); pd += __shfl_xor(pd, o); }
  if (lane == 0) { as2[wid] = ps; ad2[wid] = pd; }
}

/* ---------------- layer-2 edge weights (with zero sentinel) ---------------- */

__global__ void k_ex2(const float* __restrict__ as2, const float* __restrict__ ad2,
                      const int* __restrict__ srcs, const int* __restrict__ dsts,
                      float* __restrict__ ex2) {
  int e = blockIdx.x * blockDim.x + threadIdx.x;
  if (e > E_TOT) return;
  if (e == E_TOT) { ex2[e] = 0.f; return; }
  float v = as2[srcs[e]] + ad2[dsts[e]];
  ex2[e] = __expf(lrelu(v));
}

/* ---------------- layer-2 aggregation + bias + ReLU + pool, group-8, fused denom -- */

__global__ __launch_bounds__(256) void k_gat2v3(const ushort_t* __restrict__ z2b,
                                                const float* __restrict__ ex2,
                                                const int* __restrict__ offs,
                                                const int* __restrict__ srcs,
                                                const float* __restrict__ b2,
                                                const int* __restrict__ batch,
                                                unsigned int* __restrict__ pool) {
  int wid = (blockIdx.x * 256 + threadIdx.x) >> 6;
  int lane = threadIdx.x & 63;
  if (wid >= N_NODES) return;
  int n = wid;
  int beg = offs[n], deg = offs[n + 1] - beg;
  const unsigned int* zrow = (const unsigned int*)z2b;

  float acc0 = 0.f, acc1 = 0.f, sum = 0.f;

  for (int j = 0; j < deg; j += 8) {
    int ej[8], sj[8];
#pragma unroll
    for (int q = 0; q < 8; q++) {
      int jj = j + q;
      bool v = jj < deg;
      ej[q] = v ? beg + jj : E_TOT;
      sj[q] = srcs[v ? beg + jj : beg];
    }
    float p[8];
#pragma unroll
    for (int q = 0; q < 8; q++) p[q] = ex2[ej[q]];
    unsigned int z[8] = {0, 0, 0, 0, 0, 0, 0, 0};
    if (lane < C2 / 2) {
#pragma unroll
      for (int q = 0; q < 8; q++) z[q] = zrow[(size_t)sj[q] * (C2 / 2) + lane];
    }
#pragma unroll
    for (int q = 0; q < 8; q++) {
      acc0 += p[q] * bf_lo(z[q]);
      acc1 += p[q] * bf_hi(z[q]);
      sum += p[q];
    }
  }

  if (lane < C2 / 2) {
    float iv = 1.f / (sum + 1e-16f);
    float v0 = fmaxf(acc0 * iv + b2[2 * lane], 0.f);
    float v1 = fmaxf(acc1 * iv + b2[2 * lane + 1], 0.f);
    int g = batch[n];
    atomicMax(&pool[g * C2 + 2 * lane], __float_as_uint(v0));
    atomicMax(&pool[g * C2 + 2 * lane + 1], __float_as_uint(v1));
  }
}

/* ---------------- head: out = relu(pool @ Wg + bg) ---------------- */

__global__ __launch_bounds__(128) void k_head(const float* __restrict__ pool,
                                              const float* __restrict__ Wg,
                                              const float* __restrict__ bg,
                                              float* __restrict__ out) {
  __shared__ float row[C2];
  int g = blockIdx.x;
  if (threadIdx.x < C2) row[threadIdx.x] = pool[g * C2 + threadIdx.x];
  __syncthreads();
  int c = threadIdx.x;
  if (c < C2) {
    float acc = bg[c];
    for (int k = 0; k < C2; k++) acc += row[k] * Wg[k * C2 + c];
    out[g * C2 + c] = fmaxf(acc, 0.f);
  }
}

/* ---------------- launch ---------------- */

extern "C" void kernel_launch(void* const* d_in, const int* in_sizes, int n_in,
                              void* d_out, int out_size, void* d_ws, size_t ws_size,
                              hipStream_t stream) {
  const float* x      = (const float*)d_in[0];
  const int*   ei     = (const int*)d_in[1];
  const int*   batch  = (const int*)d_in[2];
  const float* W1     = (const float*)d_in[4];
  const float* a_src1 = (const float*)d_in[5];
  const float* a_dst1 = (const float*)d_in[6];
  const float* b1     = (const float*)d_in[7];
  const float* W2     = (const float*)d_in[8];
  const float* a_src2 = (const float*)d_in[9];
  const float* a_dst2 = (const float*)d_in[10];
  const float* b2     = (const float*)d_in[11];
  const float* Wg     = (const float*)d_in[12];
  const float* bg     = (const float*)d_in[13];
  float* out = (float*)d_out;

  char* w = (char*)d_ws;
  size_t off = 0;
  auto alloc = [&](size_t bytes) -> void* {
    void* p = w + off;
    off += (bytes + 255) & ~(size_t)255;
    return p;
  };

  ushort_t* xb  = (ushort_t*)alloc((size_t)H1 * N_NODES * K1PAD * 2);  /* 38.4 MB */
  ushort_t* hab = (ushort_t*)alloc((size_t)N_NODES * K2PAD * 2);       /* 32 MB  */
  float* part   = (float*)alloc((size_t)KSPLIT * N_NODES * C2 * 4);    /* 40 MB  */
  float* asb    = (float*)alloc((size_t)N_NODES * HP * 4);             /* 0.96 MB */
  float* adb    = (float*)alloc((size_t)N_NODES * HP * 4);
  unsigned int* ex1 = (unsigned int*)alloc((size_t)(E_TOT + 1) * 5 * 4); /* 6.8 MB */
  ushort_t* xbf = (ushort_t*)alloc((size_t)N_NODES * 80 * 2);          /* 3.2 MB */
  float* Vs     = (float*)alloc((size_t)H1 * C1 * 4);
  float* Vd     = (float*)alloc((size_t)H1 * C1 * 4);
  ushort_t* W1t = (ushort_t*)alloc((size_t)H1 * 80 * K1PAD * 2);
  ushort_t* W2t = (ushort_t*)alloc((size_t)112 * K2PAD * 2);
  /* cnt / cursor / pool: one contiguous zero region */
  int* cnt           = (int*)alloc((size_t)N_NODES * 4);
  int* cursor        = (int*)alloc((size_t)N_NODES * 4);
  unsigned int* pool = (unsigned int*)alloc((size_t)N_GRAPHS * C2 * 4);
  size_t zspan = (size_t)((char*)(pool + (size_t)N_GRAPHS * C2) - (char*)cnt);
  int* offs   = (int*)alloc((size_t)(N_NODES + 1) * 4);
  int* srcs   = (int*)alloc((size_t)E_TOT * 4);
  int* dsts   = (int*)alloc((size_t)E_TOT * 4);

  /* layer-2 buffers alias xb (dead after k_bgemm_m): ~5.7 MB < 38.4 MB */
  float* as2    = (float*)xb;
  float* ad2    = as2 + N_NODES;
  ushort_t* z2b = (ushort_t*)(ad2 + N_NODES);
  float* ex2    = (float*)(z2b + (size_t)N_NODES * C2);

  hipMemsetAsync(cnt, 0, zspan, stream);

  k_count<<<(E_TOT + 255) / 256, 256, 0, stream>>>(ei, cnt);
  k_scan<<<1, 1024, 0, stream>>>(cnt, offs, N_NODES);
  k_scatter<<<(E_TOT + 255) / 256, 256, 0, stream>>>(ei, offs, cursor, srcs, dsts);

  k_prep<<<(PR0 + PR1 + PR2 + PR3 + PR4 + 255) / 256, 256, 0, stream>>>(
      W1, a_src1, a_dst1, W2, x, Vs, Vd, W1t, W2t, hab, xbf);
  k_alpha1x<<<(N_NODES * H1 + 255) / 256, 256, 0, stream>>>(x, Vs, Vd, asb, adb);
  k_ex1<<<(E_TOT + 1 + 255) / 256, 256, 0, stream>>>(asb, adb, srcs, dsts, ex1);
  k_aggv4<<<(N_NODES + 3) / 4, 256, 0, stream>>>(xbf, ex1, offs, srcs, xb);
  k_bgemm_m<<<dim3((N_NODES + 63) / 64, H1), 256, 0, stream>>>(xb, W1t, b1, hab);

  k_gemm2m<<<dim3((N_NODES + 63) / 64, KSPLIT), 256, 0, stream>>>(hab, W2t, part);
  k_redalpha<<<(N_NODES + 3) / 4, 256, 0, stream>>>(part, a_src2, a_dst2, z2b, as2, ad2);
  k_ex2<<<(E_TOT + 1 + 255) / 256, 256, 0, stream>>>(as2, ad2, srcs, dsts, ex2);
  k_gat2v3<<<(N_NODES + 3) / 4, 256, 0, stream>>>(z2b, ex2, offs, srcs, b2, batch, pool);
  k_head<<<N_GRAPHS, 128, 0, stream>>>((const float*)pool, Wg, bg, out);
}

// Round 10
// 275.650 us; speedup vs baseline: 10.3225x; 1.0188x over previous
//
#include <hip/hip_runtime.h>
#include <hip/hip_bf16.h>

#define N_NODES  20000
#define N_EDGES  320000
#define E_TOT    (N_EDGES + N_NODES)   /* 340000 incl. self loops */
#define N_GRAPHS 512
#define H1 10
#define C1 78
#define F1 780                          /* H1*C1 */
#define C2 100
#define NEG_SLOPE 0.2f
#define KSPLIT 5
#define K1PAD 96                        /* layer-1 K (78) padded to 3x32 */
#define K2PAD 800                       /* layer-2 K (780) padded to 25x32 */
#define K2CHUNK 160                     /* 800 / KSPLIT */
#define AP1 104                         /* LDS row stride (bf16) for bgemm */
#define AP2 40                          /* LDS row stride for gemm2 */
#define HP 12                           /* padded head stride for asb/adb */

typedef short bf16x8 __attribute__((ext_vector_type(8)));
typedef float f32x4 __attribute__((ext_vector_type(4)));
typedef _Float16 half2v __attribute__((ext_vector_type(2)));
typedef unsigned short ushort_t;

__device__ __forceinline__ float bf_lo(unsigned int u) { return __uint_as_float(u << 16); }
__device__ __forceinline__ float bf_hi(unsigned int u) { return __uint_as_float(u & 0xFFFF0000u); }
__device__ __forceinline__ ushort_t f2b(float v) {
  __hip_bfloat16 b = __float2bfloat16(v);   /* RNE */
  return *reinterpret_cast<ushort_t*>(&b);
}
__device__ __forceinline__ ushort_t f2h(float v) {
  _Float16 h = (_Float16)v;                 /* RNE */
  return *reinterpret_cast<ushort_t*>(&h);
}
__device__ __forceinline__ float lrelu(float v) { return (v > 0.f) ? v : NEG_SLOPE * v; }
__device__ __forceinline__ float dot2h(unsigned int a, unsigned int b, float c) {
  union { unsigned int u; half2v v; } A, B;
  A.u = a; B.u = b;
  return __builtin_amdgcn_fdot2(A.v, B.v, c, false);
}

/* ---------------- CSR build (by destination) ---------------- */

__global__ void k_count(const int* __restrict__ ei, int* __restrict__ cnt) {
  int e = blockIdx.x * blockDim.x + threadIdx.x;
  if (e >= E_TOT) return;
  int dst = (e < N_EDGES) ? ei[N_EDGES + e] : (e - N_EDGES);
  atomicAdd(&cnt[dst], 1);
}

__global__ __launch_bounds__(1024) void k_scan(const int* __restrict__ cnt,
                                               int* __restrict__ offs, int n) {
  const int PER = 20;
  int t = threadIdx.x;
  int lane = t & 63, wv = t >> 6;
  int base = t * PER;
  int loc[PER];
  int run = 0;
#pragma unroll
  for (int k = 0; k < PER; k++) {
    int idx = base + k;
    int v = (idx < n) ? cnt[idx] : 0;
    run += v;
    loc[k] = run;
  }
  int total = run;
  int sc = total;
#pragma unroll
  for (int o = 1; o < 64; o <<= 1) {
    int u = __shfl_up(sc, o);
    if (lane >= o) sc += u;
  }
  __shared__ int ws[16];
  if (lane == 63) ws[wv] = sc;
  __syncthreads();
  if (t == 0) {
    int r = 0;
#pragma unroll
    for (int i = 0; i < 16; i++) { int v = ws[i]; ws[i] = r; r += v; }
  }
  __syncthreads();
  int excl = ws[wv] + sc - total;
#pragma unroll
  for (int k = 0; k < PER; k++) {
    int idx = base + k;
    if (idx < n) offs[idx + 1] = excl + loc[k];
  }
  if (t == 0) offs[0] = 0;
}

__global__ void k_scatter(const int* __restrict__ ei, const int* __restrict__ offs,
                          int* __restrict__ cursor, int* __restrict__ srcs,
                          int* __restrict__ dsts) {
  int e = blockIdx.x * blockDim.x + threadIdx.x;
  if (e >= E_TOT) return;
  int src, dst;
  if (e < N_EDGES) { src = ei[e]; dst = ei[N_EDGES + e]; }
  else             { src = dst = e - N_EDGES; }
  int pos = offs[dst] + atomicAdd(&cursor[dst], 1);
  srcs[pos] = src;
  dsts[pos] = dst;
}

/* ---------------- fused prep: Vs/Vd + W1t + W2t + hab K-pad zero + x->fp16 -------- */

#define PR0 (2 * H1 * C1)
#define PR1 (H1 * 80 * K1PAD)
#define PR2 (112 * K2PAD)
#define PR3 (N_NODES * (K2PAD - F1))
#define PR4 (N_NODES * 40)

__global__ void k_prep(const float* __restrict__ W1, const float* __restrict__ a_src,
                       const float* __restrict__ a_dst, const float* __restrict__ W2,
                       const float* __restrict__ x,
                       float* __restrict__ Vs, float* __restrict__ Vd,
                       ushort_t* __restrict__ W1t, ushort_t* __restrict__ W2t,
                       ushort_t* __restrict__ hab, ushort_t* __restrict__ xhf) {
  int t = blockIdx.x * blockDim.x + threadIdx.x;
  if (t < PR0) {
    int which = (t >= H1 * C1) ? 1 : 0;
    int r = t - which * H1 * C1;
    int h = r / C1, k = r - h * C1;
    const float* a = which ? a_dst : a_src;
    float s = 0.f;
    for (int c = 0; c < C1; c++) s += W1[(size_t)k * F1 + h * C1 + c] * a[h * C1 + c];
    (which ? Vd : Vs)[h * C1 + k] = s;
    return;
  }
  t -= PR0;
  if (t < PR1) {
    int h = t / (80 * K1PAD);
    int rem = t - h * 80 * K1PAD;
    int c = rem / K1PAD, k = rem - c * K1PAD;
    float v = (c < C1 && k < C1) ? W1[(size_t)k * F1 + h * C1 + c] : 0.f;
    W1t[t] = f2b(v);
    return;
  }
  t -= PR1;
  if (t < PR2) {
    int c = t / K2PAD, k = t - c * K2PAD;
    float v = (c < C2 && k < F1) ? W2[(size_t)k * C2 + c] : 0.f;
    W2t[t] = f2b(v);
    return;
  }
  t -= PR2;
  if (t < PR3) {
    int n = t / (K2PAD - F1), j = t - n * (K2PAD - F1);
    hab[(size_t)n * K2PAD + F1 + j] = 0;
    return;
  }
  t -= PR3;
  if (t < PR4) {
    int n = t / 40, c2 = t - n * 40;
    ushort2 o;
    if (c2 < 39) { o.x = f2h(x[(size_t)n * C1 + 2 * c2]); o.y = f2h(x[(size_t)n * C1 + 2 * c2 + 1]); }
    else         { o.x = 0; o.y = 0; }
    *(ushort2*)(xhf + (size_t)n * 80 + 2 * c2) = o;
  }
}

/* ---------------- layer-1 logits: asb[n][12] node-major ---------------- */

__global__ __launch_bounds__(256) void k_alpha1x(const float* __restrict__ x,
                                                 const float* __restrict__ Vs,
                                                 const float* __restrict__ Vd,
                                                 float* __restrict__ asb,
                                                 float* __restrict__ adb) {
  __shared__ float sVs[H1 * C1], sVd[H1 * C1];
  for (int i = threadIdx.x; i < H1 * C1; i += 256) { sVs[i] = Vs[i]; sVd[i] = Vd[i]; }
  __syncthreads();
  int t = blockIdx.x * 256 + threadIdx.x;
  if (t >= N_NODES * H1) return;
  int n = t / H1, h = t - n * H1;
  const float2* row = (const float2*)(x + (size_t)n * C1);
  const float2* vs2 = (const float2*)(sVs + h * C1);
  const float2* vd2 = (const float2*)(sVd + h * C1);
  float s0 = 0.f, s1 = 0.f;
#pragma unroll 13
  for (int i = 0; i < C1 / 2; i++) {
    float2 v = row[i];
    float2 a = vs2[i];
    float2 b = vd2[i];
    s0 += v.x * a.x + v.y * a.y;
    s1 += v.x * b.x + v.y * b.y;
  }
  asb[(size_t)n * HP + h] = s0;
  adb[(size_t)n * HP + h] = s1;
}

/* ---------------- edge-parallel weights: ex1t[h][e] fp16 head-planes ---------------- */

__global__ void k_ex1(const float* __restrict__ asb, const float* __restrict__ adb,
                      const int* __restrict__ srcs, const int* __restrict__ dsts,
                      ushort_t* __restrict__ ex1t) {
  int e = blockIdx.x * blockDim.x + threadIdx.x;
  if (e >= E_TOT) return;
  int s = srcs[e], d = dsts[e];
  const float* pa = asb + (size_t)s * HP;
  const float* pd = adb + (size_t)d * HP;
  float4 a0 = *(const float4*)pa, a1 = *(const float4*)(pa + 4);
  float2 a2 = *(const float2*)(pa + 8);
  float4 d0 = *(const float4*)pd, d1 = *(const float4*)(pd + 4);
  float2 d2 = *(const float2*)(pd + 8);
  float r[10];
  r[0] = __expf(lrelu(a0.x + d0.x)); r[1] = __expf(lrelu(a0.y + d0.y));
  r[2] = __expf(lrelu(a0.z + d0.z)); r[3] = __expf(lrelu(a0.w + d0.w));
  r[4] = __expf(lrelu(a1.x + d1.x)); r[5] = __expf(lrelu(a1.y + d1.y));
  r[6] = __expf(lrelu(a1.z + d1.z)); r[7] = __expf(lrelu(a1.w + d1.w));
  r[8] = __expf(lrelu(a2.x + d2.x)); r[9] = __expf(lrelu(a2.y + d2.y));
#pragma unroll
  for (int h = 0; h < H1; h++) ex1t[(size_t)h * E_TOT + e] = f2h(r[h]);
}

/* ---------------- layer-1 aggregation: wave per dst, fp16 dot2, fused denom -------
   xb[h][n][96] = bf16( (1/sum ex) * sum_e ex1[e][h] * x[src_e][c] )
   Pairs are GLOBAL-even-aligned (e0 = beg&~1); a 2-slot mask on the shared
   B-operands (x pair, ones pair) zeroes out-of-range slots.                         */

__global__ __launch_bounds__(256) void k_aggv5(const ushort_t* __restrict__ xhf,
                                               const ushort_t* __restrict__ ex1t,
                                               const int* __restrict__ offs,
                                               const int* __restrict__ srcs,
                                               ushort_t* __restrict__ xb) {
  int wid = (blockIdx.x * 256 + threadIdx.x) >> 6;
  int lane = threadIdx.x & 63;
  if (wid >= N_NODES) return;
  int n = wid;
  int beg = __builtin_amdgcn_readfirstlane(offs[n]);
  int end = __builtin_amdgcn_readfirstlane(offs[n + 1]);

  float acc0[H1] = {}, acc1[H1] = {}, sum[H1] = {};
  const unsigned int ONES = 0x3C003C00u;   /* (fp16 1.0, fp16 1.0) */

  for (int e0 = beg & ~1; e0 < end; e0 += 2) {
    unsigned int m = 0xFFFFFFFFu;
    if (e0 < beg) m &= 0xFFFF0000u;          /* slot0 before this node's range */
    if (e0 + 1 >= end) m &= 0x0000FFFFu;     /* slot1 past this node's range  */
    int s0 = srcs[e0], s1 = srcs[e0 + 1];    /* e0 even <= E_TOT-2: in bounds */
    unsigned int w[H1];
#pragma unroll
    for (int h = 0; h < H1; h++)
      w[h] = *(const unsigned int*)(ex1t + (size_t)h * E_TOT + e0);   /* 4B aligned */
    unsigned int xv0 = 0, xv1 = 0;
    if (lane < 39) {
      xv0 = *(const unsigned int*)(xhf + (size_t)s0 * 80 + 2 * lane);
      xv1 = *(const unsigned int*)(xhf + (size_t)s1 * 80 + 2 * lane);
    }
    unsigned int xA = __builtin_amdgcn_perm(xv1, xv0, 0x05040100u) & m;  /* (s0.lo, s1.lo) */
    unsigned int xB = __builtin_amdgcn_perm(xv1, xv0, 0x07060302u) & m;  /* (s0.hi, s1.hi) */
    unsigned int on = ONES & m;
#pragma unroll
    for (int h = 0; h < H1; h++) {
      acc0[h] = dot2h(w[h], xA, acc0[h]);
      acc1[h] = dot2h(w[h], xB, acc1[h]);
      sum[h]  = dot2h(w[h], on, sum[h]);
    }
  }

  if (lane < 48) {
    int colu = (lane < 39) ? 2 * lane : C1 + 2 * (lane - 39);   /* pad cols 78..95 */
#pragma unroll
    for (int h = 0; h < H1; h++) {
      float iv = 1.f / (sum[h] + 1e-16f);
      ushort2 o;
      if (lane < 39) { o.x = f2b(acc0[h] * iv); o.y = f2b(acc1[h] * iv); }
      else           { o.x = 0; o.y = 0; }
      *(ushort2*)(xb + ((size_t)h * N_NODES + n) * K1PAD + colu) = o;
    }
  }
}

/* ---------------- layer-1 block-diag GEMM via MFMA (unchanged) ---------------- */

__global__ __launch_bounds__(256) void k_bgemm_m(const ushort_t* __restrict__ xb,
                                                 const ushort_t* __restrict__ W1t,
                                                 const float* __restrict__ b1,
                                                 ushort_t* __restrict__ hab) {
  __shared__ ushort_t sA[64 * AP1];
  __shared__ ushort_t sB[80 * AP1];
  int h = blockIdx.y;
  int m0 = blockIdx.x * 64;
  int tid = threadIdx.x;

  for (int i = tid; i < 64 * 12; i += 256) {
    int r = i / 12, cx = i - r * 12;
    uint4 v = make_uint4(0, 0, 0, 0);
    int m = m0 + r;
    if (m < N_NODES) v = *(const uint4*)(xb + ((size_t)h * N_NODES + m) * K1PAD + cx * 8);
    *(uint4*)(sA + r * AP1 + cx * 8) = v;
  }
  for (int i = tid; i < 80 * 12; i += 256) {
    int c = i / 12, cx = i - c * 12;
    uint4 v = *(const uint4*)(W1t + ((size_t)h * 80 + c) * K1PAD + cx * 8);
    *(uint4*)(sB + c * AP1 + cx * 8) = v;
  }
  __syncthreads();

  int w = tid >> 6, l = tid & 63;
  int rb = l & 15, g = l >> 4;
  f32x4 acc[5] = {};
  const ushort_t* pa = sA + (w * 16 + rb) * AP1 + g * 8;
#pragma unroll
  for (int k0 = 0; k0 < K1PAD; k0 += 32) {
    bf16x8 a = *(const bf16x8*)(pa + k0);
#pragma unroll
    for (int ct = 0; ct < 5; ct++) {
      bf16x8 b = *(const bf16x8*)(sB + (ct * 16 + rb) * AP1 + k0 + g * 8);
      acc[ct] = __builtin_amdgcn_mfma_f32_16x16x32_bf16(a, b, acc[ct], 0, 0, 0);
    }
  }

  int mrow = m0 + w * 16 + g * 4;
#pragma unroll
  for (int ct = 0; ct < 5; ct++) {
    int col = ct * 16 + rb;
    if (col >= C1) continue;
    float bias = b1[h * C1 + col];
#pragma unroll
    for (int r = 0; r < 4; r++) {
      int m = mrow + r;
      if (m >= N_NODES) continue;
      float v = acc[ct][r] + bias;
      v = (v > 0.f) ? v : (__expf(v) - 1.f);
      hab[(size_t)m * K2PAD + h * C1 + col] = f2b(v);
    }
  }
}

/* ---------------- layer-2 GEMM via MFMA, split-K (unchanged) ---------------- */

__global__ __launch_bounds__(256) void k_gemm2m(const ushort_t* __restrict__ hab,
                                                const ushort_t* __restrict__ W2t,
                                                float* __restrict__ part) {
  __shared__ ushort_t sA[64 * AP2];
  __shared__ ushort_t sB[112 * AP2];
  int m0 = blockIdx.x * 64;
  int kz = blockIdx.y * K2CHUNK;
  int tid = threadIdx.x;
  int w = tid >> 6, l = tid & 63;
  int rb = l & 15, g = l >> 4;
  f32x4 acc[7] = {};

  for (int ks = 0; ks < K2CHUNK; ks += 32) {
    int kbase = kz + ks;
    {
      int r = tid >> 2, cx = tid & 3;
      uint4 v = make_uint4(0, 0, 0, 0);
      int m = m0 + r;
      if (m < N_NODES) v = *(const uint4*)(hab + (size_t)m * K2PAD + kbase + cx * 8);
      *(uint4*)(sA + r * AP2 + cx * 8) = v;
    }
    for (int i = tid; i < 112 * 4; i += 256) {
      int c = i >> 2, cx = i & 3;
      uint4 v = *(const uint4*)(W2t + (size_t)c * K2PAD + kbase + cx * 8);
      *(uint4*)(sB + c * AP2 + cx * 8) = v;
    }
    __syncthreads();
    bf16x8 a = *(const bf16x8*)(sA + (w * 16 + rb) * AP2 + g * 8);
#pragma unroll
    for (int ct = 0; ct < 7; ct++) {
      bf16x8 b = *(const bf16x8*)(sB + (ct * 16 + rb) * AP2 + g * 8);
      acc[ct] = __builtin_amdgcn_mfma_f32_16x16x32_bf16(a, b, acc[ct], 0, 0, 0);
    }
    __syncthreads();
  }

  float* P = part + (size_t)blockIdx.y * N_NODES * C2;
  int mrow = m0 + w * 16 + g * 4;
#pragma unroll
  for (int ct = 0; ct < 7; ct++) {
    int col = ct * 16 + rb;
    if (col >= C2) continue;
#pragma unroll
    for (int r = 0; r < 4; r++) {
      int m = mrow + r;
      if (m < N_NODES) P[(size_t)m * C2 + col] = acc[ct][r];
    }
  }
}

/* ---------------- fused reduce + layer-2 logits: wave per node ---------------- */

__global__ __launch_bounds__(256) void k_redalpha(const float* __restrict__ part,
                                                  const float* __restrict__ a_src,
                                                  const float* __restrict__ a_dst,
                                                  ushort_t* __restrict__ z2b,
                                                  float* __restrict__ as2,
                                                  float* __restrict__ ad2) {
  int wid = (blockIdx.x * 256 + threadIdx.x) >> 6;
  int lane = threadIdx.x & 63;
  if (wid >= N_NODES) return;
  float ps = 0.f, pd = 0.f;
  if (lane < C2 / 2) {
    float2 s = make_float2(0.f, 0.f);
#pragma unroll
    for (int c = 0; c < KSPLIT; c++) {
      float2 v = *(const float2*)(part + (size_t)c * N_NODES * C2 + (size_t)wid * C2 + 2 * lane);
      s.x += v.x; s.y += v.y;
    }
    ushort2 o; o.x = f2b(s.x); o.y = f2b(s.y);
    *(ushort2*)(z2b + (size_t)wid * C2 + 2 * lane) = o;
    ps = s.x * a_src[2 * lane] + s.y * a_src[2 * lane + 1];
    pd = s.x * a_dst[2 * lane] + s.y * a_dst[2 * lane + 1];
  }
#pragma unroll
  for (int o = 32; o; o >>= 1) { ps += __shfl_xor(ps, o); pd += __shfl_xor(pd, o); }
  if (lane == 0) { as2[wid] = ps; ad2[wid] = pd; }
}

/* ---------------- layer-2 edge weights (with zero sentinel) ---------------- */

__global__ void k_ex2(const float* __restrict__ as2, const float* __restrict__ ad2,
                      const int* __restrict__ srcs, const int* __restrict__ dsts,
                      float* __restrict__ ex2) {
  int e = blockIdx.x * blockDim.x + threadIdx.x;
  if (e > E_TOT) return;
  if (e == E_TOT) { ex2[e] = 0.f; return; }
  float v = as2[srcs[e]] + ad2[dsts[e]];
  ex2[e] = __expf(lrelu(v));
}

/* ---------------- layer-2 aggregation + bias + ReLU + pool, group-8, fused denom -- */

__global__ __launch_bounds__(256) void k_gat2v3(const ushort_t* __restrict__ z2b,
                                                const float* __restrict__ ex2,
                                                const int* __restrict__ offs,
                                                const int* __restrict__ srcs,
                                                const float* __restrict__ b2,
                                                const int* __restrict__ batch,
                                                unsigned int* __restrict__ pool) {
  int wid = (blockIdx.x * 256 + threadIdx.x) >> 6;
  int lane = threadIdx.x & 63;
  if (wid >= N_NODES) return;
  int n = wid;
  int beg = offs[n], deg = offs[n + 1] - beg;
  const unsigned int* zrow = (const unsigned int*)z2b;

  float acc0 = 0.f, acc1 = 0.f, sum = 0.f;

  for (int j = 0; j < deg; j += 8) {
    int ej[8], sj[8];
#pragma unroll
    for (int q = 0; q < 8; q++) {
      int jj = j + q;
      bool v = jj < deg;
      ej[q] = v ? beg + jj : E_TOT;
      sj[q] = srcs[v ? beg + jj : beg];
    }
    float p[8];
#pragma unroll
    for (int q = 0; q < 8; q++) p[q] = ex2[ej[q]];
    unsigned int z[8] = {0, 0, 0, 0, 0, 0, 0, 0};
    if (lane < C2 / 2) {
#pragma unroll
      for (int q = 0; q < 8; q++) z[q] = zrow[(size_t)sj[q] * (C2 / 2) + lane];
    }
#pragma unroll
    for (int q = 0; q < 8; q++) {
      acc0 += p[q] * bf_lo(z[q]);
      acc1 += p[q] * bf_hi(z[q]);
      sum += p[q];
    }
  }

  if (lane < C2 / 2) {
    float iv = 1.f / (sum + 1e-16f);
    float v0 = fmaxf(acc0 * iv + b2[2 * lane], 0.f);
    float v1 = fmaxf(acc1 * iv + b2[2 * lane + 1], 0.f);
    int g = batch[n];
    atomicMax(&pool[g * C2 + 2 * lane], __float_as_uint(v0));
    atomicMax(&pool[g * C2 + 2 * lane + 1], __float_as_uint(v1));
  }
}

/* ---------------- head: out = relu(pool @ Wg + bg) ---------------- */

__global__ __launch_bounds__(128) void k_head(const float* __restrict__ pool,
                                              const float* __restrict__ Wg,
                                              const float* __restrict__ bg,
                                              float* __restrict__ out) {
  __shared__ float row[C2];
  int g = blockIdx.x;
  if (threadIdx.x < C2) row[threadIdx.x] = pool[g * C2 + threadIdx.x];
  __syncthreads();
  int c = threadIdx.x;
  if (c < C2) {
    float acc = bg[c];
    for (int k = 0; k < C2; k++) acc += row[k] * Wg[k * C2 + c];
    out[g * C2 + c] = fmaxf(acc, 0.f);
  }
}

/* ---------------- launch ---------------- */

extern "C" void kernel_launch(void* const* d_in, const int* in_sizes, int n_in,
                              void* d_out, int out_size, void* d_ws, size_t ws_size,
                              hipStream_t stream) {
  const float* x      = (const float*)d_in[0];
  const int*   ei     = (const int*)d_in[1];
  const int*   batch  = (const int*)d_in[2];
  const float* W1     = (const float*)d_in[4];
  const float* a_src1 = (const float*)d_in[5];
  const float* a_dst1 = (const float*)d_in[6];
  const float* b1     = (const float*)d_in[7];
  const float* W2     = (const float*)d_in[8];
  const float* a_src2 = (const float*)d_in[9];
  const float* a_dst2 = (const float*)d_in[10];
  const float* b2     = (const float*)d_in[11];
  const float* Wg     = (const float*)d_in[12];
  const float* bg     = (const float*)d_in[13];
  float* out = (float*)d_out;

  char* w = (char*)d_ws;
  size_t off = 0;
  auto alloc = [&](size_t bytes) -> void* {
    void* p = w + off;
    off += (bytes + 255) & ~(size_t)255;
    return p;
  };

  ushort_t* xb   = (ushort_t*)alloc((size_t)H1 * N_NODES * K1PAD * 2);  /* 38.4 MB */
  ushort_t* hab  = (ushort_t*)alloc((size_t)N_NODES * K2PAD * 2);       /* 32 MB  */
  float* part    = (float*)alloc((size_t)KSPLIT * N_NODES * C2 * 4);    /* 40 MB  */
  float* asb     = (float*)alloc((size_t)N_NODES * HP * 4);             /* 0.96 MB */
  float* adb     = (float*)alloc((size_t)N_NODES * HP * 4);
  ushort_t* ex1t = (ushort_t*)alloc((size_t)H1 * E_TOT * 2);            /* 6.8 MB, head planes */
  ushort_t* xhf  = (ushort_t*)alloc((size_t)N_NODES * 80 * 2);          /* 3.2 MB fp16 */
  float* Vs      = (float*)alloc((size_t)H1 * C1 * 4);
  float* Vd      = (float*)alloc((size_t)H1 * C1 * 4);
  ushort_t* W1t  = (ushort_t*)alloc((size_t)H1 * 80 * K1PAD * 2);
  ushort_t* W2t  = (ushort_t*)alloc((size_t)112 * K2PAD * 2);
  /* cnt / cursor / pool: one contiguous zero region */
  int* cnt           = (int*)alloc((size_t)N_NODES * 4);
  int* cursor        = (int*)alloc((size_t)N_NODES * 4);
  unsigned int* pool = (unsigned int*)alloc((size_t)N_GRAPHS * C2 * 4);
  size_t zspan = (size_t)((char*)(pool + (size_t)N_GRAPHS * C2) - (char*)cnt);
  int* offs   = (int*)alloc((size_t)(N_NODES + 1) * 4);
  int* srcs   = (int*)alloc((size_t)E_TOT * 4);
  int* dsts   = (int*)alloc((size_t)E_TOT * 4);

  /* layer-2 buffers alias xb (dead after k_bgemm_m): ~5.7 MB < 38.4 MB */
  float* as2    = (float*)xb;
  float* ad2    = as2 + N_NODES;
  ushort_t* z2b = (ushort_t*)(ad2 + N_NODES);
  float* ex2    = (float*)(z2b + (size_t)N_NODES * C2);

  hipMemsetAsync(cnt, 0, zspan, stream);

  k_count<<<(E_TOT + 255) / 256, 256, 0, stream>>>(ei, cnt);
  k_scan<<<1, 1024, 0, stream>>>(cnt, offs, N_NODES);
  k_scatter<<<(E_TOT + 255) / 256, 256, 0, stream>>>(ei, offs, cursor, srcs, dsts);

  k_prep<<<(PR0 + PR1 + PR2 + PR3 + PR4 + 255) / 256, 256, 0, stream>>>(
      W1, a_src1, a_dst1, W2, x, Vs, Vd, W1t, W2t, hab, xhf);
  k_alpha1x<<<(N_NODES * H1 + 255) / 256, 256, 0, stream>>>(x, Vs, Vd, asb, adb);
  k_ex1<<<(E_TOT + 255) / 256, 256, 0, stream>>>(asb, adb, srcs, dsts, ex1t);
  k_aggv5<<<(N_NODES + 3) / 4, 256, 0, stream>>>(xhf, ex1t, offs, srcs, xb);
  k_bgemm_m<<<dim3((N_NODES + 63) / 64, H1), 256, 0, stream>>>(xb, W1t, b1, hab);

  k_gemm2m<<<dim3((N_NODES + 63) / 64, KSPLIT), 256, 0, stream>>>(hab, W2t, part);
  k_redalpha<<<(N_NODES + 3) / 4, 256, 0, stream>>>(part, a_src2, a_dst2, z2b, as2, ad2);
  k_ex2<<<(E_TOT + 1 + 255) / 256, 256, 0, stream>>>(as2, ad2, srcs, dsts, ex2);
  k_gat2v3<<<(N_NODES + 3) / 4, 256, 0, stream>>>(z2b, ex2, offs, srcs, b2, batch, pool);
  k_head<<<N_GRAPHS, 128, 0, stream>>>((const float*)pool, Wg, bg, out);
}

// Round 11
// 255.475 us; speedup vs baseline: 11.1377x; 1.0790x over previous
//
#include <hip/hip_runtime.h>
#include <hip/hip_bf16.h>

#define N_NODES  20000
#define N_EDGES  320000
#define E_TOT    (N_EDGES + N_NODES)   /* 340000 incl. self loops */
#define N_GRAPHS 512
#define H1 10
#define C1 78
#define F1 780                          /* H1*C1 */
#define C2 100
#define NEG_SLOPE 0.2f
#define KSPLIT 5
#define K1PAD 96                        /* layer-1 K (78) padded to 3x32 */
#define K2PAD 800                       /* layer-2 K (780) padded to 25x32 */
#define K2CHUNK 160                     /* 800 / KSPLIT */
#define AP1 104                         /* LDS row stride (bf16) for bgemm */
#define AP2 40                          /* LDS row stride for gemm2 */
#define HP 12                           /* padded head stride for asb/adb */

typedef short bf16x8 __attribute__((ext_vector_type(8)));
typedef float f32x4 __attribute__((ext_vector_type(4)));
typedef _Float16 half2v __attribute__((ext_vector_type(2)));
typedef unsigned short ushort_t;

__device__ __forceinline__ float bf_lo(unsigned int u) { return __uint_as_float(u << 16); }
__device__ __forceinline__ float bf_hi(unsigned int u) { return __uint_as_float(u & 0xFFFF0000u); }
__device__ __forceinline__ ushort_t f2b(float v) {
  __hip_bfloat16 b = __float2bfloat16(v);   /* RNE */
  return *reinterpret_cast<ushort_t*>(&b);
}
__device__ __forceinline__ ushort_t f2h(float v) {
  _Float16 h = (_Float16)v;                 /* RNE */
  return *reinterpret_cast<ushort_t*>(&h);
}
__device__ __forceinline__ float lrelu(float v) { return (v > 0.f) ? v : NEG_SLOPE * v; }
__device__ __forceinline__ float dot2h(unsigned int a, unsigned int b, float c) {
  union { unsigned int u; half2v v; } A, B;
  A.u = a; B.u = b;
  return __builtin_amdgcn_fdot2(A.v, B.v, c, false);
}

/* ---------------- fused count + prep ----------------
   blocks [0, NB_CNT): edge-degree count
   blocks [NB_CNT, ..): Vs/Vd + W1t + W2t + hab K-pad zero + x->fp16 */

#define PR0 (2 * H1 * C1)
#define PR1 (H1 * 80 * K1PAD)
#define PR2 (112 * K2PAD)
#define PR3 (N_NODES * (K2PAD - F1))
#define PR4 (N_NODES * 40)
#define PRT (PR0 + PR1 + PR2 + PR3 + PR4)
#define NB_CNT ((E_TOT + 255) / 256)
#define NB_PREP ((PRT + 255) / 256)

__global__ void k_cntprep(const int* __restrict__ ei,
                          const float* __restrict__ W1, const float* __restrict__ a_src,
                          const float* __restrict__ a_dst, const float* __restrict__ W2,
                          const float* __restrict__ x,
                          int* __restrict__ cnt,
                          float* __restrict__ Vs, float* __restrict__ Vd,
                          ushort_t* __restrict__ W1t, ushort_t* __restrict__ W2t,
                          ushort_t* __restrict__ hab, ushort_t* __restrict__ xhf) {
  if (blockIdx.x < NB_CNT) {
    int e = blockIdx.x * 256 + threadIdx.x;
    if (e >= E_TOT) return;
    int dst = (e < N_EDGES) ? ei[N_EDGES + e] : (e - N_EDGES);
    atomicAdd(&cnt[dst], 1);
    return;
  }
  int t = (blockIdx.x - NB_CNT) * 256 + threadIdx.x;
  if (t < PR0) {
    int which = (t >= H1 * C1) ? 1 : 0;
    int r = t - which * H1 * C1;
    int h = r / C1, k = r - h * C1;
    const float* a = which ? a_dst : a_src;
    float s = 0.f;
    for (int c = 0; c < C1; c++) s += W1[(size_t)k * F1 + h * C1 + c] * a[h * C1 + c];
    (which ? Vd : Vs)[h * C1 + k] = s;
    return;
  }
  t -= PR0;
  if (t < PR1) {
    int h = t / (80 * K1PAD);
    int rem = t - h * 80 * K1PAD;
    int c = rem / K1PAD, k = rem - c * K1PAD;
    float v = (c < C1 && k < C1) ? W1[(size_t)k * F1 + h * C1 + c] : 0.f;
    W1t[t] = f2b(v);
    return;
  }
  t -= PR1;
  if (t < PR2) {
    int c = t / K2PAD, k = t - c * K2PAD;
    float v = (c < C2 && k < F1) ? W2[(size_t)k * C2 + c] : 0.f;
    W2t[t] = f2b(v);
    return;
  }
  t -= PR2;
  if (t < PR3) {
    int n = t / (K2PAD - F1), j = t - n * (K2PAD - F1);
    hab[(size_t)n * K2PAD + F1 + j] = 0;
    return;
  }
  t -= PR3;
  if (t < PR4) {
    int n = t / 40, c2 = t - n * 40;
    ushort2 o;
    if (c2 < 39) { o.x = f2h(x[(size_t)n * C1 + 2 * c2]); o.y = f2h(x[(size_t)n * C1 + 2 * c2 + 1]); }
    else         { o.x = 0; o.y = 0; }
    *(ushort2*)(xhf + (size_t)n * 80 + 2 * c2) = o;
  }
}

/* ---------------- fused scan (block 0) + layer-1 logits (blocks 1..) --------------
   scan: 1024 threads x 20 elems (int4 loads); alpha: asb[n][12] node-major          */

__global__ __launch_bounds__(1024) void k_scanalpha(const int* __restrict__ cnt,
                                                    int* __restrict__ offs,
                                                    const float* __restrict__ x,
                                                    const float* __restrict__ Vs,
                                                    const float* __restrict__ Vd,
                                                    float* __restrict__ asb,
                                                    float* __restrict__ adb) {
  if (blockIdx.x == 0) {
    const int PER = 20;
    int t = threadIdx.x;
    int lane = t & 63, wv = t >> 6;
    int base = t * PER;
    int raw[PER];
    const int4* c4 = (const int4*)(cnt + base);   /* base*4 = t*80, 16B aligned */
#pragma unroll
    for (int q = 0; q < 5; q++) {                 /* may read past n within ws: masked below */
      int4 v = c4[q];
      raw[4 * q] = v.x; raw[4 * q + 1] = v.y; raw[4 * q + 2] = v.z; raw[4 * q + 3] = v.w;
    }
    int loc[PER];
    int run = 0;
#pragma unroll
    for (int k = 0; k < PER; k++) {
      int idx = base + k;
      run += (idx < N_NODES) ? raw[k] : 0;
      loc[k] = run;
    }
    int total = run;
    int sc = total;
#pragma unroll
    for (int o = 1; o < 64; o <<= 1) {
      int u = __shfl_up(sc, o);
      if (lane >= o) sc += u;
    }
    __shared__ int ws[16];
    if (lane == 63) ws[wv] = sc;
    __syncthreads();
    if (t == 0) {
      int r = 0;
#pragma unroll
      for (int i = 0; i < 16; i++) { int v = ws[i]; ws[i] = r; r += v; }
    }
    __syncthreads();
    int excl = ws[wv] + sc - total;
#pragma unroll
    for (int k = 0; k < PER; k++) {
      int idx = base + k;
      if (idx < N_NODES) offs[idx + 1] = excl + loc[k];
    }
    if (t == 0) offs[0] = 0;
    return;
  }

  /* alpha1x part */
  __shared__ float sVs[H1 * C1], sVd[H1 * C1];
  for (int i = threadIdx.x; i < H1 * C1; i += 1024) { sVs[i] = Vs[i]; sVd[i] = Vd[i]; }
  __syncthreads();
  int t = (blockIdx.x - 1) * 1024 + threadIdx.x;
  if (t >= N_NODES * H1) return;
  int n = t / H1, h = t - n * H1;
  const float2* row = (const float2*)(x + (size_t)n * C1);
  const float2* vs2 = (const float2*)(sVs + h * C1);
  const float2* vd2 = (const float2*)(sVd + h * C1);
  float s0 = 0.f, s1 = 0.f;
#pragma unroll 13
  for (int i = 0; i < C1 / 2; i++) {
    float2 v = row[i];
    float2 a = vs2[i];
    float2 b = vd2[i];
    s0 += v.x * a.x + v.y * a.y;
    s1 += v.x * b.x + v.y * b.y;
  }
  asb[(size_t)n * HP + h] = s0;
  adb[(size_t)n * HP + h] = s1;
}

__global__ void k_scatter(const int* __restrict__ ei, const int* __restrict__ offs,
                          int* __restrict__ cursor, int* __restrict__ srcs,
                          int* __restrict__ dsts) {
  int e = blockIdx.x * blockDim.x + threadIdx.x;
  if (e >= E_TOT) return;
  int src, dst;
  if (e < N_EDGES) { src = ei[e]; dst = ei[N_EDGES + e]; }
  else             { src = dst = e - N_EDGES; }
  int pos = offs[dst] + atomicAdd(&cursor[dst], 1);
  srcs[pos] = src;
  dsts[pos] = dst;
}

/* ---------------- edge-parallel weights: ex1t[h][e] fp16 head-planes ---------------- */

__global__ void k_ex1(const float* __restrict__ asb, const float* __restrict__ adb,
                      const int* __restrict__ srcs, const int* __restrict__ dsts,
                      ushort_t* __restrict__ ex1t) {
  int e = blockIdx.x * blockDim.x + threadIdx.x;
  if (e >= E_TOT) return;
  int s = srcs[e], d = dsts[e];
  const float* pa = asb + (size_t)s * HP;
  const float* pd = adb + (size_t)d * HP;
  float4 a0 = *(const float4*)pa, a1 = *(const float4*)(pa + 4);
  float2 a2 = *(const float2*)(pa + 8);
  float4 d0 = *(const float4*)pd, d1 = *(const float4*)(pd + 4);
  float2 d2 = *(const float2*)(pd + 8);
  float r[10];
  r[0] = __expf(lrelu(a0.x + d0.x)); r[1] = __expf(lrelu(a0.y + d0.y));
  r[2] = __expf(lrelu(a0.z + d0.z)); r[3] = __expf(lrelu(a0.w + d0.w));
  r[4] = __expf(lrelu(a1.x + d1.x)); r[5] = __expf(lrelu(a1.y + d1.y));
  r[6] = __expf(lrelu(a1.z + d1.z)); r[7] = __expf(lrelu(a1.w + d1.w));
  r[8] = __expf(lrelu(a2.x + d2.x)); r[9] = __expf(lrelu(a2.y + d2.y));
#pragma unroll
  for (int h = 0; h < H1; h++) ex1t[(size_t)h * E_TOT + e] = f2h(r[h]);
}

/* ---------------- layer-1 aggregation: wave per dst, fp16 dot2, fused denom ------- */

__global__ __launch_bounds__(256) void k_aggv5(const ushort_t* __restrict__ xhf,
                                               const ushort_t* __restrict__ ex1t,
                                               const int* __restrict__ offs,
                                               const int* __restrict__ srcs,
                                               ushort_t* __restrict__ xb) {
  int wid = (blockIdx.x * 256 + threadIdx.x) >> 6;
  int lane = threadIdx.x & 63;
  if (wid >= N_NODES) return;
  int n = wid;
  int beg = __builtin_amdgcn_readfirstlane(offs[n]);
  int end = __builtin_amdgcn_readfirstlane(offs[n + 1]);

  float acc0[H1] = {}, acc1[H1] = {}, sum[H1] = {};
  const unsigned int ONES = 0x3C003C00u;   /* (fp16 1.0, fp16 1.0) */

  for (int e0 = beg & ~1; e0 < end; e0 += 2) {
    unsigned int m = 0xFFFFFFFFu;
    if (e0 < beg) m &= 0xFFFF0000u;          /* slot0 before this node's range */
    if (e0 + 1 >= end) m &= 0x0000FFFFu;     /* slot1 past this node's range  */
    int s0 = srcs[e0], s1 = srcs[e0 + 1];    /* e0 even <= E_TOT-2: in bounds */
    unsigned int w[H1];
#pragma unroll
    for (int h = 0; h < H1; h++)
      w[h] = *(const unsigned int*)(ex1t + (size_t)h * E_TOT + e0);   /* 4B aligned */
    unsigned int xv0 = 0, xv1 = 0;
    if (lane < 39) {
      xv0 = *(const unsigned int*)(xhf + (size_t)s0 * 80 + 2 * lane);
      xv1 = *(const unsigned int*)(xhf + (size_t)s1 * 80 + 2 * lane);
    }
    unsigned int xA = __builtin_amdgcn_perm(xv1, xv0, 0x05040100u) & m;  /* (s0.lo, s1.lo) */
    unsigned int xB = __builtin_amdgcn_perm(xv1, xv0, 0x07060302u) & m;  /* (s0.hi, s1.hi) */
    unsigned int on = ONES & m;
#pragma unroll
    for (int h = 0; h < H1; h++) {
      acc0[h] = dot2h(w[h], xA, acc0[h]);
      acc1[h] = dot2h(w[h], xB, acc1[h]);
      sum[h]  = dot2h(w[h], on, sum[h]);
    }
  }

  if (lane < 48) {
    int colu = (lane < 39) ? 2 * lane : C1 + 2 * (lane - 39);   /* pad cols 78..95 */
#pragma unroll
    for (int h = 0; h < H1; h++) {
      float iv = 1.f / (sum[h] + 1e-16f);
      ushort2 o;
      if (lane < 39) { o.x = f2b(acc0[h] * iv); o.y = f2b(acc1[h] * iv); }
      else           { o.x = 0; o.y = 0; }
      *(ushort2*)(xb + ((size_t)h * N_NODES + n) * K1PAD + colu) = o;
    }
  }
}

/* ---------------- layer-1 block-diag GEMM via MFMA (unchanged) ---------------- */

__global__ __launch_bounds__(256) void k_bgemm_m(const ushort_t* __restrict__ xb,
                                                 const ushort_t* __restrict__ W1t,
                                                 const float* __restrict__ b1,
                                                 ushort_t* __restrict__ hab) {
  __shared__ ushort_t sA[64 * AP1];
  __shared__ ushort_t sB[80 * AP1];
  int h = blockIdx.y;
  int m0 = blockIdx.x * 64;
  int tid = threadIdx.x;

  for (int i = tid; i < 64 * 12; i += 256) {
    int r = i / 12, cx = i - r * 12;
    uint4 v = make_uint4(0, 0, 0, 0);
    int m = m0 + r;
    if (m < N_NODES) v = *(const uint4*)(xb + ((size_t)h * N_NODES + m) * K1PAD + cx * 8);
    *(uint4*)(sA + r * AP1 + cx * 8) = v;
  }
  for (int i = tid; i < 80 * 12; i += 256) {
    int c = i / 12, cx = i - c * 12;
    uint4 v = *(const uint4*)(W1t + ((size_t)h * 80 + c) * K1PAD + cx * 8);
    *(uint4*)(sB + c * AP1 + cx * 8) = v;
  }
  __syncthreads();

  int w = tid >> 6, l = tid & 63;
  int rb = l & 15, g = l >> 4;
  f32x4 acc[5] = {};
  const ushort_t* pa = sA + (w * 16 + rb) * AP1 + g * 8;
#pragma unroll
  for (int k0 = 0; k0 < K1PAD; k0 += 32) {
    bf16x8 a = *(const bf16x8*)(pa + k0);
#pragma unroll
    for (int ct = 0; ct < 5; ct++) {
      bf16x8 b = *(const bf16x8*)(sB + (ct * 16 + rb) * AP1 + k0 + g * 8);
      acc[ct] = __builtin_amdgcn_mfma_f32_16x16x32_bf16(a, b, acc[ct], 0, 0, 0);
    }
  }

  int mrow = m0 + w * 16 + g * 4;
#pragma unroll
  for (int ct = 0; ct < 5; ct++) {
    int col = ct * 16 + rb;
    if (col >= C1) continue;
    float bias = b1[h * C1 + col];
#pragma unroll
    for (int r = 0; r < 4; r++) {
      int m = mrow + r;
      if (m >= N_NODES) continue;
      float v = acc[ct][r] + bias;
      v = (v > 0.f) ? v : (__expf(v) - 1.f);
      hab[(size_t)m * K2PAD + h * C1 + col] = f2b(v);
    }
  }
}

/* ---------------- layer-2 GEMM via MFMA, split-K (unchanged) ---------------- */

__global__ __launch_bounds__(256) void k_gemm2m(const ushort_t* __restrict__ hab,
                                                const ushort_t* __restrict__ W2t,
                                                float* __restrict__ part) {
  __shared__ ushort_t sA[64 * AP2];
  __shared__ ushort_t sB[112 * AP2];
  int m0 = blockIdx.x * 64;
  int kz = blockIdx.y * K2CHUNK;
  int tid = threadIdx.x;
  int w = tid >> 6, l = tid & 63;
  int rb = l & 15, g = l >> 4;
  f32x4 acc[7] = {};

  for (int ks = 0; ks < K2CHUNK; ks += 32) {
    int kbase = kz + ks;
    {
      int r = tid >> 2, cx = tid & 3;
      uint4 v = make_uint4(0, 0, 0, 0);
      int m = m0 + r;
      if (m < N_NODES) v = *(const uint4*)(hab + (size_t)m * K2PAD + kbase + cx * 8);
      *(uint4*)(sA + r * AP2 + cx * 8) = v;
    }
    for (int i = tid; i < 112 * 4; i += 256) {
      int c = i >> 2, cx = i & 3;
      uint4 v = *(const uint4*)(W2t + (size_t)c * K2PAD + kbase + cx * 8);
      *(uint4*)(sB + c * AP2 + cx * 8) = v;
    }
    __syncthreads();
    bf16x8 a = *(const bf16x8*)(sA + (w * 16 + rb) * AP2 + g * 8);
#pragma unroll
    for (int ct = 0; ct < 7; ct++) {
      bf16x8 b = *(const bf16x8*)(sB + (ct * 16 + rb) * AP2 + g * 8);
      acc[ct] = __builtin_amdgcn_mfma_f32_16x16x32_bf16(a, b, acc[ct], 0, 0, 0);
    }
    __syncthreads();
  }

  float* P = part + (size_t)blockIdx.y * N_NODES * C2;
  int mrow = m0 + w * 16 + g * 4;
#pragma unroll
  for (int ct = 0; ct < 7; ct++) {
    int col = ct * 16 + rb;
    if (col >= C2) continue;
#pragma unroll
    for (int r = 0; r < 4; r++) {
      int m = mrow + r;
      if (m < N_NODES) P[(size_t)m * C2 + col] = acc[ct][r];
    }
  }
}

/* ---------------- fused reduce + layer-2 logits: wave per node ---------------- */

__global__ __launch_bounds__(256) void k_redalpha(const float* __restrict__ part,
                                                  const float* __restrict__ a_src,
                                                  const float* __restrict__ a_dst,
                                                  ushort_t* __restrict__ z2b,
                                                  float* __restrict__ as2,
                                                  float* __restrict__ ad2) {
  int wid = (blockIdx.x * 256 + threadIdx.x) >> 6;
  int lane = threadIdx.x & 63;
  if (wid >= N_NODES) return;
  float ps = 0.f, pd = 0.f;
  if (lane < C2 / 2) {
    float2 s = make_float2(0.f, 0.f);
#pragma unroll
    for (int c = 0; c < KSPLIT; c++) {
      float2 v = *(const float2*)(part + (size_t)c * N_NODES * C2 + (size_t)wid * C2 + 2 * lane);
      s.x += v.x; s.y += v.y;
    }
    ushort2 o; o.x = f2b(s.x); o.y = f2b(s.y);
    *(ushort2*)(z2b + (size_t)wid * C2 + 2 * lane) = o;
    ps = s.x * a_src[2 * lane] + s.y * a_src[2 * lane + 1];
    pd = s.x * a_dst[2 * lane] + s.y * a_dst[2 * lane + 1];
  }
#pragma unroll
  for (int o = 32; o; o >>= 1) { ps += __shfl_xor(ps, o); pd += __shfl_xor(pd, o); }
  if (lane == 0) { as2[wid] = ps; ad2[wid] = pd; }
}

/* ---------------- layer-2 aggregation + inline edge-exp + bias + ReLU + pool ------ */

__global__ __launch_bounds__(256) void k_gat2v4(const ushort_t* __restrict__ z2b,
                                                const float* __restrict__ as2,
                                                const float* __restrict__ ad2,
                                                const int* __restrict__ offs,
                                                const int* __restrict__ srcs,
                                                const float* __restrict__ b2,
                                                const int* __restrict__ batch,
                                                unsigned int* __restrict__ pool) {
  int wid = (blockIdx.x * 256 + threadIdx.x) >> 6;
  int lane = threadIdx.x & 63;
  if (wid >= N_NODES) return;
  int n = wid;
  int beg = offs[n], deg = offs[n + 1] - beg;
  float adn = ad2[n];
  const unsigned int* zrow = (const unsigned int*)z2b;

  float acc0 = 0.f, acc1 = 0.f, sum = 0.f;

  for (int j = 0; j < deg; j += 8) {
    int sj[8]; bool vj[8];
#pragma unroll
    for (int q = 0; q < 8; q++) {
      int jj = j + q;
      vj[q] = jj < deg;
      sj[q] = srcs[vj[q] ? beg + jj : beg];
    }
    float p[8];
#pragma unroll
    for (int q = 0; q < 8; q++) {
      float pv = __expf(lrelu(as2[sj[q]] + adn));
      p[q] = vj[q] ? pv : 0.f;
    }
    unsigned int z[8] = {0, 0, 0, 0, 0, 0, 0, 0};
    if (lane < C2 / 2) {
#pragma unroll
      for (int q = 0; q < 8; q++) z[q] = zrow[(size_t)sj[q] * (C2 / 2) + lane];
    }
#pragma unroll
    for (int q = 0; q < 8; q++) {
      acc0 += p[q] * bf_lo(z[q]);
      acc1 += p[q] * bf_hi(z[q]);
      sum += p[q];
    }
  }

  if (lane < C2 / 2) {
    float iv = 1.f / (sum + 1e-16f);
    float v0 = fmaxf(acc0 * iv + b2[2 * lane], 0.f);
    float v1 = fmaxf(acc1 * iv + b2[2 * lane + 1], 0.f);
    int g = batch[n];
    atomicMax(&pool[g * C2 + 2 * lane], __float_as_uint(v0));
    atomicMax(&pool[g * C2 + 2 * lane + 1], __float_as_uint(v1));
  }
}

/* ---------------- head: out = relu(pool @ Wg + bg) ---------------- */

__global__ __launch_bounds__(128) void k_head(const float* __restrict__ pool,
                                              const float* __restrict__ Wg,
                                              const float* __restrict__ bg,
                                              float* __restrict__ out) {
  __shared__ float row[C2];
  int g = blockIdx.x;
  if (threadIdx.x < C2) row[threadIdx.x] = pool[g * C2 + threadIdx.x];
  __syncthreads();
  int c = threadIdx.x;
  if (c < C2) {
    float acc = bg[c];
    for (int k = 0; k < C2; k++) acc += row[k] * Wg[k * C2 + c];
    out[g * C2 + c] = fmaxf(acc, 0.f);
  }
}

/* ---------------- launch ---------------- */

extern "C" void kernel_launch(void* const* d_in, const int* in_sizes, int n_in,
                              void* d_out, int out_size, void* d_ws, size_t ws_size,
                              hipStream_t stream) {
  const float* x      = (const float*)d_in[0];
  const int*   ei     = (const int*)d_in[1];
  const int*   batch  = (const int*)d_in[2];
  const float* W1     = (const float*)d_in[4];
  const float* a_src1 = (const float*)d_in[5];
  const float* a_dst1 = (const float*)d_in[6];
  const float* b1     = (const float*)d_in[7];
  const float* W2     = (const float*)d_in[8];
  const float* a_src2 = (const float*)d_in[9];
  const float* a_dst2 = (const float*)d_in[10];
  const float* b2     = (const float*)d_in[11];
  const float* Wg     = (const float*)d_in[12];
  const float* bg     = (const float*)d_in[13];
  float* out = (float*)d_out;

  char* w = (char*)d_ws;
  size_t off = 0;
  auto alloc = [&](size_t bytes) -> void* {
    void* p = w + off;
    off += (bytes + 255) & ~(size_t)255;
    return p;
  };

  ushort_t* xb   = (ushort_t*)alloc((size_t)H1 * N_NODES * K1PAD * 2);  /* 38.4 MB */
  ushort_t* hab  = (ushort_t*)alloc((size_t)N_NODES * K2PAD * 2);       /* 32 MB  */
  float* part    = (float*)alloc((size_t)KSPLIT * N_NODES * C2 * 4);    /* 40 MB  */
  float* asb     = (float*)alloc((size_t)N_NODES * HP * 4);             /* 0.96 MB */
  float* adb     = (float*)alloc((size_t)N_NODES * HP * 4);
  ushort_t* ex1t = (ushort_t*)alloc((size_t)H1 * E_TOT * 2);            /* 6.8 MB, head planes */
  ushort_t* xhf  = (ushort_t*)alloc((size_t)N_NODES * 80 * 2);          /* 3.2 MB fp16 */
  float* Vs      = (float*)alloc((size_t)H1 * C1 * 4);
  float* Vd      = (float*)alloc((size_t)H1 * C1 * 4);
  ushort_t* W1t  = (ushort_t*)alloc((size_t)H1 * 80 * K1PAD * 2);
  ushort_t* W2t  = (ushort_t*)alloc((size_t)112 * K2PAD * 2);
  /* cnt / cursor / pool: one contiguous zero region */
  int* cnt           = (int*)alloc((size_t)N_NODES * 4);
  int* cursor        = (int*)alloc((size_t)N_NODES * 4);
  unsigned int* pool = (unsigned int*)alloc((size_t)N_GRAPHS * C2 * 4);
  size_t zspan = (size_t)((char*)(pool + (size_t)N_GRAPHS * C2) - (char*)cnt);
  int* offs   = (int*)alloc((size_t)(N_NODES + 1) * 4);
  int* srcs   = (int*)alloc((size_t)E_TOT * 4);
  int* dsts   = (int*)alloc((size_t)E_TOT * 4);

  /* layer-2 buffers alias xb (dead after k_bgemm_m): ~4.4 MB < 38.4 MB */
  float* as2    = (float*)xb;
  float* ad2    = as2 + N_NODES;
  ushort_t* z2b = (ushort_t*)(ad2 + N_NODES);

  hipMemsetAsync(cnt, 0, zspan, stream);

  k_cntprep<<<NB_CNT + NB_PREP, 256, 0, stream>>>(ei, W1, a_src1, a_dst1, W2, x,
                                                  cnt, Vs, Vd, W1t, W2t, hab, xhf);
  k_scanalpha<<<1 + (N_NODES * H1 + 1023) / 1024, 1024, 0, stream>>>(cnt, offs, x, Vs, Vd,
                                                                     asb, adb);
  k_scatter<<<(E_TOT + 255) / 256, 256, 0, stream>>>(ei, offs, cursor, srcs, dsts);
  k_ex1<<<(E_TOT + 255) / 256, 256, 0, stream>>>(asb, adb, srcs, dsts, ex1t);
  k_aggv5<<<(N_NODES + 3) / 4, 256, 0, stream>>>(xhf, ex1t, offs, srcs, xb);
  k_bgemm_m<<<dim3((N_NODES + 63) / 64, H1), 256, 0, stream>>>(xb, W1t, b1, hab);

  k_gemm2m<<<dim3((N_NODES + 63) / 64, KSPLIT), 256, 0, stream>>>(hab, W2t, part);
  k_redalpha<<<(N_NODES + 3) / 4, 256, 0, stream>>>(part, a_src2, a_dst2, z2b, as2, ad2);
  k_gat2v4<<<(N_NODES + 3) / 4, 256, 0, stream>>>(z2b, as2, ad2, offs, srcs, b2, batch, pool);
  k_head<<<N_GRAPHS, 128, 0, stream>>>((const float*)pool, Wg, bg, out);
}